// Round 10
// baseline (3208.455 us; speedup 1.0000x reference)
//
#include <hip/hip_runtime.h>
#include <hip/hip_bf16.h>
#include <stdint.h>

typedef unsigned short u16;
typedef __bf16 bf16t;
typedef _Float16 f16t;
typedef __attribute__((ext_vector_type(8))) bf16t bf16x8;
typedef __attribute__((ext_vector_type(4))) float f32x4;
typedef __attribute__((ext_vector_type(2))) _Float16 h2;

#define B_   512
#define N_   100
#define P_   20
#define E_   256
#define H_   512
#define G4H_ 2048
#define BT_  (B_ * N_)   // 51200
#define BC_  128         // phase-B batch chunk
#define NCHUNK_ (B_ / BC_)
#define TSZ_ 4608        // 64*72 shorts per LDS tile chunk (9216 B)

__device__ __forceinline__ float bfu2f(unsigned u) {
    union { unsigned i; float f; } v; v.i = u << 16; return v.f;
}
__device__ __forceinline__ float bf2f(u16 x) { return bfu2f((unsigned)x); }
__device__ __forceinline__ u16 f2bf(float f) {
    union { float f; unsigned i; } v; v.f = f;
    unsigned r = v.i + 0x7FFFu + ((v.i >> 16) & 1u);
    return (u16)(r >> 16);
}
__device__ __forceinline__ u16 f2h_bits(float f) {
    union { f16t h; u16 u; } c; c.h = (f16t)f; return c.u;
}
__device__ __forceinline__ void unpack8(uint4 r, float* o) {
    o[0] = bfu2f(r.x & 0xffffu); o[1] = bfu2f(r.x >> 16);
    o[2] = bfu2f(r.y & 0xffffu); o[3] = bfu2f(r.y >> 16);
    o[4] = bfu2f(r.z & 0xffffu); o[5] = bfu2f(r.z >> 16);
    o[6] = bfu2f(r.w & 0xffffu); o[7] = bfu2f(r.w >> 16);
}
__device__ __forceinline__ void toh2x4(uint4 r, h2* o) {
    union { uint4 u; h2 h[4]; } c; c.u = r;
    o[0] = c.h[0]; o[1] = c.h[1]; o[2] = c.h[2]; o[3] = c.h[3];
}
__device__ __forceinline__ float tanh_f(float x) {
    x = fminf(15.f, fmaxf(-15.f, x));
    float e = __expf(2.f * x);
    return __fdividef(e - 1.f, e + 1.f);
}
__device__ __forceinline__ float sig_f(float x) {
    x = fminf(15.f, fmaxf(-15.f, x));
    return __fdividef(1.f, 1.f + __expf(-x));
}
// f32 polynomial tanh (clamped both ends) — used on the per-n final logit only
__device__ __forceinline__ float tanh_poly(float x) {
    x = fminf(3.25f, fmaxf(-3.25f, x));
    float z = x * x;
    float p = fmaf(fmaf(fmaf(-0.0018661f, z, 0.037231f), z, -0.249208f), z, 0.984238f);
    float r = x * p;
    return fminf(1.0f, fmaxf(-1.0f, r));
}
// packed-f16 tanh-dot step: s += dot2(vh, tanh_pk(qh + uh)).
__device__ __forceinline__ float tanhdot_h2(h2 uh, h2 qh, h2 vh, float s) {
    const h2 kLo = { (f16t)-3.25f, (f16t)-3.25f };
    const h2 kHi = { (f16t)3.25f,  (f16t)3.25f };
    const h2 c3 = { (f16t)-0.0018661f, (f16t)-0.0018661f };
    const h2 c2 = { (f16t)0.037231f,   (f16t)0.037231f };
    const h2 c1 = { (f16t)-0.249208f,  (f16t)-0.249208f };
    const h2 c0 = { (f16t)0.984238f,   (f16t)0.984238f };
    h2 t = uh + qh;
    t = __builtin_elementwise_max(t, kLo);
    t = __builtin_elementwise_min(t, kHi);
    h2 z = t * t;
    h2 p = __builtin_elementwise_fma(c3, z, c2);
    p = __builtin_elementwise_fma(p, z, c1);
    p = __builtin_elementwise_fma(p, z, c0);
    h2 r = t * p;
#if defined(__has_builtin) && __has_builtin(__builtin_amdgcn_fdot2)
    return __builtin_amdgcn_fdot2(r, vh, s, false);
#else
    return s + (float)r.x * (float)vh.x + (float)r.y * (float)vh.y;
#endif
}
__device__ __forceinline__ f32x4 mfma16(bf16x8 a, bf16x8 b, f32x4 c) {
    return __builtin_amdgcn_mfma_f32_16x16x32_bf16(a, b, c, 0, 0, 0);
}

// ---------------------------------------------------------------------------
__global__ void sentinel_kernel(float* out) {
    int i = blockIdx.x * 256 + threadIdx.x;
    if (i < B_) out[BT_ + i] = 1.0e9f;   // signals "workspace too small"
}

// init: zero c, zero_h, ll; broadcast dec_input0 rows
__global__ void init_kernel(float* c, u16* zero_h, float* ll, u16* dec0_rows,
                            const u16* __restrict__ dec0) {
    int i = blockIdx.x * 256 + threadIdx.x;          // 262144 threads
    if (i < B_ * H_) { c[i] = 0.f; zero_h[i] = 0; }
    if (i < B_) ll[i] = 0.f;
    if (i < B_ * E_) dec0_rows[i] = dec0[i & (E_ - 1)];
}

// embed[b,n,e] = sum_p x[b,n,p] * emb_W[e,p]
__global__ void embed_kernel(const u16* __restrict__ x, const u16* __restrict__ emb_W,
                             u16* __restrict__ embed) {
    __shared__ float xs[P_];
    int bt = blockIdx.x, tid = threadIdx.x;
    if (tid < P_) xs[tid] = bf2f(x[(size_t)bt * P_ + tid]);
    __syncthreads();
    float s = 0.f;
#pragma unroll
    for (int p = 0; p < P_; ++p) s += xs[p] * bf2f(emb_W[tid * P_ + p]);
    embed[(size_t)bt * E_ + tid] = f2bf(s);
}

// mask[b,t,n] = #{s<t : y[b,s]==n}   (cumulative COUNT, y may repeat)
__global__ void mask_kernel(const int* __restrict__ y, unsigned char* __restrict__ mask) {
    int b = blockIdx.x, n = threadIdx.x;
    if (n >= N_) return;
    unsigned char cnt = 0;
    for (int t = 0; t < N_; ++t) {
        mask[((size_t)b * N_ + t) * N_ + n] = cnt;
        if (y[b * N_ + t] == n) cnt++;
    }
}

// ---------------------------------------------------------------------------
// Fused LSTM step v7 (verified R8): BK=192, 4 K-iterations x 2 barriers.
__global__ __launch_bounds__(256) void fused7_step_kernel(
    const u16* __restrict__ h_base, int h_lda,
    const u16* __restrict__ x_base,
    const int* __restrict__ y,
    const u16* __restrict__ Whh, const u16* __restrict__ Wih,
    const u16* __restrict__ bih, const u16* __restrict__ bhh,
    float* __restrict__ cbuf,
    u16* __restrict__ hout,
    int mode, int t)
{
    __shared__ __align__(16) short As[3 * TSZ_];   // chunk slots 0|1|2
    __shared__ __align__(16) short Bs[3 * TSZ_];
    const int tid = threadIdx.x;
    const int bn = blockIdx.x, bm = blockIdx.y;
    const int w = tid >> 6, l = tid & 63, rl = l & 15, q = l >> 4, q8 = q * 8;
    const int srow = tid >> 2, koff = (tid & 3) * 16;
    const int brw = bm * 64 + srow;

    const u16* hp = h_base + (size_t)brw * h_lda + koff;
    size_t xrow;
    if (mode == 0)      xrow = ((size_t)brw * N_ + t) * E_;
    else if (mode == 1) xrow = (size_t)brw * E_;
    else                xrow = ((size_t)brw * N_ + (size_t)y[brw * N_ + t - 1]) * E_;
    const u16* xp = x_base + xrow + koff;

    const int wrow = (srow >> 4) * 512 + bn * 16 + (srow & 15);
    const u16* whp = Whh + (size_t)wrow * H_ + koff;
    const u16* wip = Wih + (size_t)wrow * E_ + koff;

    float bsum[4];
#pragma unroll
    for (int g = 0; g < 4; ++g) {
        int col = g * 512 + bn * 16 + rl;
        bsum[g] = bf2f(bih[col]) + bf2f(bhh[col]);
    }

    f32x4 acc[4];
#pragma unroll
    for (int g = 0; g < 4; ++g) acc[g] = (f32x4){0.f, 0.f, 0.f, 0.f};

    auto srcA = [&](int c) -> const u16* {
        return (c < 8) ? (hp + c * 64) : (xp + (c - 8) * 64);
    };
    auto srcB = [&](int c) -> const u16* {
        return (c < 8) ? (whp + c * 64) : (wip + (c - 8) * 64);
    };

    uint4 a00, a01, a10, a11, a20, a21;      // named, never indexed
    uint4 b00, b01, b10, b11, b20, b21;
    {
        const u16* sa0 = srcA(0); const u16* sa1 = srcA(1); const u16* sa2 = srcA(2);
        const u16* sb0 = srcB(0); const u16* sb1 = srcB(1); const u16* sb2 = srcB(2);
        a00 = *(const uint4*)sa0; a01 = *(const uint4*)(sa0 + 8);
        a10 = *(const uint4*)sa1; a11 = *(const uint4*)(sa1 + 8);
        a20 = *(const uint4*)sa2; a21 = *(const uint4*)(sa2 + 8);
        b00 = *(const uint4*)sb0; b01 = *(const uint4*)(sb0 + 8);
        b10 = *(const uint4*)sb1; b11 = *(const uint4*)(sb1 + 8);
        b20 = *(const uint4*)sb2; b21 = *(const uint4*)(sb2 + 8);
    }

    short* asw0 = &As[srow * 72 + koff];
    short* asw1 = asw0 + TSZ_;
    short* asw2 = asw0 + 2 * TSZ_;
    short* bsw0 = &Bs[srow * 72 + koff];
    short* bsw1 = bsw0 + TSZ_;
    short* bsw2 = bsw0 + 2 * TSZ_;
    const short* arp = &As[(w * 16 + rl) * 72 + q8];

    for (int it = 0; it < 4; ++it) {
        __syncthreads();
        *(uint4*)asw0 = a00;  *(uint4*)(asw0 + 8) = a01;
        *(uint4*)asw1 = a10;  *(uint4*)(asw1 + 8) = a11;
        *(uint4*)asw2 = a20;  *(uint4*)(asw2 + 8) = a21;
        *(uint4*)bsw0 = b00;  *(uint4*)(bsw0 + 8) = b01;
        *(uint4*)bsw1 = b10;  *(uint4*)(bsw1 + 8) = b11;
        *(uint4*)bsw2 = b20;  *(uint4*)(bsw2 + 8) = b21;
        __syncthreads();
        if (it + 1 < 4) {
            const int c0 = 3 * it + 3;
            const u16* sa0 = srcA(c0);     const u16* sa1 = srcA(c0 + 1);
            const u16* sa2 = srcA(c0 + 2);
            const u16* sb0 = srcB(c0);     const u16* sb1 = srcB(c0 + 1);
            const u16* sb2 = srcB(c0 + 2);
            a00 = *(const uint4*)sa0; a01 = *(const uint4*)(sa0 + 8);
            a10 = *(const uint4*)sa1; a11 = *(const uint4*)(sa1 + 8);
            a20 = *(const uint4*)sa2; a21 = *(const uint4*)(sa2 + 8);
            b00 = *(const uint4*)sb0; b01 = *(const uint4*)(sb0 + 8);
            b10 = *(const uint4*)sb1; b11 = *(const uint4*)(sb1 + 8);
            b20 = *(const uint4*)sb2; b21 = *(const uint4*)(sb2 + 8);
        }
        // chunks in ascending k order; per chunk same MFMA sequence as fused3
#pragma unroll
        for (int s = 0; s < 3; ++s) {
            const int so = s * TSZ_;
            bf16x8 af0 = *(const bf16x8*)(arp + so);
            bf16x8 af1 = *(const bf16x8*)(arp + so + 32);
#pragma unroll
            for (int g = 0; g < 4; ++g) {
                const short* brp = &Bs[so + (g * 16 + rl) * 72 + q8];
                bf16x8 bb0 = *(const bf16x8*)brp;
                bf16x8 bb1 = *(const bf16x8*)(brp + 32);
                acc[g] = mfma16(af0, bb0, acc[g]);
                acc[g] = mfma16(af1, bb1, acc[g]);
            }
        }
    }

    const int hcol = bn * 16 + rl;
#pragma unroll
    for (int r = 0; r < 4; ++r) {
        int brow = bm * 64 + w * 16 + q * 4 + r;
        float gi = acc[0][r] + bsum[0];
        float gf = acc[1][r] + bsum[1];
        float gg = acc[2][r] + bsum[2];
        float go = acc[3][r] + bsum[3];
        size_t cidx = (size_t)brow * H_ + hcol;
        float cv = sig_f(gf) * cbuf[cidx] + sig_f(gi) * tanh_f(gg);
        cbuf[cidx] = cv;
        hout[(size_t)brow * (N_ * H_) + hcol] = f2bf(sig_f(go) * tanh_f(cv));
    }
}

// ---------------------------------------------------------------------------
// Head GEMM (R3-proven structure): C = A @ Bw^T + bias, 64x64 tile, BK=32.
__global__ __launch_bounds__(256) void gemm_bt_kernel(
    const u16* __restrict__ A, int lda,
    const u16* __restrict__ Bw,
    const u16* __restrict__ bias,
    u16* __restrict__ C, int ldc, int K)
{
    __shared__ __align__(16) short As[64 * 40];
    __shared__ __align__(16) short Bs[64 * 40];
    const int tid = threadIdx.x;
    const int bn = blockIdx.x, bm = blockIdx.y;
    const int srow = tid >> 2, koff = (tid & 3) * 8;
    const size_t aBase = (size_t)(bm * 64 + srow) * lda + koff;
    const size_t bBase = (size_t)(bn * 64 + srow) * K + koff;
    const int NKT = K >> 5;
    uint4 aReg = *(const uint4*)(A + aBase);
    uint4 bReg = *(const uint4*)(Bw + bBase);
    const int w = tid >> 6, l = tid & 63;
    const int wm = w & 1, wn = w >> 1;
    const int rl = l & 15, q8 = (l >> 4) * 8;
    f32x4 acc00 = {0.f,0.f,0.f,0.f}, acc01 = {0.f,0.f,0.f,0.f};
    f32x4 acc10 = {0.f,0.f,0.f,0.f}, acc11 = {0.f,0.f,0.f,0.f};
    short* asw = &As[srow * 40 + koff];
    short* bsw = &Bs[srow * 40 + koff];
    const short* ar0 = &As[(wm * 32 + rl) * 40 + q8];
    const short* ar1 = &As[(wm * 32 + 16 + rl) * 40 + q8];
    const short* br0 = &Bs[(wn * 32 + rl) * 40 + q8];
    const short* br1 = &Bs[(wn * 32 + 16 + rl) * 40 + q8];
    for (int kt = 0; kt < NKT; ++kt) {
        __syncthreads();
        *(uint4*)asw = aReg;
        *(uint4*)bsw = bReg;
        __syncthreads();
        if (kt + 1 < NKT) {
            aReg = *(const uint4*)(A + aBase + (kt + 1) * 32);
            bReg = *(const uint4*)(Bw + bBase + (kt + 1) * 32);
        }
        bf16x8 a0 = *(const bf16x8*)ar0;
        bf16x8 a1 = *(const bf16x8*)ar1;
        bf16x8 b0 = *(const bf16x8*)br0;
        bf16x8 b1 = *(const bf16x8*)br1;
        acc00 = mfma16(a0, b0, acc00);
        acc01 = mfma16(a0, b1, acc01);
        acc10 = mfma16(a1, b0, acc10);
        acc11 = mfma16(a1, b1, acc11);
    }
    const int col0 = bn * 64 + wn * 32 + rl;
    const int row0 = bm * 64 + wm * 32 + (l >> 4) * 4;
    const float bv0 = bias ? bf2f(bias[col0]) : 0.f;
    const float bv1 = bias ? bf2f(bias[col0 + 16]) : 0.f;
#pragma unroll
    for (int r = 0; r < 4; ++r) {
        C[(size_t)(row0 + r) * ldc + col0]           = f2h_bits(acc00[r] + bv0);
        C[(size_t)(row0 + r) * ldc + col0 + 16]      = f2h_bits(acc01[r] + bv1);
        C[(size_t)(row0 + 16 + r) * ldc + col0]      = f2h_bits(acc10[r] + bv0);
        C[(size_t)(row0 + 16 + r) * ldc + col0 + 16] = f2h_bits(acc11[r] + bv1);
    }
}

// ---------------------------------------------------------------------------
// Glimpse v8: v7 16-lane-group scoring + 1-deep register prefetch on the
// u2g row loads (R9 diagnosis: latency-bound, not VALU-bound) and on the
// PV ref rows. Same values/order => bit-identical numerics vs v7.
__global__ __launch_bounds__(256) void glimpse_kernel(
    const u16* __restrict__ q1, const u16* __restrict__ u2g,
    const u16* __restrict__ ref, const u16* __restrict__ Vec,
    const unsigned char* __restrict__ mask, u16* __restrict__ query2)
{
    const int bt = blockIdx.x, b = bt / N_;
    const int tid = threadIdx.x, w = tid >> 6, l = tid & 63;
    const int g16 = l >> 4, l16 = l & 15;
    __shared__ float u_s[N_], a_s[N_], red[8];
    __shared__ short list[N_];
    __shared__ int wcnt[2], cnt_s;
    __shared__ __align__(16) float pv_s[4][H_];   // 8 KB PV partials
    const int h32 = l16 * 32;                     // scoring slice (16 lanes/n)
    const int h0 = l * 8;                         // PV slice (64 lanes)
    // ---- preload q and Vec 32-elem slices (scoring) ----
    h2 qh[16], vh[16];
    {
        const u16* qp = q1 + (size_t)bt * H_ + h32;
        toh2x4(*(const uint4*)qp,        qh);
        toh2x4(*(const uint4*)(qp + 8),  qh + 4);
        toh2x4(*(const uint4*)(qp + 16), qh + 8);
        toh2x4(*(const uint4*)(qp + 24), qh + 12);
        const u16* vp = Vec + h32;
#pragma unroll
        for (int m = 0; m < 4; ++m) {
            float vf[8]; unpack8(*(const uint4*)(vp + m * 8), vf);
#pragma unroll
            for (int j = 0; j < 4; ++j)
                vh[m * 4 + j] = (h2){ (f16t)vf[2 * j], (f16t)vf[2 * j + 1] };
        }
    }
    bool un = false;
    if (tid < N_) {
        un = (mask[(size_t)bt * N_ + tid] == 0);
        u_s[tid] = -3.0e38f;                 // init ALL entries (R6 scar)
    }
    unsigned long long bal = __ballot(un);
    if (l == 0 && w < 2) wcnt[w] = __popcll(bal);
    __syncthreads();
    const int base = (w == 1) ? wcnt[0] : 0;
    const int pos = __popcll(bal & ((1ULL << l) - 1ULL));
    if (un) list[base + pos] = (short)tid;
    if (tid == 0) cnt_s = wcnt[0] + wcnt[1];
    __syncthreads();
    const int cnt = cnt_s;
    const u16* ub = u2g + (size_t)b * N_ * H_;
    // ---- scoring: group (w,g16) handles k = w*4+g16 (mod 16), 1-deep PF ----
    {
        const int kstart = w * 4 + g16;
        uint4 cu0, cu1, cu2, cu3;
        if (kstart < cnt) {
            const u16* up = ub + (size_t)list[kstart] * H_ + h32;
            cu0 = *(const uint4*)up;        cu1 = *(const uint4*)(up + 8);
            cu2 = *(const uint4*)(up + 16); cu3 = *(const uint4*)(up + 24);
        }
        for (int k = kstart; k < cnt; k += 16) {
            uint4 nu0, nu1, nu2, nu3;
            const int kn = k + 16;
            if (kn < cnt) {                      // group-uniform guard
                const u16* up = ub + (size_t)list[kn] * H_ + h32;
                nu0 = *(const uint4*)up;        nu1 = *(const uint4*)(up + 8);
                nu2 = *(const uint4*)(up + 16); nu3 = *(const uint4*)(up + 24);
            }
            h2 uh[16];
            toh2x4(cu0, uh); toh2x4(cu1, uh + 4);
            toh2x4(cu2, uh + 8); toh2x4(cu3, uh + 12);
            float sa = 0.f, sb = 0.f, sc = 0.f, sd = 0.f;
#pragma unroll
            for (int j = 0; j < 4; ++j) {
                sa = tanhdot_h2(uh[j],      qh[j],      vh[j],      sa);
                sb = tanhdot_h2(uh[4 + j],  qh[4 + j],  vh[4 + j],  sb);
                sc = tanhdot_h2(uh[8 + j],  qh[8 + j],  vh[8 + j],  sc);
                sd = tanhdot_h2(uh[12 + j], qh[12 + j], vh[12 + j], sd);
            }
            float s = (sa + sb) + (sc + sd);
#pragma unroll
            for (int off = 8; off > 0; off >>= 1) s += __shfl_xor(s, off, 64);
            if (l16 == 0) u_s[list[k]] = s;
            cu0 = nu0; cu1 = nu1; cu2 = nu2; cu3 = nu3;
        }
    }
    __syncthreads();
    float v = un ? u_s[tid] : -3.0e38f;
    float m = v;
#pragma unroll
    for (int off = 32; off > 0; off >>= 1) m = fmaxf(m, __shfl_xor(m, off, 64));
    if (l == 0) red[w] = m;
    __syncthreads();
    float mx = fmaxf(fmaxf(red[0], red[1]), fmaxf(red[2], red[3]));
    float e = un ? __expf(v - mx) : 0.f;
    float s2 = e;
#pragma unroll
    for (int off = 32; off > 0; off >>= 1) s2 += __shfl_xor(s2, off, 64);
    if (l == 0) red[4 + w] = s2;
    __syncthreads();
    float inv = __fdividef(1.f, red[4] + red[5] + red[6] + red[7]);
    if (tid < N_) a_s[tid] = e * inv;
    __syncthreads();
    // ---- PV split-k with 1-deep prefetch: wave w sums k == w (mod 4) ----
    const u16* refb = ref + (size_t)b * N_ * H_;
    float pacc[8] = {0.f, 0.f, 0.f, 0.f, 0.f, 0.f, 0.f, 0.f};
    {
        uint4 cr; float ca = 0.f;
        if (w < cnt) {
            const int n = list[w];
            cr = *(const uint4*)(refb + (size_t)n * H_ + h0);
            ca = a_s[n];
        }
        for (int k = w; k < cnt; k += 4) {
            uint4 nr; float na = 0.f;
            const int kn = k + 4;
            if (kn < cnt) {                      // wave-uniform guard
                const int n = list[kn];
                nr = *(const uint4*)(refb + (size_t)n * H_ + h0);
                na = a_s[n];
            }
            float rv[8];
            unpack8(cr, rv);
#pragma unroll
            for (int j = 0; j < 8; ++j) pacc[j] = fmaf(ca, rv[j], pacc[j]);
            cr = nr; ca = na;
        }
    }
    {
        float4 pa0 = {pacc[0], pacc[1], pacc[2], pacc[3]};
        float4 pa1 = {pacc[4], pacc[5], pacc[6], pacc[7]};
        *(float4*)&pv_s[w][h0]     = pa0;
        *(float4*)&pv_s[w][h0 + 4] = pa1;
    }
    __syncthreads();
    const int hh = tid * 2;
    float s0 = ((pv_s[0][hh]     + pv_s[1][hh])     + pv_s[2][hh])     + pv_s[3][hh];
    float s1 = ((pv_s[0][hh + 1] + pv_s[1][hh + 1]) + pv_s[2][hh + 1]) + pv_s[3][hh + 1];
    unsigned packed = ((unsigned)f2bf(s1) << 16) | (unsigned)f2bf(s0);
    *(unsigned*)(query2 + (size_t)bt * H_ + hh) = packed;
}

// Pointer head v7: 16-lane-group scoring + 1-deep register prefetch.
__global__ __launch_bounds__(256) void final_attn_kernel(
    const u16* __restrict__ q2, const u16* __restrict__ u2p,
    const u16* __restrict__ Vec2, const unsigned char* __restrict__ mask,
    const int* __restrict__ y, float* __restrict__ ll, float* __restrict__ ps)
{
    const int bt = blockIdx.x, b = bt / N_;
    const int tid = threadIdx.x, w = tid >> 6, l = tid & 63;
    const int g16 = l >> 4, l16 = l & 15;
    __shared__ float u_s[N_], lp_s[N_], red[8];
    __shared__ short list[N_];
    __shared__ unsigned char msk[128];
    __shared__ int wcnt[2], cnt_s;
    const int h32 = l16 * 32;
    h2 qh[16], vh[16];
    {
        const u16* qp = q2 + (size_t)bt * H_ + h32;
        toh2x4(*(const uint4*)qp,        qh);
        toh2x4(*(const uint4*)(qp + 8),  qh + 4);
        toh2x4(*(const uint4*)(qp + 16), qh + 8);
        toh2x4(*(const uint4*)(qp + 24), qh + 12);
        const u16* vp = Vec2 + h32;
#pragma unroll
        for (int m = 0; m < 4; ++m) {
            float vf[8]; unpack8(*(const uint4*)(vp + m * 8), vf);
#pragma unroll
            for (int j = 0; j < 4; ++j)
                vh[m * 4 + j] = (h2){ (f16t)vf[2 * j], (f16t)vf[2 * j + 1] };
        }
    }
    bool un = false;
    if (tid < 128) msk[tid] = (tid < N_) ? mask[(size_t)bt * N_ + tid] : 1;
    if (tid < N_) {
        un = (msk[tid] == 0);
        u_s[tid] = 0.f;
    }
    unsigned long long bal = __ballot(un);
    if (l == 0 && w < 2) wcnt[w] = __popcll(bal);
    __syncthreads();
    const int base = (w == 1) ? wcnt[0] : 0;
    const int pos = __popcll(bal & ((1ULL << l) - 1ULL));
    if (un) list[base + pos] = (short)tid;
    if (tid == 0) cnt_s = wcnt[0] + wcnt[1];
    __syncthreads();
    const int cnt = cnt_s;
    const u16* ub = u2p + (size_t)b * N_ * H_;
    {
        const int kstart = w * 4 + g16;
        uint4 cu0, cu1, cu2, cu3;
        if (kstart < cnt) {
            const u16* up = ub + (size_t)list[kstart] * H_ + h32;
            cu0 = *(const uint4*)up;        cu1 = *(const uint4*)(up + 8);
            cu2 = *(const uint4*)(up + 16); cu3 = *(const uint4*)(up + 24);
        }
        for (int k = kstart; k < cnt; k += 16) {
            uint4 nu0, nu1, nu2, nu3;
            const int kn = k + 16;
            if (kn < cnt) {
                const u16* up = ub + (size_t)list[kn] * H_ + h32;
                nu0 = *(const uint4*)up;        nu1 = *(const uint4*)(up + 8);
                nu2 = *(const uint4*)(up + 16); nu3 = *(const uint4*)(up + 24);
            }
            h2 uh[16];
            toh2x4(cu0, uh); toh2x4(cu1, uh + 4);
            toh2x4(cu2, uh + 8); toh2x4(cu3, uh + 12);
            float sa = 0.f, sb = 0.f, sc = 0.f, sd = 0.f;
#pragma unroll
            for (int j = 0; j < 4; ++j) {
                sa = tanhdot_h2(uh[j],      qh[j],      vh[j],      sa);
                sb = tanhdot_h2(uh[4 + j],  qh[4 + j],  vh[4 + j],  sb);
                sc = tanhdot_h2(uh[8 + j],  qh[8 + j],  vh[8 + j],  sc);
                sd = tanhdot_h2(uh[12 + j], qh[12 + j], vh[12 + j], sd);
            }
            float s = (sa + sb) + (sc + sd);
#pragma unroll
            for (int off = 8; off > 0; off >>= 1) s += __shfl_xor(s, off, 64);
            if (l16 == 0) u_s[list[k]] = s;
            cu0 = nu0; cu1 = nu1; cu2 = nu2; cu3 = nu3;
        }
    }
    __syncthreads();
    float lg = -3.0e38f;
    if (tid < N_) {
        unsigned char c = msk[tid];
        if (c) lg = -1e8f * (float)c;
        else   lg = 10.f * tanh_poly(u_s[tid]);
    }
    float m = lg;
#pragma unroll
    for (int off = 32; off > 0; off >>= 1) m = fmaxf(m, __shfl_xor(m, off, 64));
    if (l == 0) red[w] = m;
    __syncthreads();
    float mx = fmaxf(fmaxf(red[0], red[1]), fmaxf(red[2], red[3]));
    float e = (tid < N_) ? __expf(lg - mx) : 0.f;
    float s2 = e;
#pragma unroll
    for (int off = 32; off > 0; off >>= 1) s2 += __shfl_xor(s2, off, 64);
    if (l == 0) red[4 + w] = s2;
    __syncthreads();
    float lse = mx + __logf(red[4] + red[5] + red[6] + red[7]);
    if (tid < N_) {
        float lp = lg - lse;
        ps[(size_t)bt * N_ + tid] = lp;
        lp_s[tid] = lp;
    }
    __syncthreads();
    if (tid == 0) atomicAdd(&ll[b], lp_s[y[bt]]);
}

// outputs (float32): pi = float(y); ll from f32 accumulator
__global__ void write_out_kernel(const int* __restrict__ y, const float* __restrict__ ll,
                                 float* __restrict__ out) {
    int i = blockIdx.x * 256 + threadIdx.x;   // 51200 threads
    if (i < BT_) out[i] = (float)y[i];
    if (i < B_)  out[BT_ + i] = ll[i];
}

// ---------------------------------------------------------------------------
extern "C" void kernel_launch(void* const* d_in, const int* in_sizes, int n_in,
                              void* d_out, int out_size, void* d_ws, size_t ws_size,
                              hipStream_t stream)
{
    const u16* x        = (const u16*)d_in[0];
    const int* y        = (const int*)d_in[1];
    const u16* emb_W    = (const u16*)d_in[2];
    const u16* enc_Wih  = (const u16*)d_in[3];
    const u16* enc_Whh  = (const u16*)d_in[4];
    const u16* enc_bih  = (const u16*)d_in[5];
    const u16* enc_bhh  = (const u16*)d_in[6];
    const u16* dec_Wih  = (const u16*)d_in[7];
    const u16* dec_Whh  = (const u16*)d_in[8];
    const u16* dec_bih  = (const u16*)d_in[9];
    const u16* dec_bhh  = (const u16*)d_in[10];
    const u16* Vec      = (const u16*)d_in[11];
    const u16* Vec2     = (const u16*)d_in[12];
    const u16* Wq_W     = (const u16*)d_in[13];
    const u16* Wq_b     = (const u16*)d_in[14];
    const u16* Wref_W   = (const u16*)d_in[15];
    const u16* Wref_b   = (const u16*)d_in[16];
    const u16* Wq2_W    = (const u16*)d_in[17];
    const u16* Wq2_b    = (const u16*)d_in[18];
    const u16* Wref2_W  = (const u16*)d_in[19];
    const u16* Wref2_b  = (const u16*)d_in[20];
    const u16* dec0     = (const u16*)d_in[21];

    char* p = (char*)d_ws;
    auto carve = [&](size_t bytes) -> char* {
        char* r = p; p += (bytes + 255) & ~(size_t)255; return r;
    };
    u16*   embed     = (u16*)  carve((size_t)BT_ * E_ * 2);      // 26.21 MB
    float* cbuf      = (float*)carve((size_t)B_ * H_ * 4);       //  1.05 MB
    u16*   zero_h    = (u16*)  carve((size_t)B_ * H_ * 2);       //  0.52 MB
    u16*   dec0_rows = (u16*)  carve((size_t)B_ * E_ * 2);       //  0.26 MB
    u16*   ref       = (u16*)  carve((size_t)BT_ * H_ * 2);      // 52.43 MB
    u16*   dec_hs    = (u16*)  carve((size_t)BT_ * H_ * 2);      // 52.43 MB (later: qry2)
    unsigned char* maskb = (unsigned char*)carve((size_t)BT_ * N_); // 5.12 MB
    float* llb       = (float*)carve((size_t)B_ * 4);
    const size_t need = (size_t)(p - (char*)d_ws);
    u16* Ybuf = embed;                                  // u2g / u2p chunk (f16)
    u16* Zbuf = embed + (size_t)BC_ * N_ * H_;          // q1 / q2 chunk (f16)

    if (need > ws_size) {
        sentinel_kernel<<<(B_ + 255) / 256, 256, 0, stream>>>((float*)d_out);
        return;
    }

    init_kernel<<<(B_ * H_) / 256, 256, 0, stream>>>(cbuf, zero_h, llb, dec0_rows, dec0);
    embed_kernel<<<BT_, 256, 0, stream>>>(x, emb_W, embed);
    mask_kernel<<<B_, 128, 0, stream>>>(y, maskb);

    // ---- LSTM steps: multi-launch, fused7 (BK=192, 8 barriers/step) ----
    dim3 sgrid(32, 8);   // hc tiles x batch tiles
    for (int t = 0; t < N_; ++t) {
        const u16* hb = (t == 0) ? zero_h : (ref + (size_t)(t - 1) * H_);
        int hlda = (t == 0) ? H_ : (N_ * H_);
        fused7_step_kernel<<<sgrid, 256, 0, stream>>>(hb, hlda, embed, y,
                                                      enc_Whh, enc_Wih, enc_bih, enc_bhh,
                                                      cbuf, ref + (size_t)t * H_, 0, t);
    }
    for (int t = 0; t < N_; ++t) {
        const u16* hb = (t == 0) ? (ref + (size_t)(N_ - 1) * H_) : (dec_hs + (size_t)(t - 1) * H_);
        const u16* xb = (t == 0) ? dec0_rows : embed;
        int mode = (t == 0) ? 1 : 2;
        fused7_step_kernel<<<sgrid, 256, 0, stream>>>(hb, N_ * H_, xb, y,
                                                      dec_Whh, dec_Wih, dec_bih, dec_bhh,
                                                      cbuf, dec_hs + (size_t)t * H_, mode, t);
    }

    // ---- batched attention, chunked over batch (embed now dead) ----
    float* out = (float*)d_out;
    const int MC = BC_ * N_;                     // 12800 rows per chunk
    dim3 cgrid(H_ / 64, MC / 64);                // (8, 200)
    for (int c = 0; c < NCHUNK_; ++c) {
        const size_t rowOff = (size_t)c * BC_ * N_ * H_;
        const size_t btOff  = (size_t)c * BC_ * N_;
        gemm_bt_kernel<<<cgrid, 256, 0, stream>>>(dec_hs + rowOff, H_, Wq_W,  Wq_b,  Zbuf, H_, H_);
        gemm_bt_kernel<<<cgrid, 256, 0, stream>>>(ref + rowOff,    H_, Wref_W, Wref_b, Ybuf, H_, H_);
        glimpse_kernel<<<MC, 256, 0, stream>>>(Zbuf, Ybuf, ref + rowOff, Vec,
                                               maskb + btOff * N_, dec_hs + rowOff);
        gemm_bt_kernel<<<cgrid, 256, 0, stream>>>(dec_hs + rowOff, H_, Wq2_W, Wq2_b, Zbuf, H_, H_);
        gemm_bt_kernel<<<cgrid, 256, 0, stream>>>(ref + rowOff,    H_, Wref2_W, Wref2_b, Ybuf, H_, H_);
        final_attn_kernel<<<MC, 256, 0, stream>>>(Zbuf, Ybuf, Vec2, maskb + btOff * N_,
                                                  y + btOff, llb + (size_t)c * BC_,
                                                  out + BT_ + B_ + btOff * N_);
    }
    write_out_kernel<<<BT_ / 256, 256, 0, stream>>>(y, llb, out);
}

// Round 11
// 3005.929 us; speedup vs baseline: 1.0674x; 1.0674x over previous
//
#include <hip/hip_runtime.h>
#include <hip/hip_bf16.h>
#include <stdint.h>

typedef unsigned short u16;
typedef __bf16 bf16t;
typedef _Float16 f16t;
typedef __attribute__((ext_vector_type(8))) bf16t bf16x8;
typedef __attribute__((ext_vector_type(4))) float f32x4;
typedef __attribute__((ext_vector_type(2))) _Float16 h2;

#define B_   512
#define N_   100
#define P_   20
#define E_   256
#define H_   512
#define G4H_ 2048
#define BT_  (B_ * N_)   // 51200
#define BC_  128         // phase-B batch chunk
#define NCHUNK_ (B_ / BC_)
#define TSZ_ 4608        // 64*72 shorts per LDS tile chunk (9216 B)

__device__ __forceinline__ float bfu2f(unsigned u) {
    union { unsigned i; float f; } v; v.i = u << 16; return v.f;
}
__device__ __forceinline__ float bf2f(u16 x) { return bfu2f((unsigned)x); }
__device__ __forceinline__ u16 f2bf(float f) {
    union { float f; unsigned i; } v; v.f = f;
    unsigned r = v.i + 0x7FFFu + ((v.i >> 16) & 1u);
    return (u16)(r >> 16);
}
__device__ __forceinline__ u16 f2h_bits(float f) {
    union { f16t h; u16 u; } c; c.h = (f16t)f; return c.u;
}
__device__ __forceinline__ void unpack8(uint4 r, float* o) {
    o[0] = bfu2f(r.x & 0xffffu); o[1] = bfu2f(r.x >> 16);
    o[2] = bfu2f(r.y & 0xffffu); o[3] = bfu2f(r.y >> 16);
    o[4] = bfu2f(r.z & 0xffffu); o[5] = bfu2f(r.z >> 16);
    o[6] = bfu2f(r.w & 0xffffu); o[7] = bfu2f(r.w >> 16);
}
__device__ __forceinline__ void toh2x4(uint4 r, h2* o) {
    union { uint4 u; h2 h[4]; } c; c.u = r;
    o[0] = c.h[0]; o[1] = c.h[1]; o[2] = c.h[2]; o[3] = c.h[3];
}
__device__ __forceinline__ float tanh_f(float x) {
    x = fminf(15.f, fmaxf(-15.f, x));
    float e = __expf(2.f * x);
    return __fdividef(e - 1.f, e + 1.f);
}
__device__ __forceinline__ float sig_f(float x) {
    x = fminf(15.f, fmaxf(-15.f, x));
    return __fdividef(1.f, 1.f + __expf(-x));
}
// f32 polynomial tanh (clamped both ends) — used on the per-n final logit only
__device__ __forceinline__ float tanh_poly(float x) {
    x = fminf(3.25f, fmaxf(-3.25f, x));
    float z = x * x;
    float p = fmaf(fmaf(fmaf(-0.0018661f, z, 0.037231f), z, -0.249208f), z, 0.984238f);
    float r = x * p;
    return fminf(1.0f, fmaxf(-1.0f, r));
}
// packed-f16 tanh-dot step: s += dot2(vh, tanh_pk(qh + uh)).
__device__ __forceinline__ float tanhdot_h2(h2 uh, h2 qh, h2 vh, float s) {
    const h2 kLo = { (f16t)-3.25f, (f16t)-3.25f };
    const h2 kHi = { (f16t)3.25f,  (f16t)3.25f };
    const h2 c3 = { (f16t)-0.0018661f, (f16t)-0.0018661f };
    const h2 c2 = { (f16t)0.037231f,   (f16t)0.037231f };
    const h2 c1 = { (f16t)-0.249208f,  (f16t)-0.249208f };
    const h2 c0 = { (f16t)0.984238f,   (f16t)0.984238f };
    h2 t = uh + qh;
    t = __builtin_elementwise_max(t, kLo);
    t = __builtin_elementwise_min(t, kHi);
    h2 z = t * t;
    h2 p = __builtin_elementwise_fma(c3, z, c2);
    p = __builtin_elementwise_fma(p, z, c1);
    p = __builtin_elementwise_fma(p, z, c0);
    h2 r = t * p;
#if defined(__has_builtin) && __has_builtin(__builtin_amdgcn_fdot2)
    return __builtin_amdgcn_fdot2(r, vh, s, false);
#else
    return s + (float)r.x * (float)vh.x + (float)r.y * (float)vh.y;
#endif
}
__device__ __forceinline__ f32x4 mfma16(bf16x8 a, bf16x8 b, f32x4 c) {
    return __builtin_amdgcn_mfma_f32_16x16x32_bf16(a, b, c, 0, 0, 0);
}

// ---------------------------------------------------------------------------
__global__ void sentinel_kernel(float* out) {
    int i = blockIdx.x * 256 + threadIdx.x;
    if (i < B_) out[BT_ + i] = 1.0e9f;   // signals "workspace too small"
}

// init: zero c, zero_h, ll; broadcast dec_input0 rows
__global__ void init_kernel(float* c, u16* zero_h, float* ll, u16* dec0_rows,
                            const u16* __restrict__ dec0) {
    int i = blockIdx.x * 256 + threadIdx.x;          // 262144 threads
    if (i < B_ * H_) { c[i] = 0.f; zero_h[i] = 0; }
    if (i < B_) ll[i] = 0.f;
    if (i < B_ * E_) dec0_rows[i] = dec0[i & (E_ - 1)];
}

// embed[b,n,e] = sum_p x[b,n,p] * emb_W[e,p]
__global__ void embed_kernel(const u16* __restrict__ x, const u16* __restrict__ emb_W,
                             u16* __restrict__ embed) {
    __shared__ float xs[P_];
    int bt = blockIdx.x, tid = threadIdx.x;
    if (tid < P_) xs[tid] = bf2f(x[(size_t)bt * P_ + tid]);
    __syncthreads();
    float s = 0.f;
#pragma unroll
    for (int p = 0; p < P_; ++p) s += xs[p] * bf2f(emb_W[tid * P_ + p]);
    embed[(size_t)bt * E_ + tid] = f2bf(s);
}

// mask[b,t,n] = #{s<t : y[b,s]==n}   (cumulative COUNT, y may repeat)
__global__ void mask_kernel(const int* __restrict__ y, unsigned char* __restrict__ mask) {
    int b = blockIdx.x, n = threadIdx.x;
    if (n >= N_) return;
    unsigned char cnt = 0;
    for (int t = 0; t < N_; ++t) {
        mask[((size_t)b * N_ + t) * N_ + n] = cnt;
        if (y[b * N_ + t] == n) cnt++;
    }
}

// ---------------------------------------------------------------------------
// Fused LSTM step v8: fused7 (BK=192, 4 K-iters, 8 barriers) + DEPTH-2
// register prefetch, fully unrolled. Loads for iteration it+2 are issued at
// iteration it (2 compute phases + barriers to land, vs 1 in fused7) — named
// register sets X/Y alternate, no arrays/runtime indexing/divergent guards.
// MFMA order per accumulator unchanged (chunks 0..11 ascending) =>
// bit-identical numerics vs fused7/fused3.
#define LOADSET(c0, A0,A1,A2,A3,A4,A5,B0,B1,B2,B3,B4,B5) do { \
    const u16* sa0_ = srcA(c0); const u16* sa1_ = srcA((c0)+1); const u16* sa2_ = srcA((c0)+2); \
    const u16* sb0_ = srcB(c0); const u16* sb1_ = srcB((c0)+1); const u16* sb2_ = srcB((c0)+2); \
    A0 = *(const uint4*)sa0_; A1 = *(const uint4*)(sa0_ + 8); \
    A2 = *(const uint4*)sa1_; A3 = *(const uint4*)(sa1_ + 8); \
    A4 = *(const uint4*)sa2_; A5 = *(const uint4*)(sa2_ + 8); \
    B0 = *(const uint4*)sb0_; B1 = *(const uint4*)(sb0_ + 8); \
    B2 = *(const uint4*)sb1_; B3 = *(const uint4*)(sb1_ + 8); \
    B4 = *(const uint4*)sb2_; B5 = *(const uint4*)(sb2_ + 8); \
} while(0)

#define WRITESET(A0,A1,A2,A3,A4,A5,B0,B1,B2,B3,B4,B5) do { \
    *(uint4*)asw0 = A0;  *(uint4*)(asw0 + 8) = A1; \
    *(uint4*)asw1 = A2;  *(uint4*)(asw1 + 8) = A3; \
    *(uint4*)asw2 = A4;  *(uint4*)(asw2 + 8) = A5; \
    *(uint4*)bsw0 = B0;  *(uint4*)(bsw0 + 8) = B1; \
    *(uint4*)bsw1 = B2;  *(uint4*)(bsw1 + 8) = B3; \
    *(uint4*)bsw2 = B4;  *(uint4*)(bsw2 + 8) = B5; \
} while(0)

#define COMPUTE3() do { \
    _Pragma("unroll") \
    for (int s_ = 0; s_ < 3; ++s_) { \
        const int so_ = s_ * TSZ_; \
        bf16x8 af0_ = *(const bf16x8*)(arp + so_); \
        bf16x8 af1_ = *(const bf16x8*)(arp + so_ + 32); \
        _Pragma("unroll") \
        for (int g_ = 0; g_ < 4; ++g_) { \
            const short* brp_ = &Bs[so_ + (g_ * 16 + rl) * 72 + q8]; \
            bf16x8 bb0_ = *(const bf16x8*)brp_; \
            bf16x8 bb1_ = *(const bf16x8*)(brp_ + 32); \
            acc[g_] = mfma16(af0_, bb0_, acc[g_]); \
            acc[g_] = mfma16(af1_, bb1_, acc[g_]); \
        } \
    } \
} while(0)

__global__ __launch_bounds__(256) void fused8_step_kernel(
    const u16* __restrict__ h_base, int h_lda,
    const u16* __restrict__ x_base,
    const int* __restrict__ y,
    const u16* __restrict__ Whh, const u16* __restrict__ Wih,
    const u16* __restrict__ bih, const u16* __restrict__ bhh,
    float* __restrict__ cbuf,
    u16* __restrict__ hout,
    int mode, int t)
{
    __shared__ __align__(16) short As[3 * TSZ_];   // chunk slots 0|1|2
    __shared__ __align__(16) short Bs[3 * TSZ_];
    const int tid = threadIdx.x;
    const int bn = blockIdx.x, bm = blockIdx.y;
    const int w = tid >> 6, l = tid & 63, rl = l & 15, q = l >> 4, q8 = q * 8;
    const int srow = tid >> 2, koff = (tid & 3) * 16;
    const int brw = bm * 64 + srow;

    const u16* hp = h_base + (size_t)brw * h_lda + koff;
    size_t xrow;
    if (mode == 0)      xrow = ((size_t)brw * N_ + t) * E_;
    else if (mode == 1) xrow = (size_t)brw * E_;
    else                xrow = ((size_t)brw * N_ + (size_t)y[brw * N_ + t - 1]) * E_;
    const u16* xp = x_base + xrow + koff;

    const int wrow = (srow >> 4) * 512 + bn * 16 + (srow & 15);
    const u16* whp = Whh + (size_t)wrow * H_ + koff;
    const u16* wip = Wih + (size_t)wrow * E_ + koff;

    float bsum[4];
#pragma unroll
    for (int g = 0; g < 4; ++g) {
        int col = g * 512 + bn * 16 + rl;
        bsum[g] = bf2f(bih[col]) + bf2f(bhh[col]);
    }

    f32x4 acc[4];
#pragma unroll
    for (int g = 0; g < 4; ++g) acc[g] = (f32x4){0.f, 0.f, 0.f, 0.f};

    auto srcA = [&](int c) -> const u16* {
        return (c < 8) ? (hp + c * 64) : (xp + (c - 8) * 64);
    };
    auto srcB = [&](int c) -> const u16* {
        return (c < 8) ? (whp + c * 64) : (wip + (c - 8) * 64);
    };

    short* asw0 = &As[srow * 72 + koff];
    short* asw1 = asw0 + TSZ_;
    short* asw2 = asw0 + 2 * TSZ_;
    short* bsw0 = &Bs[srow * 72 + koff];
    short* bsw1 = bsw0 + TSZ_;
    short* bsw2 = bsw0 + 2 * TSZ_;
    const short* arp = &As[(w * 16 + rl) * 72 + q8];

    // named register sets X (even its) and Y (odd its)
    uint4 xa0, xa1, xa2, xa3, xa4, xa5, xb0, xb1, xb2, xb3, xb4, xb5;
    uint4 ya0, ya1, ya2, ya3, ya4, ya5, yb0, yb1, yb2, yb3, yb4, yb5;

    // prologue: chunks 0-2 -> X, 3-5 -> Y  (depth 2)
    LOADSET(0, xa0,xa1,xa2,xa3,xa4,xa5, xb0,xb1,xb2,xb3,xb4,xb5);
    LOADSET(3, ya0,ya1,ya2,ya3,ya4,ya5, yb0,yb1,yb2,yb3,yb4,yb5);

    // it0: write X, refill X with chunks 6-8, compute
    __syncthreads();
    WRITESET(xa0,xa1,xa2,xa3,xa4,xa5, xb0,xb1,xb2,xb3,xb4,xb5);
    __syncthreads();
    LOADSET(6, xa0,xa1,xa2,xa3,xa4,xa5, xb0,xb1,xb2,xb3,xb4,xb5);
    COMPUTE3();
    // it1: write Y, refill Y with chunks 9-11, compute
    __syncthreads();
    WRITESET(ya0,ya1,ya2,ya3,ya4,ya5, yb0,yb1,yb2,yb3,yb4,yb5);
    __syncthreads();
    LOADSET(9, ya0,ya1,ya2,ya3,ya4,ya5, yb0,yb1,yb2,yb3,yb4,yb5);
    COMPUTE3();
    // it2: write X, compute
    __syncthreads();
    WRITESET(xa0,xa1,xa2,xa3,xa4,xa5, xb0,xb1,xb2,xb3,xb4,xb5);
    __syncthreads();
    COMPUTE3();
    // it3: write Y, compute
    __syncthreads();
    WRITESET(ya0,ya1,ya2,ya3,ya4,ya5, yb0,yb1,yb2,yb3,yb4,yb5);
    __syncthreads();
    COMPUTE3();

    const int hcol = bn * 16 + rl;
#pragma unroll
    for (int r = 0; r < 4; ++r) {
        int brow = bm * 64 + w * 16 + q * 4 + r;
        float gi = acc[0][r] + bsum[0];
        float gf = acc[1][r] + bsum[1];
        float gg = acc[2][r] + bsum[2];
        float go = acc[3][r] + bsum[3];
        size_t cidx = (size_t)brow * H_ + hcol;
        float cv = sig_f(gf) * cbuf[cidx] + sig_f(gi) * tanh_f(gg);
        cbuf[cidx] = cv;
        hout[(size_t)brow * (N_ * H_) + hcol] = f2bf(sig_f(go) * tanh_f(cv));
    }
}

// ---------------------------------------------------------------------------
// Head GEMM (R3-proven structure): C = A @ Bw^T + bias, 64x64 tile, BK=32.
__global__ __launch_bounds__(256) void gemm_bt_kernel(
    const u16* __restrict__ A, int lda,
    const u16* __restrict__ Bw,
    const u16* __restrict__ bias,
    u16* __restrict__ C, int ldc, int K)
{
    __shared__ __align__(16) short As[64 * 40];
    __shared__ __align__(16) short Bs[64 * 40];
    const int tid = threadIdx.x;
    const int bn = blockIdx.x, bm = blockIdx.y;
    const int srow = tid >> 2, koff = (tid & 3) * 8;
    const size_t aBase = (size_t)(bm * 64 + srow) * lda + koff;
    const size_t bBase = (size_t)(bn * 64 + srow) * K + koff;
    const int NKT = K >> 5;
    uint4 aReg = *(const uint4*)(A + aBase);
    uint4 bReg = *(const uint4*)(Bw + bBase);
    const int w = tid >> 6, l = tid & 63;
    const int wm = w & 1, wn = w >> 1;
    const int rl = l & 15, q8 = (l >> 4) * 8;
    f32x4 acc00 = {0.f,0.f,0.f,0.f}, acc01 = {0.f,0.f,0.f,0.f};
    f32x4 acc10 = {0.f,0.f,0.f,0.f}, acc11 = {0.f,0.f,0.f,0.f};
    short* asw = &As[srow * 40 + koff];
    short* bsw = &Bs[srow * 40 + koff];
    const short* ar0 = &As[(wm * 32 + rl) * 40 + q8];
    const short* ar1 = &As[(wm * 32 + 16 + rl) * 40 + q8];
    const short* br0 = &Bs[(wn * 32 + rl) * 40 + q8];
    const short* br1 = &Bs[(wn * 32 + 16 + rl) * 40 + q8];
    for (int kt = 0; kt < NKT; ++kt) {
        __syncthreads();
        *(uint4*)asw = aReg;
        *(uint4*)bsw = bReg;
        __syncthreads();
        if (kt + 1 < NKT) {
            aReg = *(const uint4*)(A + aBase + (kt + 1) * 32);
            bReg = *(const uint4*)(Bw + bBase + (kt + 1) * 32);
        }
        bf16x8 a0 = *(const bf16x8*)ar0;
        bf16x8 a1 = *(const bf16x8*)ar1;
        bf16x8 b0 = *(const bf16x8*)br0;
        bf16x8 b1 = *(const bf16x8*)br1;
        acc00 = mfma16(a0, b0, acc00);
        acc01 = mfma16(a0, b1, acc01);
        acc10 = mfma16(a1, b0, acc10);
        acc11 = mfma16(a1, b1, acc11);
    }
    const int col0 = bn * 64 + wn * 32 + rl;
    const int row0 = bm * 64 + wm * 32 + (l >> 4) * 4;
    const float bv0 = bias ? bf2f(bias[col0]) : 0.f;
    const float bv1 = bias ? bf2f(bias[col0 + 16]) : 0.f;
#pragma unroll
    for (int r = 0; r < 4; ++r) {
        C[(size_t)(row0 + r) * ldc + col0]           = f2h_bits(acc00[r] + bv0);
        C[(size_t)(row0 + r) * ldc + col0 + 16]      = f2h_bits(acc01[r] + bv1);
        C[(size_t)(row0 + 16 + r) * ldc + col0]      = f2h_bits(acc10[r] + bv0);
        C[(size_t)(row0 + 16 + r) * ldc + col0 + 16] = f2h_bits(acc11[r] + bv1);
    }
}

// ---------------------------------------------------------------------------
// Glimpse v7 (verified R9): 16-lane-per-n group scoring, 4 n's per wave,
// 32 elems/lane, 4 independent accumulators, 4-level group reduce; PV
// split-k across waves with uint4 loads + LDS partial reduce.
__global__ __launch_bounds__(256) void glimpse_kernel(
    const u16* __restrict__ q1, const u16* __restrict__ u2g,
    const u16* __restrict__ ref, const u16* __restrict__ Vec,
    const unsigned char* __restrict__ mask, u16* __restrict__ query2)
{
    const int bt = blockIdx.x, b = bt / N_;
    const int tid = threadIdx.x, w = tid >> 6, l = tid & 63;
    const int g16 = l >> 4, l16 = l & 15;
    __shared__ float u_s[N_], a_s[N_], red[8];
    __shared__ short list[N_];
    __shared__ int wcnt[2], cnt_s;
    __shared__ __align__(16) float pv_s[4][H_];   // 8 KB PV partials
    const int h32 = l16 * 32;                     // scoring slice (16 lanes/n)
    const int h0 = l * 8;                         // PV slice (64 lanes)
    // ---- preload q and Vec 32-elem slices (scoring) ----
    h2 qh[16], vh[16];
    {
        const u16* qp = q1 + (size_t)bt * H_ + h32;
        toh2x4(*(const uint4*)qp,        qh);
        toh2x4(*(const uint4*)(qp + 8),  qh + 4);
        toh2x4(*(const uint4*)(qp + 16), qh + 8);
        toh2x4(*(const uint4*)(qp + 24), qh + 12);
        const u16* vp = Vec + h32;
#pragma unroll
        for (int m = 0; m < 4; ++m) {
            float vf[8]; unpack8(*(const uint4*)(vp + m * 8), vf);
#pragma unroll
            for (int j = 0; j < 4; ++j)
                vh[m * 4 + j] = (h2){ (f16t)vf[2 * j], (f16t)vf[2 * j + 1] };
        }
    }
    bool un = false;
    if (tid < N_) {
        un = (mask[(size_t)bt * N_ + tid] == 0);
        u_s[tid] = -3.0e38f;                 // init ALL entries (R6 scar)
    }
    unsigned long long bal = __ballot(un);
    if (l == 0 && w < 2) wcnt[w] = __popcll(bal);
    __syncthreads();
    const int base = (w == 1) ? wcnt[0] : 0;
    const int pos = __popcll(bal & ((1ULL << l) - 1ULL));
    if (un) list[base + pos] = (short)tid;
    if (tid == 0) cnt_s = wcnt[0] + wcnt[1];
    __syncthreads();
    const int cnt = cnt_s;
    const u16* ub = u2g + (size_t)b * N_ * H_;
    // ---- scoring: group (w,g16) handles k = w*4+g16 (mod 16) ----
    for (int k = w * 4 + g16; k < cnt; k += 16) {
        const int n = list[k];
        const u16* up = ub + (size_t)n * H_ + h32;
        h2 uh[16];
        toh2x4(*(const uint4*)up,        uh);
        toh2x4(*(const uint4*)(up + 8),  uh + 4);
        toh2x4(*(const uint4*)(up + 16), uh + 8);
        toh2x4(*(const uint4*)(up + 24), uh + 12);
        float sa = 0.f, sb = 0.f, sc = 0.f, sd = 0.f;
#pragma unroll
        for (int j = 0; j < 4; ++j) {
            sa = tanhdot_h2(uh[j],      qh[j],      vh[j],      sa);
            sb = tanhdot_h2(uh[4 + j],  qh[4 + j],  vh[4 + j],  sb);
            sc = tanhdot_h2(uh[8 + j],  qh[8 + j],  vh[8 + j],  sc);
            sd = tanhdot_h2(uh[12 + j], qh[12 + j], vh[12 + j], sd);
        }
        float s = (sa + sb) + (sc + sd);
#pragma unroll
        for (int off = 8; off > 0; off >>= 1) s += __shfl_xor(s, off, 64);
        if (l16 == 0) u_s[n] = s;
    }
    __syncthreads();
    float v = un ? u_s[tid] : -3.0e38f;
    float m = v;
#pragma unroll
    for (int off = 32; off > 0; off >>= 1) m = fmaxf(m, __shfl_xor(m, off, 64));
    if (l == 0) red[w] = m;
    __syncthreads();
    float mx = fmaxf(fmaxf(red[0], red[1]), fmaxf(red[2], red[3]));
    float e = un ? __expf(v - mx) : 0.f;
    float s2 = e;
#pragma unroll
    for (int off = 32; off > 0; off >>= 1) s2 += __shfl_xor(s2, off, 64);
    if (l == 0) red[4 + w] = s2;
    __syncthreads();
    float inv = __fdividef(1.f, red[4] + red[5] + red[6] + red[7]);
    if (tid < N_) a_s[tid] = e * inv;
    __syncthreads();
    // ---- PV split-k: wave w sums k == w (mod 4); lane owns h0..h0+7 ----
    const u16* refb = ref + (size_t)b * N_ * H_;
    float pacc[8] = {0.f, 0.f, 0.f, 0.f, 0.f, 0.f, 0.f, 0.f};
    for (int k = w; k < cnt; k += 4) {
        const int n = list[k];
        const float a = a_s[n];
        float rv[8];
        unpack8(*(const uint4*)(refb + (size_t)n * H_ + h0), rv);
#pragma unroll
        for (int j = 0; j < 8; ++j) pacc[j] = fmaf(a, rv[j], pacc[j]);
    }
    {
        float4 pa0 = {pacc[0], pacc[1], pacc[2], pacc[3]};
        float4 pa1 = {pacc[4], pacc[5], pacc[6], pacc[7]};
        *(float4*)&pv_s[w][h0]     = pa0;
        *(float4*)&pv_s[w][h0 + 4] = pa1;
    }
    __syncthreads();
    const int hh = tid * 2;
    float s0 = ((pv_s[0][hh]     + pv_s[1][hh])     + pv_s[2][hh])     + pv_s[3][hh];
    float s1 = ((pv_s[0][hh + 1] + pv_s[1][hh + 1]) + pv_s[2][hh + 1]) + pv_s[3][hh + 1];
    unsigned packed = ((unsigned)f2bf(s1) << 16) | (unsigned)f2bf(s0);
    *(unsigned*)(query2 + (size_t)bt * H_ + hh) = packed;
}

// Pointer head v6 (verified R9): 16-lane-per-n group scoring (no PV here).
__global__ __launch_bounds__(256) void final_attn_kernel(
    const u16* __restrict__ q2, const u16* __restrict__ u2p,
    const u16* __restrict__ Vec2, const unsigned char* __restrict__ mask,
    const int* __restrict__ y, float* __restrict__ ll, float* __restrict__ ps)
{
    const int bt = blockIdx.x, b = bt / N_;
    const int tid = threadIdx.x, w = tid >> 6, l = tid & 63;
    const int g16 = l >> 4, l16 = l & 15;
    __shared__ float u_s[N_], lp_s[N_], red[8];
    __shared__ short list[N_];
    __shared__ unsigned char msk[128];
    __shared__ int wcnt[2], cnt_s;
    const int h32 = l16 * 32;
    h2 qh[16], vh[16];
    {
        const u16* qp = q2 + (size_t)bt * H_ + h32;
        toh2x4(*(const uint4*)qp,        qh);
        toh2x4(*(const uint4*)(qp + 8),  qh + 4);
        toh2x4(*(const uint4*)(qp + 16), qh + 8);
        toh2x4(*(const uint4*)(qp + 24), qh + 12);
        const u16* vp = Vec2 + h32;
#pragma unroll
        for (int m = 0; m < 4; ++m) {
            float vf[8]; unpack8(*(const uint4*)(vp + m * 8), vf);
#pragma unroll
            for (int j = 0; j < 4; ++j)
                vh[m * 4 + j] = (h2){ (f16t)vf[2 * j], (f16t)vf[2 * j + 1] };
        }
    }
    bool un = false;
    if (tid < 128) msk[tid] = (tid < N_) ? mask[(size_t)bt * N_ + tid] : 1;
    if (tid < N_) {
        un = (msk[tid] == 0);
        u_s[tid] = 0.f;
    }
    unsigned long long bal = __ballot(un);
    if (l == 0 && w < 2) wcnt[w] = __popcll(bal);
    __syncthreads();
    const int base = (w == 1) ? wcnt[0] : 0;
    const int pos = __popcll(bal & ((1ULL << l) - 1ULL));
    if (un) list[base + pos] = (short)tid;
    if (tid == 0) cnt_s = wcnt[0] + wcnt[1];
    __syncthreads();
    const int cnt = cnt_s;
    const u16* ub = u2p + (size_t)b * N_ * H_;
    for (int k = w * 4 + g16; k < cnt; k += 16) {
        const int n = list[k];
        const u16* up = ub + (size_t)n * H_ + h32;
        h2 uh[16];
        toh2x4(*(const uint4*)up,        uh);
        toh2x4(*(const uint4*)(up + 8),  uh + 4);
        toh2x4(*(const uint4*)(up + 16), uh + 8);
        toh2x4(*(const uint4*)(up + 24), uh + 12);
        float sa = 0.f, sb = 0.f, sc = 0.f, sd = 0.f;
#pragma unroll
        for (int j = 0; j < 4; ++j) {
            sa = tanhdot_h2(uh[j],      qh[j],      vh[j],      sa);
            sb = tanhdot_h2(uh[4 + j],  qh[4 + j],  vh[4 + j],  sb);
            sc = tanhdot_h2(uh[8 + j],  qh[8 + j],  vh[8 + j],  sc);
            sd = tanhdot_h2(uh[12 + j], qh[12 + j], vh[12 + j], sd);
        }
        float s = (sa + sb) + (sc + sd);
#pragma unroll
        for (int off = 8; off > 0; off >>= 1) s += __shfl_xor(s, off, 64);
        if (l16 == 0) u_s[n] = s;
    }
    __syncthreads();
    float lg = -3.0e38f;
    if (tid < N_) {
        unsigned char c = msk[tid];
        if (c) lg = -1e8f * (float)c;
        else   lg = 10.f * tanh_poly(u_s[tid]);
    }
    float m = lg;
#pragma unroll
    for (int off = 32; off > 0; off >>= 1) m = fmaxf(m, __shfl_xor(m, off, 64));
    if (l == 0) red[w] = m;
    __syncthreads();
    float mx = fmaxf(fmaxf(red[0], red[1]), fmaxf(red[2], red[3]));
    float e = (tid < N_) ? __expf(lg - mx) : 0.f;
    float s2 = e;
#pragma unroll
    for (int off = 32; off > 0; off >>= 1) s2 += __shfl_xor(s2, off, 64);
    if (l == 0) red[4 + w] = s2;
    __syncthreads();
    float lse = mx + __logf(red[4] + red[5] + red[6] + red[7]);
    if (tid < N_) {
        float lp = lg - lse;
        ps[(size_t)bt * N_ + tid] = lp;
        lp_s[tid] = lp;
    }
    __syncthreads();
    if (tid == 0) atomicAdd(&ll[b], lp_s[y[bt]]);
}

// outputs (float32): pi = float(y); ll from f32 accumulator
__global__ void write_out_kernel(const int* __restrict__ y, const float* __restrict__ ll,
                                 float* __restrict__ out) {
    int i = blockIdx.x * 256 + threadIdx.x;   // 51200 threads
    if (i < BT_) out[i] = (float)y[i];
    if (i < B_)  out[BT_ + i] = ll[i];
}

// ---------------------------------------------------------------------------
extern "C" void kernel_launch(void* const* d_in, const int* in_sizes, int n_in,
                              void* d_out, int out_size, void* d_ws, size_t ws_size,
                              hipStream_t stream)
{
    const u16* x        = (const u16*)d_in[0];
    const int* y        = (const int*)d_in[1];
    const u16* emb_W    = (const u16*)d_in[2];
    const u16* enc_Wih  = (const u16*)d_in[3];
    const u16* enc_Whh  = (const u16*)d_in[4];
    const u16* enc_bih  = (const u16*)d_in[5];
    const u16* enc_bhh  = (const u16*)d_in[6];
    const u16* dec_Wih  = (const u16*)d_in[7];
    const u16* dec_Whh  = (const u16*)d_in[8];
    const u16* dec_bih  = (const u16*)d_in[9];
    const u16* dec_bhh  = (const u16*)d_in[10];
    const u16* Vec      = (const u16*)d_in[11];
    const u16* Vec2     = (const u16*)d_in[12];
    const u16* Wq_W     = (const u16*)d_in[13];
    const u16* Wq_b     = (const u16*)d_in[14];
    const u16* Wref_W   = (const u16*)d_in[15];
    const u16* Wref_b   = (const u16*)d_in[16];
    const u16* Wq2_W    = (const u16*)d_in[17];
    const u16* Wq2_b    = (const u16*)d_in[18];
    const u16* Wref2_W  = (const u16*)d_in[19];
    const u16* Wref2_b  = (const u16*)d_in[20];
    const u16* dec0     = (const u16*)d_in[21];

    char* p = (char*)d_ws;
    auto carve = [&](size_t bytes) -> char* {
        char* r = p; p += (bytes + 255) & ~(size_t)255; return r;
    };
    u16*   embed     = (u16*)  carve((size_t)BT_ * E_ * 2);      // 26.21 MB
    float* cbuf      = (float*)carve((size_t)B_ * H_ * 4);       //  1.05 MB
    u16*   zero_h    = (u16*)  carve((size_t)B_ * H_ * 2);       //  0.52 MB
    u16*   dec0_rows = (u16*)  carve((size_t)B_ * E_ * 2);       //  0.26 MB
    u16*   ref       = (u16*)  carve((size_t)BT_ * H_ * 2);      // 52.43 MB
    u16*   dec_hs    = (u16*)  carve((size_t)BT_ * H_ * 2);      // 52.43 MB (later: qry2)
    unsigned char* maskb = (unsigned char*)carve((size_t)BT_ * N_); // 5.12 MB
    float* llb       = (float*)carve((size_t)B_ * 4);
    const size_t need = (size_t)(p - (char*)d_ws);
    u16* Ybuf = embed;                                  // u2g / u2p chunk (f16)
    u16* Zbuf = embed + (size_t)BC_ * N_ * H_;          // q1 / q2 chunk (f16)

    if (need > ws_size) {
        sentinel_kernel<<<(B_ + 255) / 256, 256, 0, stream>>>((float*)d_out);
        return;
    }

    init_kernel<<<(B_ * H_) / 256, 256, 0, stream>>>(cbuf, zero_h, llb, dec0_rows, dec0);
    embed_kernel<<<BT_, 256, 0, stream>>>(x, emb_W, embed);
    mask_kernel<<<B_, 128, 0, stream>>>(y, maskb);

    // ---- LSTM steps: multi-launch, fused8 (BK=192, depth-2 prefetch) ----
    dim3 sgrid(32, 8);   // hc tiles x batch tiles
    for (int t = 0; t < N_; ++t) {
        const u16* hb = (t == 0) ? zero_h : (ref + (size_t)(t - 1) * H_);
        int hlda = (t == 0) ? H_ : (N_ * H_);
        fused8_step_kernel<<<sgrid, 256, 0, stream>>>(hb, hlda, embed, y,
                                                      enc_Whh, enc_Wih, enc_bih, enc_bhh,
                                                      cbuf, ref + (size_t)t * H_, 0, t);
    }
    for (int t = 0; t < N_; ++t) {
        const u16* hb = (t == 0) ? (ref + (size_t)(N_ - 1) * H_) : (dec_hs + (size_t)(t - 1) * H_);
        const u16* xb = (t == 0) ? dec0_rows : embed;
        int mode = (t == 0) ? 1 : 2;
        fused8_step_kernel<<<sgrid, 256, 0, stream>>>(hb, N_ * H_, xb, y,
                                                      dec_Whh, dec_Wih, dec_bih, dec_bhh,
                                                      cbuf, dec_hs + (size_t)t * H_, mode, t);
    }

    // ---- batched attention, chunked over batch (embed now dead) ----
    float* out = (float*)d_out;
    const int MC = BC_ * N_;                     // 12800 rows per chunk
    dim3 cgrid(H_ / 64, MC / 64);                // (8, 200)
    for (int c = 0; c < NCHUNK_; ++c) {
        const size_t rowOff = (size_t)c * BC_ * N_ * H_;
        const size_t btOff  = (size_t)c * BC_ * N_;
        gemm_bt_kernel<<<cgrid, 256, 0, stream>>>(dec_hs + rowOff, H_, Wq_W,  Wq_b,  Zbuf, H_, H_);
        gemm_bt_kernel<<<cgrid, 256, 0, stream>>>(ref + rowOff,    H_, Wref_W, Wref_b, Ybuf, H_, H_);
        glimpse_kernel<<<MC, 256, 0, stream>>>(Zbuf, Ybuf, ref + rowOff, Vec,
                                               maskb + btOff * N_, dec_hs + rowOff);
        gemm_bt_kernel<<<cgrid, 256, 0, stream>>>(dec_hs + rowOff, H_, Wq2_W, Wq2_b, Zbuf, H_, H_);
        gemm_bt_kernel<<<cgrid, 256, 0, stream>>>(ref + rowOff,    H_, Wref2_W, Wref2_b, Ybuf, H_, H_);
        final_attn_kernel<<<MC, 256, 0, stream>>>(Zbuf, Ybuf, Vec2, maskb + btOff * N_,
                                                  y + btOff, llb + (size_t)c * BC_,
                                                  out + BT_ + B_ + btOff * N_);
    }
    write_out_kernel<<<BT_ / 256, 256, 0, stream>>>(y, llb, out);
}

// Round 12
// 2940.288 us; speedup vs baseline: 1.0912x; 1.0223x over previous
//
#include <hip/hip_runtime.h>
#include <hip/hip_bf16.h>
#include <stdint.h>

typedef unsigned short u16;
typedef __bf16 bf16t;
typedef _Float16 f16t;
typedef __attribute__((ext_vector_type(8))) bf16t bf16x8;
typedef __attribute__((ext_vector_type(4))) float f32x4;
typedef __attribute__((ext_vector_type(2))) _Float16 h2;

#define B_   512
#define N_   100
#define P_   20
#define E_   256
#define H_   512
#define G4H_ 2048
#define BT_  (B_ * N_)   // 51200
#define BC_  128         // phase-B batch chunk
#define NCHUNK_ (B_ / BC_)
#define TSZ_ 4608        // 64*72 shorts per LDS tile chunk (9216 B)

__device__ __forceinline__ float bfu2f(unsigned u) {
    union { unsigned i; float f; } v; v.i = u << 16; return v.f;
}
__device__ __forceinline__ float bf2f(u16 x) { return bfu2f((unsigned)x); }
__device__ __forceinline__ u16 f2bf(float f) {
    union { float f; unsigned i; } v; v.f = f;
    unsigned r = v.i + 0x7FFFu + ((v.i >> 16) & 1u);
    return (u16)(r >> 16);
}
__device__ __forceinline__ u16 f2h_bits(float f) {
    union { f16t h; u16 u; } c; c.h = (f16t)f; return c.u;
}
__device__ __forceinline__ void unpack8(uint4 r, float* o) {
    o[0] = bfu2f(r.x & 0xffffu); o[1] = bfu2f(r.x >> 16);
    o[2] = bfu2f(r.y & 0xffffu); o[3] = bfu2f(r.y >> 16);
    o[4] = bfu2f(r.z & 0xffffu); o[5] = bfu2f(r.z >> 16);
    o[6] = bfu2f(r.w & 0xffffu); o[7] = bfu2f(r.w >> 16);
}
__device__ __forceinline__ void toh2x4(uint4 r, h2* o) {
    union { uint4 u; h2 h[4]; } c; c.u = r;
    o[0] = c.h[0]; o[1] = c.h[1]; o[2] = c.h[2]; o[3] = c.h[3];
}
__device__ __forceinline__ float tanh_f(float x) {
    x = fminf(15.f, fmaxf(-15.f, x));
    float e = __expf(2.f * x);
    return __fdividef(e - 1.f, e + 1.f);
}
__device__ __forceinline__ float sig_f(float x) {
    x = fminf(15.f, fmaxf(-15.f, x));
    return __fdividef(1.f, 1.f + __expf(-x));
}
// f32 polynomial tanh (clamped both ends) — used on the per-n final logit only
__device__ __forceinline__ float tanh_poly(float x) {
    x = fminf(3.25f, fmaxf(-3.25f, x));
    float z = x * x;
    float p = fmaf(fmaf(fmaf(-0.0018661f, z, 0.037231f), z, -0.249208f), z, 0.984238f);
    float r = x * p;
    return fminf(1.0f, fmaxf(-1.0f, r));
}
// packed-f16 tanh-dot step: s += dot2(vh, tanh_pk(qh + uh)).
__device__ __forceinline__ float tanhdot_h2(h2 uh, h2 qh, h2 vh, float s) {
    const h2 kLo = { (f16t)-3.25f, (f16t)-3.25f };
    const h2 kHi = { (f16t)3.25f,  (f16t)3.25f };
    const h2 c3 = { (f16t)-0.0018661f, (f16t)-0.0018661f };
    const h2 c2 = { (f16t)0.037231f,   (f16t)0.037231f };
    const h2 c1 = { (f16t)-0.249208f,  (f16t)-0.249208f };
    const h2 c0 = { (f16t)0.984238f,   (f16t)0.984238f };
    h2 t = uh + qh;
    t = __builtin_elementwise_max(t, kLo);
    t = __builtin_elementwise_min(t, kHi);
    h2 z = t * t;
    h2 p = __builtin_elementwise_fma(c3, z, c2);
    p = __builtin_elementwise_fma(p, z, c1);
    p = __builtin_elementwise_fma(p, z, c0);
    h2 r = t * p;
#if defined(__has_builtin) && __has_builtin(__builtin_amdgcn_fdot2)
    return __builtin_amdgcn_fdot2(r, vh, s, false);
#else
    return s + (float)r.x * (float)vh.x + (float)r.y * (float)vh.y;
#endif
}
__device__ __forceinline__ f32x4 mfma16(bf16x8 a, bf16x8 b, f32x4 c) {
    return __builtin_amdgcn_mfma_f32_16x16x32_bf16(a, b, c, 0, 0, 0);
}

// ---------------------------------------------------------------------------
__global__ void sentinel_kernel(float* out) {
    int i = blockIdx.x * 256 + threadIdx.x;
    if (i < B_) out[BT_ + i] = 1.0e9f;   // signals "workspace too small"
}

// init: zero c, zero_h, ll; broadcast dec_input0 rows
__global__ void init_kernel(float* c, u16* zero_h, float* ll, u16* dec0_rows,
                            const u16* __restrict__ dec0) {
    int i = blockIdx.x * 256 + threadIdx.x;          // 262144 threads
    if (i < B_ * H_) { c[i] = 0.f; zero_h[i] = 0; }
    if (i < B_) ll[i] = 0.f;
    if (i < B_ * E_) dec0_rows[i] = dec0[i & (E_ - 1)];
}

// embed[b,n,e] = sum_p x[b,n,p] * emb_W[e,p]
__global__ void embed_kernel(const u16* __restrict__ x, const u16* __restrict__ emb_W,
                             u16* __restrict__ embed) {
    __shared__ float xs[P_];
    int bt = blockIdx.x, tid = threadIdx.x;
    if (tid < P_) xs[tid] = bf2f(x[(size_t)bt * P_ + tid]);
    __syncthreads();
    float s = 0.f;
#pragma unroll
    for (int p = 0; p < P_; ++p) s += xs[p] * bf2f(emb_W[tid * P_ + p]);
    embed[(size_t)bt * E_ + tid] = f2bf(s);
}

// mask[b,t,n] = #{s<t : y[b,s]==n}   (cumulative COUNT, y may repeat)
__global__ void mask_kernel(const int* __restrict__ y, unsigned char* __restrict__ mask) {
    int b = blockIdx.x, n = threadIdx.x;
    if (n >= N_) return;
    unsigned char cnt = 0;
    for (int t = 0; t < N_; ++t) {
        mask[((size_t)b * N_ + t) * N_ + n] = cnt;
        if (y[b * N_ + t] == n) cnt++;
    }
}

// ---------------------------------------------------------------------------
// Fused LSTM step v8 (verified R11): BK=192, 4 K-iters, 8 barriers, depth-2
// register prefetch (named sets X/Y), bit-identical numerics vs fused3.
#define LOADSET(c0, A0,A1,A2,A3,A4,A5,B0,B1,B2,B3,B4,B5) do { \
    const u16* sa0_ = srcA(c0); const u16* sa1_ = srcA((c0)+1); const u16* sa2_ = srcA((c0)+2); \
    const u16* sb0_ = srcB(c0); const u16* sb1_ = srcB((c0)+1); const u16* sb2_ = srcB((c0)+2); \
    A0 = *(const uint4*)sa0_; A1 = *(const uint4*)(sa0_ + 8); \
    A2 = *(const uint4*)sa1_; A3 = *(const uint4*)(sa1_ + 8); \
    A4 = *(const uint4*)sa2_; A5 = *(const uint4*)(sa2_ + 8); \
    B0 = *(const uint4*)sb0_; B1 = *(const uint4*)(sb0_ + 8); \
    B2 = *(const uint4*)sb1_; B3 = *(const uint4*)(sb1_ + 8); \
    B4 = *(const uint4*)sb2_; B5 = *(const uint4*)(sb2_ + 8); \
} while(0)

#define WRITESET(A0,A1,A2,A3,A4,A5,B0,B1,B2,B3,B4,B5) do { \
    *(uint4*)asw0 = A0;  *(uint4*)(asw0 + 8) = A1; \
    *(uint4*)asw1 = A2;  *(uint4*)(asw1 + 8) = A3; \
    *(uint4*)asw2 = A4;  *(uint4*)(asw2 + 8) = A5; \
    *(uint4*)bsw0 = B0;  *(uint4*)(bsw0 + 8) = B1; \
    *(uint4*)bsw1 = B2;  *(uint4*)(bsw1 + 8) = B3; \
    *(uint4*)bsw2 = B4;  *(uint4*)(bsw2 + 8) = B5; \
} while(0)

#define COMPUTE3() do { \
    _Pragma("unroll") \
    for (int s_ = 0; s_ < 3; ++s_) { \
        const int so_ = s_ * TSZ_; \
        bf16x8 af0_ = *(const bf16x8*)(arp + so_); \
        bf16x8 af1_ = *(const bf16x8*)(arp + so_ + 32); \
        _Pragma("unroll") \
        for (int g_ = 0; g_ < 4; ++g_) { \
            const short* brp_ = &Bs[so_ + (g_ * 16 + rl) * 72 + q8]; \
            bf16x8 bb0_ = *(const bf16x8*)brp_; \
            bf16x8 bb1_ = *(const bf16x8*)(brp_ + 32); \
            acc[g_] = mfma16(af0_, bb0_, acc[g_]); \
            acc[g_] = mfma16(af1_, bb1_, acc[g_]); \
        } \
    } \
} while(0)

__global__ __launch_bounds__(256) void fused8_step_kernel(
    const u16* __restrict__ h_base, int h_lda,
    const u16* __restrict__ x_base,
    const int* __restrict__ y,
    const u16* __restrict__ Whh, const u16* __restrict__ Wih,
    const u16* __restrict__ bih, const u16* __restrict__ bhh,
    float* __restrict__ cbuf,
    u16* __restrict__ hout,
    int mode, int t)
{
    __shared__ __align__(16) short As[3 * TSZ_];   // chunk slots 0|1|2
    __shared__ __align__(16) short Bs[3 * TSZ_];
    const int tid = threadIdx.x;
    const int bn = blockIdx.x, bm = blockIdx.y;
    const int w = tid >> 6, l = tid & 63, rl = l & 15, q = l >> 4, q8 = q * 8;
    const int srow = tid >> 2, koff = (tid & 3) * 16;
    const int brw = bm * 64 + srow;

    const u16* hp = h_base + (size_t)brw * h_lda + koff;
    size_t xrow;
    if (mode == 0)      xrow = ((size_t)brw * N_ + t) * E_;
    else if (mode == 1) xrow = (size_t)brw * E_;
    else                xrow = ((size_t)brw * N_ + (size_t)y[brw * N_ + t - 1]) * E_;
    const u16* xp = x_base + xrow + koff;

    const int wrow = (srow >> 4) * 512 + bn * 16 + (srow & 15);
    const u16* whp = Whh + (size_t)wrow * H_ + koff;
    const u16* wip = Wih + (size_t)wrow * E_ + koff;

    float bsum[4];
#pragma unroll
    for (int g = 0; g < 4; ++g) {
        int col = g * 512 + bn * 16 + rl;
        bsum[g] = bf2f(bih[col]) + bf2f(bhh[col]);
    }

    f32x4 acc[4];
#pragma unroll
    for (int g = 0; g < 4; ++g) acc[g] = (f32x4){0.f, 0.f, 0.f, 0.f};

    auto srcA = [&](int c) -> const u16* {
        return (c < 8) ? (hp + c * 64) : (xp + (c - 8) * 64);
    };
    auto srcB = [&](int c) -> const u16* {
        return (c < 8) ? (whp + c * 64) : (wip + (c - 8) * 64);
    };

    short* asw0 = &As[srow * 72 + koff];
    short* asw1 = asw0 + TSZ_;
    short* asw2 = asw0 + 2 * TSZ_;
    short* bsw0 = &Bs[srow * 72 + koff];
    short* bsw1 = bsw0 + TSZ_;
    short* bsw2 = bsw0 + 2 * TSZ_;
    const short* arp = &As[(w * 16 + rl) * 72 + q8];

    uint4 xa0, xa1, xa2, xa3, xa4, xa5, xb0, xb1, xb2, xb3, xb4, xb5;
    uint4 ya0, ya1, ya2, ya3, ya4, ya5, yb0, yb1, yb2, yb3, yb4, yb5;

    LOADSET(0, xa0,xa1,xa2,xa3,xa4,xa5, xb0,xb1,xb2,xb3,xb4,xb5);
    LOADSET(3, ya0,ya1,ya2,ya3,ya4,ya5, yb0,yb1,yb2,yb3,yb4,yb5);

    __syncthreads();
    WRITESET(xa0,xa1,xa2,xa3,xa4,xa5, xb0,xb1,xb2,xb3,xb4,xb5);
    __syncthreads();
    LOADSET(6, xa0,xa1,xa2,xa3,xa4,xa5, xb0,xb1,xb2,xb3,xb4,xb5);
    COMPUTE3();
    __syncthreads();
    WRITESET(ya0,ya1,ya2,ya3,ya4,ya5, yb0,yb1,yb2,yb3,yb4,yb5);
    __syncthreads();
    LOADSET(9, ya0,ya1,ya2,ya3,ya4,ya5, yb0,yb1,yb2,yb3,yb4,yb5);
    COMPUTE3();
    __syncthreads();
    WRITESET(xa0,xa1,xa2,xa3,xa4,xa5, xb0,xb1,xb2,xb3,xb4,xb5);
    __syncthreads();
    COMPUTE3();
    __syncthreads();
    WRITESET(ya0,ya1,ya2,ya3,ya4,ya5, yb0,yb1,yb2,yb3,yb4,yb5);
    __syncthreads();
    COMPUTE3();

    const int hcol = bn * 16 + rl;
#pragma unroll
    for (int r = 0; r < 4; ++r) {
        int brow = bm * 64 + w * 16 + q * 4 + r;
        float gi = acc[0][r] + bsum[0];
        float gf = acc[1][r] + bsum[1];
        float gg = acc[2][r] + bsum[2];
        float go = acc[3][r] + bsum[3];
        size_t cidx = (size_t)brow * H_ + hcol;
        float cv = sig_f(gf) * cbuf[cidx] + sig_f(gi) * tanh_f(gg);
        cbuf[cidx] = cv;
        hout[(size_t)brow * (N_ * H_) + hcol] = f2bf(sig_f(go) * tanh_f(cv));
    }
}

// ---------------------------------------------------------------------------
// Head GEMM (R3-proven structure): C = A @ Bw^T + bias, 64x64 tile, BK=32.
__global__ __launch_bounds__(256) void gemm_bt_kernel(
    const u16* __restrict__ A, int lda,
    const u16* __restrict__ Bw,
    const u16* __restrict__ bias,
    u16* __restrict__ C, int ldc, int K)
{
    __shared__ __align__(16) short As[64 * 40];
    __shared__ __align__(16) short Bs[64 * 40];
    const int tid = threadIdx.x;
    const int bn = blockIdx.x, bm = blockIdx.y;
    const int srow = tid >> 2, koff = (tid & 3) * 8;
    const size_t aBase = (size_t)(bm * 64 + srow) * lda + koff;
    const size_t bBase = (size_t)(bn * 64 + srow) * K + koff;
    const int NKT = K >> 5;
    uint4 aReg = *(const uint4*)(A + aBase);
    uint4 bReg = *(const uint4*)(Bw + bBase);
    const int w = tid >> 6, l = tid & 63;
    const int wm = w & 1, wn = w >> 1;
    const int rl = l & 15, q8 = (l >> 4) * 8;
    f32x4 acc00 = {0.f,0.f,0.f,0.f}, acc01 = {0.f,0.f,0.f,0.f};
    f32x4 acc10 = {0.f,0.f,0.f,0.f}, acc11 = {0.f,0.f,0.f,0.f};
    short* asw = &As[srow * 40 + koff];
    short* bsw = &Bs[srow * 40 + koff];
    const short* ar0 = &As[(wm * 32 + rl) * 40 + q8];
    const short* ar1 = &As[(wm * 32 + 16 + rl) * 40 + q8];
    const short* br0 = &Bs[(wn * 32 + rl) * 40 + q8];
    const short* br1 = &Bs[(wn * 32 + 16 + rl) * 40 + q8];
    for (int kt = 0; kt < NKT; ++kt) {
        __syncthreads();
        *(uint4*)asw = aReg;
        *(uint4*)bsw = bReg;
        __syncthreads();
        if (kt + 1 < NKT) {
            aReg = *(const uint4*)(A + aBase + (kt + 1) * 32);
            bReg = *(const uint4*)(Bw + bBase + (kt + 1) * 32);
        }
        bf16x8 a0 = *(const bf16x8*)ar0;
        bf16x8 a1 = *(const bf16x8*)ar1;
        bf16x8 b0 = *(const bf16x8*)br0;
        bf16x8 b1 = *(const bf16x8*)br1;
        acc00 = mfma16(a0, b0, acc00);
        acc01 = mfma16(a0, b1, acc01);
        acc10 = mfma16(a1, b0, acc10);
        acc11 = mfma16(a1, b1, acc11);
    }
    const int col0 = bn * 64 + wn * 32 + rl;
    const int row0 = bm * 64 + wm * 32 + (l >> 4) * 4;
    const float bv0 = bias ? bf2f(bias[col0]) : 0.f;
    const float bv1 = bias ? bf2f(bias[col0 + 16]) : 0.f;
#pragma unroll
    for (int r = 0; r < 4; ++r) {
        C[(size_t)(row0 + r) * ldc + col0]           = f2h_bits(acc00[r] + bv0);
        C[(size_t)(row0 + r) * ldc + col0 + 16]      = f2h_bits(acc01[r] + bv1);
        C[(size_t)(row0 + 16 + r) * ldc + col0]      = f2h_bits(acc10[r] + bv0);
        C[(size_t)(row0 + 16 + r) * ldc + col0 + 16] = f2h_bits(acc11[r] + bv1);
    }
}

// ---------------------------------------------------------------------------
// Glimpse v9: R9 structure at 128 threads (2 waves) — 16 blocks/CU max (was
// 8), fewer idle lanes in tid<N_ phases, cheaper barriers. Scoring: 8 groups
// of 16 lanes (stride 8), per-n math identical. PV split-k over 2 waves.
__global__ __launch_bounds__(128) void glimpse_kernel(
    const u16* __restrict__ q1, const u16* __restrict__ u2g,
    const u16* __restrict__ ref, const u16* __restrict__ Vec,
    const unsigned char* __restrict__ mask, u16* __restrict__ query2)
{
    const int bt = blockIdx.x, b = bt / N_;
    const int tid = threadIdx.x, w = tid >> 6, l = tid & 63;
    const int g16 = l >> 4, l16 = l & 15;
    __shared__ float u_s[N_], a_s[N_], red[4];
    __shared__ short list[N_];
    __shared__ int wcnt[2], cnt_s;
    __shared__ __align__(16) float pv_s[2][H_];   // 4 KB PV partials
    const int h32 = l16 * 32;                     // scoring slice (16 lanes/n)
    const int h0 = l * 8;                         // PV slice (64 lanes)
    // ---- preload q and Vec 32-elem slices (scoring) ----
    h2 qh[16], vh[16];
    {
        const u16* qp = q1 + (size_t)bt * H_ + h32;
        toh2x4(*(const uint4*)qp,        qh);
        toh2x4(*(const uint4*)(qp + 8),  qh + 4);
        toh2x4(*(const uint4*)(qp + 16), qh + 8);
        toh2x4(*(const uint4*)(qp + 24), qh + 12);
        const u16* vp = Vec + h32;
#pragma unroll
        for (int m = 0; m < 4; ++m) {
            float vf[8]; unpack8(*(const uint4*)(vp + m * 8), vf);
#pragma unroll
            for (int j = 0; j < 4; ++j)
                vh[m * 4 + j] = (h2){ (f16t)vf[2 * j], (f16t)vf[2 * j + 1] };
        }
    }
    bool un = false;
    if (tid < N_) {
        un = (mask[(size_t)bt * N_ + tid] == 0);
        u_s[tid] = -3.0e38f;                 // init ALL entries (R6 scar)
    }
    unsigned long long bal = __ballot(un);
    if (l == 0) wcnt[w] = __popcll(bal);
    __syncthreads();
    const int base = (w == 1) ? wcnt[0] : 0;
    const int pos = __popcll(bal & ((1ULL << l) - 1ULL));
    if (un) list[base + pos] = (short)tid;
    if (tid == 0) cnt_s = wcnt[0] + wcnt[1];
    __syncthreads();
    const int cnt = cnt_s;
    const u16* ub = u2g + (size_t)b * N_ * H_;
    // ---- scoring: group (w,g16) handles k = w*4+g16 (mod 8) ----
    for (int k = w * 4 + g16; k < cnt; k += 8) {
        const int n = list[k];
        const u16* up = ub + (size_t)n * H_ + h32;
        h2 uh[16];
        toh2x4(*(const uint4*)up,        uh);
        toh2x4(*(const uint4*)(up + 8),  uh + 4);
        toh2x4(*(const uint4*)(up + 16), uh + 8);
        toh2x4(*(const uint4*)(up + 24), uh + 12);
        float sa = 0.f, sb = 0.f, sc = 0.f, sd = 0.f;
#pragma unroll
        for (int j = 0; j < 4; ++j) {
            sa = tanhdot_h2(uh[j],      qh[j],      vh[j],      sa);
            sb = tanhdot_h2(uh[4 + j],  qh[4 + j],  vh[4 + j],  sb);
            sc = tanhdot_h2(uh[8 + j],  qh[8 + j],  vh[8 + j],  sc);
            sd = tanhdot_h2(uh[12 + j], qh[12 + j], vh[12 + j], sd);
        }
        float s = (sa + sb) + (sc + sd);
#pragma unroll
        for (int off = 8; off > 0; off >>= 1) s += __shfl_xor(s, off, 64);
        if (l16 == 0) u_s[n] = s;
    }
    __syncthreads();
    float v = un ? u_s[tid] : -3.0e38f;
    float m = v;
#pragma unroll
    for (int off = 32; off > 0; off >>= 1) m = fmaxf(m, __shfl_xor(m, off, 64));
    if (l == 0) red[w] = m;
    __syncthreads();
    float mx = fmaxf(red[0], red[1]);
    float e = un ? __expf(v - mx) : 0.f;
    float s2 = e;
#pragma unroll
    for (int off = 32; off > 0; off >>= 1) s2 += __shfl_xor(s2, off, 64);
    if (l == 0) red[2 + w] = s2;
    __syncthreads();
    float inv = __fdividef(1.f, red[2] + red[3]);
    if (tid < N_) a_s[tid] = e * inv;
    __syncthreads();
    // ---- PV split-k: wave w sums k == w (mod 2); lane owns h0..h0+7 ----
    const u16* refb = ref + (size_t)b * N_ * H_;
    float pacc[8] = {0.f, 0.f, 0.f, 0.f, 0.f, 0.f, 0.f, 0.f};
    for (int k = w; k < cnt; k += 2) {
        const int n = list[k];
        const float a = a_s[n];
        float rv[8];
        unpack8(*(const uint4*)(refb + (size_t)n * H_ + h0), rv);
#pragma unroll
        for (int j = 0; j < 8; ++j) pacc[j] = fmaf(a, rv[j], pacc[j]);
    }
    {
        float4 pa0 = {pacc[0], pacc[1], pacc[2], pacc[3]};
        float4 pa1 = {pacc[4], pacc[5], pacc[6], pacc[7]};
        *(float4*)&pv_s[w][h0]     = pa0;
        *(float4*)&pv_s[w][h0 + 4] = pa1;
    }
    __syncthreads();
    const int hh = tid * 4;                       // 128 threads x 4 elems
    float s0 = pv_s[0][hh]     + pv_s[1][hh];
    float s1 = pv_s[0][hh + 1] + pv_s[1][hh + 1];
    float s2b = pv_s[0][hh + 2] + pv_s[1][hh + 2];
    float s3 = pv_s[0][hh + 3] + pv_s[1][hh + 3];
    uint2 packed;
    packed.x = ((unsigned)f2bf(s1) << 16) | (unsigned)f2bf(s0);
    packed.y = ((unsigned)f2bf(s3) << 16) | (unsigned)f2bf(s2b);
    *(uint2*)(query2 + (size_t)bt * H_ + hh) = packed;
}

// Pointer head v8: R9 structure at 128 threads (2 waves), no PV here.
__global__ __launch_bounds__(128) void final_attn_kernel(
    const u16* __restrict__ q2, const u16* __restrict__ u2p,
    const u16* __restrict__ Vec2, const unsigned char* __restrict__ mask,
    const int* __restrict__ y, float* __restrict__ ll, float* __restrict__ ps)
{
    const int bt = blockIdx.x, b = bt / N_;
    const int tid = threadIdx.x, w = tid >> 6, l = tid & 63;
    const int g16 = l >> 4, l16 = l & 15;
    __shared__ float u_s[N_], lp_s[N_], red[4];
    __shared__ short list[N_];
    __shared__ unsigned char msk[128];
    __shared__ int wcnt[2], cnt_s;
    const int h32 = l16 * 32;
    h2 qh[16], vh[16];
    {
        const u16* qp = q2 + (size_t)bt * H_ + h32;
        toh2x4(*(const uint4*)qp,        qh);
        toh2x4(*(const uint4*)(qp + 8),  qh + 4);
        toh2x4(*(const uint4*)(qp + 16), qh + 8);
        toh2x4(*(const uint4*)(qp + 24), qh + 12);
        const u16* vp = Vec2 + h32;
#pragma unroll
        for (int m = 0; m < 4; ++m) {
            float vf[8]; unpack8(*(const uint4*)(vp + m * 8), vf);
#pragma unroll
            for (int j = 0; j < 4; ++j)
                vh[m * 4 + j] = (h2){ (f16t)vf[2 * j], (f16t)vf[2 * j + 1] };
        }
    }
    bool un = false;
    msk[tid] = (tid < N_) ? mask[(size_t)bt * N_ + tid] : 1;
    if (tid < N_) {
        un = (msk[tid] == 0);
        u_s[tid] = 0.f;
    }
    unsigned long long bal = __ballot(un);
    if (l == 0) wcnt[w] = __popcll(bal);
    __syncthreads();
    const int base = (w == 1) ? wcnt[0] : 0;
    const int pos = __popcll(bal & ((1ULL << l) - 1ULL));
    if (un) list[base + pos] = (short)tid;
    if (tid == 0) cnt_s = wcnt[0] + wcnt[1];
    __syncthreads();
    const int cnt = cnt_s;
    const u16* ub = u2p + (size_t)b * N_ * H_;
    for (int k = w * 4 + g16; k < cnt; k += 8) {
        const int n = list[k];
        const u16* up = ub + (size_t)n * H_ + h32;
        h2 uh[16];
        toh2x4(*(const uint4*)up,        uh);
        toh2x4(*(const uint4*)(up + 8),  uh + 4);
        toh2x4(*(const uint4*)(up + 16), uh + 8);
        toh2x4(*(const uint4*)(up + 24), uh + 12);
        float sa = 0.f, sb = 0.f, sc = 0.f, sd = 0.f;
#pragma unroll
        for (int j = 0; j < 4; ++j) {
            sa = tanhdot_h2(uh[j],      qh[j],      vh[j],      sa);
            sb = tanhdot_h2(uh[4 + j],  qh[4 + j],  vh[4 + j],  sb);
            sc = tanhdot_h2(uh[8 + j],  qh[8 + j],  vh[8 + j],  sc);
            sd = tanhdot_h2(uh[12 + j], qh[12 + j], vh[12 + j], sd);
        }
        float s = (sa + sb) + (sc + sd);
#pragma unroll
        for (int off = 8; off > 0; off >>= 1) s += __shfl_xor(s, off, 64);
        if (l16 == 0) u_s[n] = s;
    }
    __syncthreads();
    float lg = -3.0e38f;
    if (tid < N_) {
        unsigned char c = msk[tid];
        if (c) lg = -1e8f * (float)c;
        else   lg = 10.f * tanh_poly(u_s[tid]);
    }
    float m = lg;
#pragma unroll
    for (int off = 32; off > 0; off >>= 1) m = fmaxf(m, __shfl_xor(m, off, 64));
    if (l == 0) red[w] = m;
    __syncthreads();
    float mx = fmaxf(red[0], red[1]);
    float e = (tid < N_) ? __expf(lg - mx) : 0.f;
    float s2 = e;
#pragma unroll
    for (int off = 32; off > 0; off >>= 1) s2 += __shfl_xor(s2, off, 64);
    if (l == 0) red[2 + w] = s2;
    __syncthreads();
    float lse = mx + __logf(red[2] + red[3]);
    if (tid < N_) {
        float lp = lg - lse;
        ps[(size_t)bt * N_ + tid] = lp;
        lp_s[tid] = lp;
    }
    __syncthreads();
    if (tid == 0) atomicAdd(&ll[b], lp_s[y[bt]]);
}

// outputs (float32): pi = float(y); ll from f32 accumulator
__global__ void write_out_kernel(const int* __restrict__ y, const float* __restrict__ ll,
                                 float* __restrict__ out) {
    int i = blockIdx.x * 256 + threadIdx.x;   // 51200 threads
    if (i < BT_) out[i] = (float)y[i];
    if (i < B_)  out[BT_ + i] = ll[i];
}

// ---------------------------------------------------------------------------
extern "C" void kernel_launch(void* const* d_in, const int* in_sizes, int n_in,
                              void* d_out, int out_size, void* d_ws, size_t ws_size,
                              hipStream_t stream)
{
    const u16* x        = (const u16*)d_in[0];
    const int* y        = (const int*)d_in[1];
    const u16* emb_W    = (const u16*)d_in[2];
    const u16* enc_Wih  = (const u16*)d_in[3];
    const u16* enc_Whh  = (const u16*)d_in[4];
    const u16* enc_bih  = (const u16*)d_in[5];
    const u16* enc_bhh  = (const u16*)d_in[6];
    const u16* dec_Wih  = (const u16*)d_in[7];
    const u16* dec_Whh  = (const u16*)d_in[8];
    const u16* dec_bih  = (const u16*)d_in[9];
    const u16* dec_bhh  = (const u16*)d_in[10];
    const u16* Vec      = (const u16*)d_in[11];
    const u16* Vec2     = (const u16*)d_in[12];
    const u16* Wq_W     = (const u16*)d_in[13];
    const u16* Wq_b     = (const u16*)d_in[14];
    const u16* Wref_W   = (const u16*)d_in[15];
    const u16* Wref_b   = (const u16*)d_in[16];
    const u16* Wq2_W    = (const u16*)d_in[17];
    const u16* Wq2_b    = (const u16*)d_in[18];
    const u16* Wref2_W  = (const u16*)d_in[19];
    const u16* Wref2_b  = (const u16*)d_in[20];
    const u16* dec0     = (const u16*)d_in[21];

    char* p = (char*)d_ws;
    auto carve = [&](size_t bytes) -> char* {
        char* r = p; p += (bytes + 255) & ~(size_t)255; return r;
    };
    u16*   embed     = (u16*)  carve((size_t)BT_ * E_ * 2);      // 26.21 MB
    float* cbuf      = (float*)carve((size_t)B_ * H_ * 4);       //  1.05 MB
    u16*   zero_h    = (u16*)  carve((size_t)B_ * H_ * 2);       //  0.52 MB
    u16*   dec0_rows = (u16*)  carve((size_t)B_ * E_ * 2);       //  0.26 MB
    u16*   ref       = (u16*)  carve((size_t)BT_ * H_ * 2);      // 52.43 MB
    u16*   dec_hs    = (u16*)  carve((size_t)BT_ * H_ * 2);      // 52.43 MB (later: qry2)
    unsigned char* maskb = (unsigned char*)carve((size_t)BT_ * N_); // 5.12 MB
    float* llb       = (float*)carve((size_t)B_ * 4);
    const size_t need = (size_t)(p - (char*)d_ws);
    u16* Ybuf = embed;                                  // u2g / u2p chunk (f16)
    u16* Zbuf = embed + (size_t)BC_ * N_ * H_;          // q1 / q2 chunk (f16)

    if (need > ws_size) {
        sentinel_kernel<<<(B_ + 255) / 256, 256, 0, stream>>>((float*)d_out);
        return;
    }

    init_kernel<<<(B_ * H_) / 256, 256, 0, stream>>>(cbuf, zero_h, llb, dec0_rows, dec0);
    embed_kernel<<<BT_, 256, 0, stream>>>(x, emb_W, embed);
    mask_kernel<<<B_, 128, 0, stream>>>(y, maskb);

    // ---- LSTM steps: multi-launch, fused8 (BK=192, depth-2 prefetch) ----
    dim3 sgrid(32, 8);   // hc tiles x batch tiles
    for (int t = 0; t < N_; ++t) {
        const u16* hb = (t == 0) ? zero_h : (ref + (size_t)(t - 1) * H_);
        int hlda = (t == 0) ? H_ : (N_ * H_);
        fused8_step_kernel<<<sgrid, 256, 0, stream>>>(hb, hlda, embed, y,
                                                      enc_Whh, enc_Wih, enc_bih, enc_bhh,
                                                      cbuf, ref + (size_t)t * H_, 0, t);
    }
    for (int t = 0; t < N_; ++t) {
        const u16* hb = (t == 0) ? (ref + (size_t)(N_ - 1) * H_) : (dec_hs + (size_t)(t - 1) * H_);
        const u16* xb = (t == 0) ? dec0_rows : embed;
        int mode = (t == 0) ? 1 : 2;
        fused8_step_kernel<<<sgrid, 256, 0, stream>>>(hb, N_ * H_, xb, y,
                                                      dec_Whh, dec_Wih, dec_bih, dec_bhh,
                                                      cbuf, dec_hs + (size_t)t * H_, mode, t);
    }

    // ---- batched attention, chunked over batch (embed now dead) ----
    float* out = (float*)d_out;
    const int MC = BC_ * N_;                     // 12800 rows per chunk
    dim3 cgrid(H_ / 64, MC / 64);                // (8, 200)
    for (int c = 0; c < NCHUNK_; ++c) {
        const size_t rowOff = (size_t)c * BC_ * N_ * H_;
        const size_t btOff  = (size_t)c * BC_ * N_;
        gemm_bt_kernel<<<cgrid, 256, 0, stream>>>(dec_hs + rowOff, H_, Wq_W,  Wq_b,  Zbuf, H_, H_);
        gemm_bt_kernel<<<cgrid, 256, 0, stream>>>(ref + rowOff,    H_, Wref_W, Wref_b, Ybuf, H_, H_);
        glimpse_kernel<<<MC, 128, 0, stream>>>(Zbuf, Ybuf, ref + rowOff, Vec,
                                               maskb + btOff * N_, dec_hs + rowOff);
        gemm_bt_kernel<<<cgrid, 256, 0, stream>>>(dec_hs + rowOff, H_, Wq2_W, Wq2_b, Zbuf, H_, H_);
        gemm_bt_kernel<<<cgrid, 256, 0, stream>>>(ref + rowOff,    H_, Wref2_W, Wref2_b, Ybuf, H_, H_);
        final_attn_kernel<<<MC, 128, 0, stream>>>(Zbuf, Ybuf, Vec2, maskb + btOff * N_,
                                                  y + btOff, llb + (size_t)c * BC_,
                                                  out + BT_ + B_ + btOff * N_);
    }
    write_out_kernel<<<BT_ / 256, 256, 0, stream>>>(y, llb, out);
}

// Round 13
// 2784.339 us; speedup vs baseline: 1.1523x; 1.0560x over previous
//
#include <hip/hip_runtime.h>
#include <hip/hip_bf16.h>
#include <stdint.h>

typedef unsigned short u16;
typedef __bf16 bf16t;
typedef _Float16 f16t;
typedef __attribute__((ext_vector_type(8))) bf16t bf16x8;
typedef __attribute__((ext_vector_type(4))) float f32x4;
typedef __attribute__((ext_vector_type(2))) _Float16 h2;

#define B_   512
#define N_   100
#define P_   20
#define E_   256
#define H_   512
#define G4H_ 2048
#define BT_  (B_ * N_)   // 51200
#define BC_  128         // phase-B batch chunk
#define NCHUNK_ (B_ / BC_)
#define TSZ_ 4608        // 64*72 shorts per LDS tile chunk (9216 B)

__device__ __forceinline__ float bfu2f(unsigned u) {
    union { unsigned i; float f; } v; v.i = u << 16; return v.f;
}
__device__ __forceinline__ float bf2f(u16 x) { return bfu2f((unsigned)x); }
__device__ __forceinline__ u16 f2bf(float f) {
    union { float f; unsigned i; } v; v.f = f;
    unsigned r = v.i + 0x7FFFu + ((v.i >> 16) & 1u);
    return (u16)(r >> 16);
}
__device__ __forceinline__ u16 f2h_bits(float f) {
    union { f16t h; u16 u; } c; c.h = (f16t)f; return c.u;
}
__device__ __forceinline__ void unpack8(uint4 r, float* o) {
    o[0] = bfu2f(r.x & 0xffffu); o[1] = bfu2f(r.x >> 16);
    o[2] = bfu2f(r.y & 0xffffu); o[3] = bfu2f(r.y >> 16);
    o[4] = bfu2f(r.z & 0xffffu); o[5] = bfu2f(r.z >> 16);
    o[6] = bfu2f(r.w & 0xffffu); o[7] = bfu2f(r.w >> 16);
}
__device__ __forceinline__ void toh2x4(uint4 r, h2* o) {
    union { uint4 u; h2 h[4]; } c; c.u = r;
    o[0] = c.h[0]; o[1] = c.h[1]; o[2] = c.h[2]; o[3] = c.h[3];
}
__device__ __forceinline__ float tanh_f(float x) {
    x = fminf(15.f, fmaxf(-15.f, x));
    float e = __expf(2.f * x);
    return __fdividef(e - 1.f, e + 1.f);
}
__device__ __forceinline__ float sig_f(float x) {
    x = fminf(15.f, fmaxf(-15.f, x));
    return __fdividef(1.f, 1.f + __expf(-x));
}
// f32 polynomial tanh (clamped both ends) — used on the per-n final logit only
__device__ __forceinline__ float tanh_poly(float x) {
    x = fminf(3.25f, fmaxf(-3.25f, x));
    float z = x * x;
    float p = fmaf(fmaf(fmaf(-0.0018661f, z, 0.037231f), z, -0.249208f), z, 0.984238f);
    float r = x * p;
    return fminf(1.0f, fmaxf(-1.0f, r));
}
// packed-f16 tanh-dot step: s += dot2(vh, tanh_pk(qh + uh)).
__device__ __forceinline__ float tanhdot_h2(h2 uh, h2 qh, h2 vh, float s) {
    const h2 kLo = { (f16t)-3.25f, (f16t)-3.25f };
    const h2 kHi = { (f16t)3.25f,  (f16t)3.25f };
    const h2 c3 = { (f16t)-0.0018661f, (f16t)-0.0018661f };
    const h2 c2 = { (f16t)0.037231f,   (f16t)0.037231f };
    const h2 c1 = { (f16t)-0.249208f,  (f16t)-0.249208f };
    const h2 c0 = { (f16t)0.984238f,   (f16t)0.984238f };
    h2 t = uh + qh;
    t = __builtin_elementwise_max(t, kLo);
    t = __builtin_elementwise_min(t, kHi);
    h2 z = t * t;
    h2 p = __builtin_elementwise_fma(c3, z, c2);
    p = __builtin_elementwise_fma(p, z, c1);
    p = __builtin_elementwise_fma(p, z, c0);
    h2 r = t * p;
#if defined(__has_builtin) && __has_builtin(__builtin_amdgcn_fdot2)
    return __builtin_amdgcn_fdot2(r, vh, s, false);
#else
    return s + (float)r.x * (float)vh.x + (float)r.y * (float)vh.y;
#endif
}
__device__ __forceinline__ f32x4 mfma16(bf16x8 a, bf16x8 b, f32x4 c) {
    return __builtin_amdgcn_mfma_f32_16x16x32_bf16(a, b, c, 0, 0, 0);
}

// ---------------------------------------------------------------------------
__global__ void sentinel_kernel(float* out) {
    int i = blockIdx.x * 256 + threadIdx.x;
    if (i < B_) out[BT_ + i] = 1.0e9f;   // signals "workspace too small"
}

// init: zero c, zero_h, ll; broadcast dec_input0 rows
__global__ void init_kernel(float* c, u16* zero_h, float* ll, u16* dec0_rows,
                            const u16* __restrict__ dec0) {
    int i = blockIdx.x * 256 + threadIdx.x;          // 262144 threads
    if (i < B_ * H_) { c[i] = 0.f; zero_h[i] = 0; }
    if (i < B_) ll[i] = 0.f;
    if (i < B_ * E_) dec0_rows[i] = dec0[i & (E_ - 1)];
}

// embed[b,n,e] = sum_p x[b,n,p] * emb_W[e,p]
__global__ void embed_kernel(const u16* __restrict__ x, const u16* __restrict__ emb_W,
                             u16* __restrict__ embed) {
    __shared__ float xs[P_];
    int bt = blockIdx.x, tid = threadIdx.x;
    if (tid < P_) xs[tid] = bf2f(x[(size_t)bt * P_ + tid]);
    __syncthreads();
    float s = 0.f;
#pragma unroll
    for (int p = 0; p < P_; ++p) s += xs[p] * bf2f(emb_W[tid * P_ + p]);
    embed[(size_t)bt * E_ + tid] = f2bf(s);
}

// mask[b,t,n] = #{s<t : y[b,s]==n}   (cumulative COUNT, y may repeat)
__global__ void mask_kernel(const int* __restrict__ y, unsigned char* __restrict__ mask) {
    int b = blockIdx.x, n = threadIdx.x;
    if (n >= N_) return;
    unsigned char cnt = 0;
    for (int t = 0; t < N_; ++t) {
        mask[((size_t)b * N_ + t) * N_ + n] = cnt;
        if (y[b * N_ + t] == n) cnt++;
    }
}

// ---------------------------------------------------------------------------
// Fused LSTM step v8 (verified R11): BK=192, 4 K-iters, 8 barriers, depth-2
// register prefetch (named sets X/Y), bit-identical numerics vs fused3.
#define LOADSET(c0, A0,A1,A2,A3,A4,A5,B0,B1,B2,B3,B4,B5) do { \
    const u16* sa0_ = srcA(c0); const u16* sa1_ = srcA((c0)+1); const u16* sa2_ = srcA((c0)+2); \
    const u16* sb0_ = srcB(c0); const u16* sb1_ = srcB((c0)+1); const u16* sb2_ = srcB((c0)+2); \
    A0 = *(const uint4*)sa0_; A1 = *(const uint4*)(sa0_ + 8); \
    A2 = *(const uint4*)sa1_; A3 = *(const uint4*)(sa1_ + 8); \
    A4 = *(const uint4*)sa2_; A5 = *(const uint4*)(sa2_ + 8); \
    B0 = *(const uint4*)sb0_; B1 = *(const uint4*)(sb0_ + 8); \
    B2 = *(const uint4*)sb1_; B3 = *(const uint4*)(sb1_ + 8); \
    B4 = *(const uint4*)sb2_; B5 = *(const uint4*)(sb2_ + 8); \
} while(0)

#define WRITESET(A0,A1,A2,A3,A4,A5,B0,B1,B2,B3,B4,B5) do { \
    *(uint4*)asw0 = A0;  *(uint4*)(asw0 + 8) = A1; \
    *(uint4*)asw1 = A2;  *(uint4*)(asw1 + 8) = A3; \
    *(uint4*)asw2 = A4;  *(uint4*)(asw2 + 8) = A5; \
    *(uint4*)bsw0 = B0;  *(uint4*)(bsw0 + 8) = B1; \
    *(uint4*)bsw1 = B2;  *(uint4*)(bsw1 + 8) = B3; \
    *(uint4*)bsw2 = B4;  *(uint4*)(bsw2 + 8) = B5; \
} while(0)

#define COMPUTE3() do { \
    _Pragma("unroll") \
    for (int s_ = 0; s_ < 3; ++s_) { \
        const int so_ = s_ * TSZ_; \
        bf16x8 af0_ = *(const bf16x8*)(arp + so_); \
        bf16x8 af1_ = *(const bf16x8*)(arp + so_ + 32); \
        _Pragma("unroll") \
        for (int g_ = 0; g_ < 4; ++g_) { \
            const short* brp_ = &Bs[so_ + (g_ * 16 + rl) * 72 + q8]; \
            bf16x8 bb0_ = *(const bf16x8*)brp_; \
            bf16x8 bb1_ = *(const bf16x8*)(brp_ + 32); \
            acc[g_] = mfma16(af0_, bb0_, acc[g_]); \
            acc[g_] = mfma16(af1_, bb1_, acc[g_]); \
        } \
    } \
} while(0)

__global__ __launch_bounds__(256) void fused8_step_kernel(
    const u16* __restrict__ h_base, int h_lda,
    const u16* __restrict__ x_base,
    const int* __restrict__ y,
    const u16* __restrict__ Whh, const u16* __restrict__ Wih,
    const u16* __restrict__ bih, const u16* __restrict__ bhh,
    float* __restrict__ cbuf,
    u16* __restrict__ hout,
    int mode, int t)
{
    __shared__ __align__(16) short As[3 * TSZ_];   // chunk slots 0|1|2
    __shared__ __align__(16) short Bs[3 * TSZ_];
    const int tid = threadIdx.x;
    const int bn = blockIdx.x, bm = blockIdx.y;
    const int w = tid >> 6, l = tid & 63, rl = l & 15, q = l >> 4, q8 = q * 8;
    const int srow = tid >> 2, koff = (tid & 3) * 16;
    const int brw = bm * 64 + srow;

    const u16* hp = h_base + (size_t)brw * h_lda + koff;
    size_t xrow;
    if (mode == 0)      xrow = ((size_t)brw * N_ + t) * E_;
    else if (mode == 1) xrow = (size_t)brw * E_;
    else                xrow = ((size_t)brw * N_ + (size_t)y[brw * N_ + t - 1]) * E_;
    const u16* xp = x_base + xrow + koff;

    const int wrow = (srow >> 4) * 512 + bn * 16 + (srow & 15);
    const u16* whp = Whh + (size_t)wrow * H_ + koff;
    const u16* wip = Wih + (size_t)wrow * E_ + koff;

    float bsum[4];
#pragma unroll
    for (int g = 0; g < 4; ++g) {
        int col = g * 512 + bn * 16 + rl;
        bsum[g] = bf2f(bih[col]) + bf2f(bhh[col]);
    }

    f32x4 acc[4];
#pragma unroll
    for (int g = 0; g < 4; ++g) acc[g] = (f32x4){0.f, 0.f, 0.f, 0.f};

    auto srcA = [&](int c) -> const u16* {
        return (c < 8) ? (hp + c * 64) : (xp + (c - 8) * 64);
    };
    auto srcB = [&](int c) -> const u16* {
        return (c < 8) ? (whp + c * 64) : (wip + (c - 8) * 64);
    };

    short* asw0 = &As[srow * 72 + koff];
    short* asw1 = asw0 + TSZ_;
    short* asw2 = asw0 + 2 * TSZ_;
    short* bsw0 = &Bs[srow * 72 + koff];
    short* bsw1 = bsw0 + TSZ_;
    short* bsw2 = bsw0 + 2 * TSZ_;
    const short* arp = &As[(w * 16 + rl) * 72 + q8];

    uint4 xa0, xa1, xa2, xa3, xa4, xa5, xb0, xb1, xb2, xb3, xb4, xb5;
    uint4 ya0, ya1, ya2, ya3, ya4, ya5, yb0, yb1, yb2, yb3, yb4, yb5;

    LOADSET(0, xa0,xa1,xa2,xa3,xa4,xa5, xb0,xb1,xb2,xb3,xb4,xb5);
    LOADSET(3, ya0,ya1,ya2,ya3,ya4,ya5, yb0,yb1,yb2,yb3,yb4,yb5);

    __syncthreads();
    WRITESET(xa0,xa1,xa2,xa3,xa4,xa5, xb0,xb1,xb2,xb3,xb4,xb5);
    __syncthreads();
    LOADSET(6, xa0,xa1,xa2,xa3,xa4,xa5, xb0,xb1,xb2,xb3,xb4,xb5);
    COMPUTE3();
    __syncthreads();
    WRITESET(ya0,ya1,ya2,ya3,ya4,ya5, yb0,yb1,yb2,yb3,yb4,yb5);
    __syncthreads();
    LOADSET(9, ya0,ya1,ya2,ya3,ya4,ya5, yb0,yb1,yb2,yb3,yb4,yb5);
    COMPUTE3();
    __syncthreads();
    WRITESET(xa0,xa1,xa2,xa3,xa4,xa5, xb0,xb1,xb2,xb3,xb4,xb5);
    __syncthreads();
    COMPUTE3();
    __syncthreads();
    WRITESET(ya0,ya1,ya2,ya3,ya4,ya5, yb0,yb1,yb2,yb3,yb4,yb5);
    __syncthreads();
    COMPUTE3();

    const int hcol = bn * 16 + rl;
#pragma unroll
    for (int r = 0; r < 4; ++r) {
        int brow = bm * 64 + w * 16 + q * 4 + r;
        float gi = acc[0][r] + bsum[0];
        float gf = acc[1][r] + bsum[1];
        float gg = acc[2][r] + bsum[2];
        float go = acc[3][r] + bsum[3];
        size_t cidx = (size_t)brow * H_ + hcol;
        float cv = sig_f(gf) * cbuf[cidx] + sig_f(gi) * tanh_f(gg);
        cbuf[cidx] = cv;
        hout[(size_t)brow * (N_ * H_) + hcol] = f2bf(sig_f(go) * tanh_f(cv));
    }
}

// ---------------------------------------------------------------------------
// Head GEMM (R3-proven structure): C = A @ Bw^T + bias, 64x64 tile, BK=32.
__global__ __launch_bounds__(256) void gemm_bt_kernel(
    const u16* __restrict__ A, int lda,
    const u16* __restrict__ Bw,
    const u16* __restrict__ bias,
    u16* __restrict__ C, int ldc, int K)
{
    __shared__ __align__(16) short As[64 * 40];
    __shared__ __align__(16) short Bs[64 * 40];
    const int tid = threadIdx.x;
    const int bn = blockIdx.x, bm = blockIdx.y;
    const int srow = tid >> 2, koff = (tid & 3) * 8;
    const size_t aBase = (size_t)(bm * 64 + srow) * lda + koff;
    const size_t bBase = (size_t)(bn * 64 + srow) * K + koff;
    const int NKT = K >> 5;
    uint4 aReg = *(const uint4*)(A + aBase);
    uint4 bReg = *(const uint4*)(Bw + bBase);
    const int w = tid >> 6, l = tid & 63;
    const int wm = w & 1, wn = w >> 1;
    const int rl = l & 15, q8 = (l >> 4) * 8;
    f32x4 acc00 = {0.f,0.f,0.f,0.f}, acc01 = {0.f,0.f,0.f,0.f};
    f32x4 acc10 = {0.f,0.f,0.f,0.f}, acc11 = {0.f,0.f,0.f,0.f};
    short* asw = &As[srow * 40 + koff];
    short* bsw = &Bs[srow * 40 + koff];
    const short* ar0 = &As[(wm * 32 + rl) * 40 + q8];
    const short* ar1 = &As[(wm * 32 + 16 + rl) * 40 + q8];
    const short* br0 = &Bs[(wn * 32 + rl) * 40 + q8];
    const short* br1 = &Bs[(wn * 32 + 16 + rl) * 40 + q8];
    for (int kt = 0; kt < NKT; ++kt) {
        __syncthreads();
        *(uint4*)asw = aReg;
        *(uint4*)bsw = bReg;
        __syncthreads();
        if (kt + 1 < NKT) {
            aReg = *(const uint4*)(A + aBase + (kt + 1) * 32);
            bReg = *(const uint4*)(Bw + bBase + (kt + 1) * 32);
        }
        bf16x8 a0 = *(const bf16x8*)ar0;
        bf16x8 a1 = *(const bf16x8*)ar1;
        bf16x8 b0 = *(const bf16x8*)br0;
        bf16x8 b1 = *(const bf16x8*)br1;
        acc00 = mfma16(a0, b0, acc00);
        acc01 = mfma16(a0, b1, acc01);
        acc10 = mfma16(a1, b0, acc10);
        acc11 = mfma16(a1, b1, acc11);
    }
    const int col0 = bn * 64 + wn * 32 + rl;
    const int row0 = bm * 64 + wm * 32 + (l >> 4) * 4;
    const float bv0 = bias ? bf2f(bias[col0]) : 0.f;
    const float bv1 = bias ? bf2f(bias[col0 + 16]) : 0.f;
#pragma unroll
    for (int r = 0; r < 4; ++r) {
        C[(size_t)(row0 + r) * ldc + col0]           = f2h_bits(acc00[r] + bv0);
        C[(size_t)(row0 + r) * ldc + col0 + 16]      = f2h_bits(acc01[r] + bv1);
        C[(size_t)(row0 + 16 + r) * ldc + col0]      = f2h_bits(acc10[r] + bv0);
        C[(size_t)(row0 + 16 + r) * ldc + col0 + 16] = f2h_bits(acc11[r] + bv1);
    }
}

// ---------------------------------------------------------------------------
// XCD-locality block remap (R13): with round-robin dispatch, blocks with
// bid%8==k land on XCD k. Map all 100 t-blocks of one b to the SAME XCD so
// u2g[b]/ref[b] (~204 KB) stay in that XCD's 4MB L2 (16 b's x 204KB = 3.3MB).
__device__ __forceinline__ void xcd_bt(int bid, int& b, int& bt) {
    b = ((bid & 7) << 4) + ((bid >> 3) / N_);
    const int t = (bid >> 3) % N_;
    bt = b * N_ + t;
}

// Glimpse v10: R12 structure (128 thr) + XCD-locality remap.
__global__ __launch_bounds__(128) void glimpse_kernel(
    const u16* __restrict__ q1, const u16* __restrict__ u2g,
    const u16* __restrict__ ref, const u16* __restrict__ Vec,
    const unsigned char* __restrict__ mask, u16* __restrict__ query2)
{
    int b, bt;
    xcd_bt(blockIdx.x, b, bt);
    const int tid = threadIdx.x, w = tid >> 6, l = tid & 63;
    const int g16 = l >> 4, l16 = l & 15;
    __shared__ float u_s[N_], a_s[N_], red[4];
    __shared__ short list[N_];
    __shared__ int wcnt[2], cnt_s;
    __shared__ __align__(16) float pv_s[2][H_];   // 4 KB PV partials
    const int h32 = l16 * 32;                     // scoring slice (16 lanes/n)
    const int h0 = l * 8;                         // PV slice (64 lanes)
    // ---- preload q and Vec 32-elem slices (scoring) ----
    h2 qh[16], vh[16];
    {
        const u16* qp = q1 + (size_t)bt * H_ + h32;
        toh2x4(*(const uint4*)qp,        qh);
        toh2x4(*(const uint4*)(qp + 8),  qh + 4);
        toh2x4(*(const uint4*)(qp + 16), qh + 8);
        toh2x4(*(const uint4*)(qp + 24), qh + 12);
        const u16* vp = Vec + h32;
#pragma unroll
        for (int m = 0; m < 4; ++m) {
            float vf[8]; unpack8(*(const uint4*)(vp + m * 8), vf);
#pragma unroll
            for (int j = 0; j < 4; ++j)
                vh[m * 4 + j] = (h2){ (f16t)vf[2 * j], (f16t)vf[2 * j + 1] };
        }
    }
    bool un = false;
    if (tid < N_) {
        un = (mask[(size_t)bt * N_ + tid] == 0);
        u_s[tid] = -3.0e38f;                 // init ALL entries (R6 scar)
    }
    unsigned long long bal = __ballot(un);
    if (l == 0) wcnt[w] = __popcll(bal);
    __syncthreads();
    const int base = (w == 1) ? wcnt[0] : 0;
    const int pos = __popcll(bal & ((1ULL << l) - 1ULL));
    if (un) list[base + pos] = (short)tid;
    if (tid == 0) cnt_s = wcnt[0] + wcnt[1];
    __syncthreads();
    const int cnt = cnt_s;
    const u16* ub = u2g + (size_t)b * N_ * H_;
    // ---- scoring: group (w,g16) handles k = w*4+g16 (mod 8) ----
    for (int k = w * 4 + g16; k < cnt; k += 8) {
        const int n = list[k];
        const u16* up = ub + (size_t)n * H_ + h32;
        h2 uh[16];
        toh2x4(*(const uint4*)up,        uh);
        toh2x4(*(const uint4*)(up + 8),  uh + 4);
        toh2x4(*(const uint4*)(up + 16), uh + 8);
        toh2x4(*(const uint4*)(up + 24), uh + 12);
        float sa = 0.f, sb = 0.f, sc = 0.f, sd = 0.f;
#pragma unroll
        for (int j = 0; j < 4; ++j) {
            sa = tanhdot_h2(uh[j],      qh[j],      vh[j],      sa);
            sb = tanhdot_h2(uh[4 + j],  qh[4 + j],  vh[4 + j],  sb);
            sc = tanhdot_h2(uh[8 + j],  qh[8 + j],  vh[8 + j],  sc);
            sd = tanhdot_h2(uh[12 + j], qh[12 + j], vh[12 + j], sd);
        }
        float s = (sa + sb) + (sc + sd);
#pragma unroll
        for (int off = 8; off > 0; off >>= 1) s += __shfl_xor(s, off, 64);
        if (l16 == 0) u_s[n] = s;
    }
    __syncthreads();
    float v = un ? u_s[tid] : -3.0e38f;
    float m = v;
#pragma unroll
    for (int off = 32; off > 0; off >>= 1) m = fmaxf(m, __shfl_xor(m, off, 64));
    if (l == 0) red[w] = m;
    __syncthreads();
    float mx = fmaxf(red[0], red[1]);
    float e = un ? __expf(v - mx) : 0.f;
    float s2 = e;
#pragma unroll
    for (int off = 32; off > 0; off >>= 1) s2 += __shfl_xor(s2, off, 64);
    if (l == 0) red[2 + w] = s2;
    __syncthreads();
    float inv = __fdividef(1.f, red[2] + red[3]);
    if (tid < N_) a_s[tid] = e * inv;
    __syncthreads();
    // ---- PV split-k: wave w sums k == w (mod 2); lane owns h0..h0+7 ----
    const u16* refb = ref + (size_t)b * N_ * H_;
    float pacc[8] = {0.f, 0.f, 0.f, 0.f, 0.f, 0.f, 0.f, 0.f};
    for (int k = w; k < cnt; k += 2) {
        const int n = list[k];
        const float a = a_s[n];
        float rv[8];
        unpack8(*(const uint4*)(refb + (size_t)n * H_ + h0), rv);
#pragma unroll
        for (int j = 0; j < 8; ++j) pacc[j] = fmaf(a, rv[j], pacc[j]);
    }
    {
        float4 pa0 = {pacc[0], pacc[1], pacc[2], pacc[3]};
        float4 pa1 = {pacc[4], pacc[5], pacc[6], pacc[7]};
        *(float4*)&pv_s[w][h0]     = pa0;
        *(float4*)&pv_s[w][h0 + 4] = pa1;
    }
    __syncthreads();
    const int hh = tid * 4;                       // 128 threads x 4 elems
    float s0 = pv_s[0][hh]     + pv_s[1][hh];
    float s1 = pv_s[0][hh + 1] + pv_s[1][hh + 1];
    float s2b = pv_s[0][hh + 2] + pv_s[1][hh + 2];
    float s3 = pv_s[0][hh + 3] + pv_s[1][hh + 3];
    uint2 packed;
    packed.x = ((unsigned)f2bf(s1) << 16) | (unsigned)f2bf(s0);
    packed.y = ((unsigned)f2bf(s3) << 16) | (unsigned)f2bf(s2b);
    *(uint2*)(query2 + (size_t)bt * H_ + hh) = packed;
}

// Pointer head v9: R12 structure (128 thr) + XCD-locality remap.
__global__ __launch_bounds__(128) void final_attn_kernel(
    const u16* __restrict__ q2, const u16* __restrict__ u2p,
    const u16* __restrict__ Vec2, const unsigned char* __restrict__ mask,
    const int* __restrict__ y, float* __restrict__ ll, float* __restrict__ ps)
{
    int b, bt;
    xcd_bt(blockIdx.x, b, bt);
    const int tid = threadIdx.x, w = tid >> 6, l = tid & 63;
    const int g16 = l >> 4, l16 = l & 15;
    __shared__ float u_s[N_], lp_s[N_], red[4];
    __shared__ short list[N_];
    __shared__ unsigned char msk[128];
    __shared__ int wcnt[2], cnt_s;
    const int h32 = l16 * 32;
    h2 qh[16], vh[16];
    {
        const u16* qp = q2 + (size_t)bt * H_ + h32;
        toh2x4(*(const uint4*)qp,        qh);
        toh2x4(*(const uint4*)(qp + 8),  qh + 4);
        toh2x4(*(const uint4*)(qp + 16), qh + 8);
        toh2x4(*(const uint4*)(qp + 24), qh + 12);
        const u16* vp = Vec2 + h32;
#pragma unroll
        for (int m = 0; m < 4; ++m) {
            float vf[8]; unpack8(*(const uint4*)(vp + m * 8), vf);
#pragma unroll
            for (int j = 0; j < 4; ++j)
                vh[m * 4 + j] = (h2){ (f16t)vf[2 * j], (f16t)vf[2 * j + 1] };
        }
    }
    bool un = false;
    msk[tid] = (tid < N_) ? mask[(size_t)bt * N_ + tid] : 1;
    if (tid < N_) {
        un = (msk[tid] == 0);
        u_s[tid] = 0.f;
    }
    unsigned long long bal = __ballot(un);
    if (l == 0) wcnt[w] = __popcll(bal);
    __syncthreads();
    const int base = (w == 1) ? wcnt[0] : 0;
    const int pos = __popcll(bal & ((1ULL << l) - 1ULL));
    if (un) list[base + pos] = (short)tid;
    if (tid == 0) cnt_s = wcnt[0] + wcnt[1];
    __syncthreads();
    const int cnt = cnt_s;
    const u16* ub = u2p + (size_t)b * N_ * H_;
    for (int k = w * 4 + g16; k < cnt; k += 8) {
        const int n = list[k];
        const u16* up = ub + (size_t)n * H_ + h32;
        h2 uh[16];
        toh2x4(*(const uint4*)up,        uh);
        toh2x4(*(const uint4*)(up + 8),  uh + 4);
        toh2x4(*(const uint4*)(up + 16), uh + 8);
        toh2x4(*(const uint4*)(up + 24), uh + 12);
        float sa = 0.f, sb = 0.f, sc = 0.f, sd = 0.f;
#pragma unroll
        for (int j = 0; j < 4; ++j) {
            sa = tanhdot_h2(uh[j],      qh[j],      vh[j],      sa);
            sb = tanhdot_h2(uh[4 + j],  qh[4 + j],  vh[4 + j],  sb);
            sc = tanhdot_h2(uh[8 + j],  qh[8 + j],  vh[8 + j],  sc);
            sd = tanhdot_h2(uh[12 + j], qh[12 + j], vh[12 + j], sd);
        }
        float s = (sa + sb) + (sc + sd);
#pragma unroll
        for (int off = 8; off > 0; off >>= 1) s += __shfl_xor(s, off, 64);
        if (l16 == 0) u_s[n] = s;
    }
    __syncthreads();
    float lg = -3.0e38f;
    if (tid < N_) {
        unsigned char c = msk[tid];
        if (c) lg = -1e8f * (float)c;
        else   lg = 10.f * tanh_poly(u_s[tid]);
    }
    float m = lg;
#pragma unroll
    for (int off = 32; off > 0; off >>= 1) m = fmaxf(m, __shfl_xor(m, off, 64));
    if (l == 0) red[w] = m;
    __syncthreads();
    float mx = fmaxf(red[0], red[1]);
    float e = (tid < N_) ? __expf(lg - mx) : 0.f;
    float s2 = e;
#pragma unroll
    for (int off = 32; off > 0; off >>= 1) s2 += __shfl_xor(s2, off, 64);
    if (l == 0) red[2 + w] = s2;
    __syncthreads();
    float lse = mx + __logf(red[2] + red[3]);
    if (tid < N_) {
        float lp = lg - lse;
        ps[(size_t)bt * N_ + tid] = lp;
        lp_s[tid] = lp;
    }
    __syncthreads();
    if (tid == 0) atomicAdd(&ll[b], lp_s[y[bt]]);
}

// outputs (float32): pi = float(y); ll from f32 accumulator
__global__ void write_out_kernel(const int* __restrict__ y, const float* __restrict__ ll,
                                 float* __restrict__ out) {
    int i = blockIdx.x * 256 + threadIdx.x;   // 51200 threads
    if (i < BT_) out[i] = (float)y[i];
    if (i < B_)  out[BT_ + i] = ll[i];
}

// ---------------------------------------------------------------------------
extern "C" void kernel_launch(void* const* d_in, const int* in_sizes, int n_in,
                              void* d_out, int out_size, void* d_ws, size_t ws_size,
                              hipStream_t stream)
{
    const u16* x        = (const u16*)d_in[0];
    const int* y        = (const int*)d_in[1];
    const u16* emb_W    = (const u16*)d_in[2];
    const u16* enc_Wih  = (const u16*)d_in[3];
    const u16* enc_Whh  = (const u16*)d_in[4];
    const u16* enc_bih  = (const u16*)d_in[5];
    const u16* enc_bhh  = (const u16*)d_in[6];
    const u16* dec_Wih  = (const u16*)d_in[7];
    const u16* dec_Whh  = (const u16*)d_in[8];
    const u16* dec_bih  = (const u16*)d_in[9];
    const u16* dec_bhh  = (const u16*)d_in[10];
    const u16* Vec      = (const u16*)d_in[11];
    const u16* Vec2     = (const u16*)d_in[12];
    const u16* Wq_W     = (const u16*)d_in[13];
    const u16* Wq_b     = (const u16*)d_in[14];
    const u16* Wref_W   = (const u16*)d_in[15];
    const u16* Wref_b   = (const u16*)d_in[16];
    const u16* Wq2_W    = (const u16*)d_in[17];
    const u16* Wq2_b    = (const u16*)d_in[18];
    const u16* Wref2_W  = (const u16*)d_in[19];
    const u16* Wref2_b  = (const u16*)d_in[20];
    const u16* dec0     = (const u16*)d_in[21];

    char* p = (char*)d_ws;
    auto carve = [&](size_t bytes) -> char* {
        char* r = p; p += (bytes + 255) & ~(size_t)255; return r;
    };
    u16*   embed     = (u16*)  carve((size_t)BT_ * E_ * 2);      // 26.21 MB
    float* cbuf      = (float*)carve((size_t)B_ * H_ * 4);       //  1.05 MB
    u16*   zero_h    = (u16*)  carve((size_t)B_ * H_ * 2);       //  0.52 MB
    u16*   dec0_rows = (u16*)  carve((size_t)B_ * E_ * 2);       //  0.26 MB
    u16*   ref       = (u16*)  carve((size_t)BT_ * H_ * 2);      // 52.43 MB
    u16*   dec_hs    = (u16*)  carve((size_t)BT_ * H_ * 2);      // 52.43 MB (later: qry2)
    unsigned char* maskb = (unsigned char*)carve((size_t)BT_ * N_); // 5.12 MB
    float* llb       = (float*)carve((size_t)B_ * 4);
    const size_t need = (size_t)(p - (char*)d_ws);
    u16* Ybuf = embed;                                  // u2g / u2p chunk (f16)
    u16* Zbuf = embed + (size_t)BC_ * N_ * H_;          // q1 / q2 chunk (f16)

    if (need > ws_size) {
        sentinel_kernel<<<(B_ + 255) / 256, 256, 0, stream>>>((float*)d_out);
        return;
    }

    init_kernel<<<(B_ * H_) / 256, 256, 0, stream>>>(cbuf, zero_h, llb, dec0_rows, dec0);
    embed_kernel<<<BT_, 256, 0, stream>>>(x, emb_W, embed);
    mask_kernel<<<B_, 128, 0, stream>>>(y, maskb);

    // ---- LSTM steps: multi-launch, fused8 (BK=192, depth-2 prefetch) ----
    dim3 sgrid(32, 8);   // hc tiles x batch tiles
    for (int t = 0; t < N_; ++t) {
        const u16* hb = (t == 0) ? zero_h : (ref + (size_t)(t - 1) * H_);
        int hlda = (t == 0) ? H_ : (N_ * H_);
        fused8_step_kernel<<<sgrid, 256, 0, stream>>>(hb, hlda, embed, y,
                                                      enc_Whh, enc_Wih, enc_bih, enc_bhh,
                                                      cbuf, ref + (size_t)t * H_, 0, t);
    }
    for (int t = 0; t < N_; ++t) {
        const u16* hb = (t == 0) ? (ref + (size_t)(N_ - 1) * H_) : (dec_hs + (size_t)(t - 1) * H_);
        const u16* xb = (t == 0) ? dec0_rows : embed;
        int mode = (t == 0) ? 1 : 2;
        fused8_step_kernel<<<sgrid, 256, 0, stream>>>(hb, N_ * H_, xb, y,
                                                      dec_Whh, dec_Wih, dec_bih, dec_bhh,
                                                      cbuf, dec_hs + (size_t)t * H_, mode, t);
    }

    // ---- batched attention, chunked over batch (embed now dead) ----
    float* out = (float*)d_out;
    const int MC = BC_ * N_;                     // 12800 rows per chunk
    dim3 cgrid(H_ / 64, MC / 64);                // (8, 200)
    for (int c = 0; c < NCHUNK_; ++c) {
        const size_t rowOff = (size_t)c * BC_ * N_ * H_;
        const size_t btOff  = (size_t)c * BC_ * N_;
        gemm_bt_kernel<<<cgrid, 256, 0, stream>>>(dec_hs + rowOff, H_, Wq_W,  Wq_b,  Zbuf, H_, H_);
        gemm_bt_kernel<<<cgrid, 256, 0, stream>>>(ref + rowOff,    H_, Wref_W, Wref_b, Ybuf, H_, H_);
        glimpse_kernel<<<MC, 128, 0, stream>>>(Zbuf, Ybuf, ref + rowOff, Vec,
                                               maskb + btOff * N_, dec_hs + rowOff);
        gemm_bt_kernel<<<cgrid, 256, 0, stream>>>(dec_hs + rowOff, H_, Wq2_W, Wq2_b, Zbuf, H_, H_);
        gemm_bt_kernel<<<cgrid, 256, 0, stream>>>(ref + rowOff,    H_, Wref2_W, Wref2_b, Ybuf, H_, H_);
        final_attn_kernel<<<MC, 128, 0, stream>>>(Zbuf, Ybuf, Vec2, maskb + btOff * N_,
                                                  y + btOff, llb + (size_t)c * BC_,
                                                  out + BT_ + B_ + btOff * N_);
    }
    write_out_kernel<<<BT_ / 256, 256, 0, stream>>>(y, llb, out);
}

// Round 14
// 2653.177 us; speedup vs baseline: 1.2093x; 1.0494x over previous
//
#include <hip/hip_runtime.h>
#include <hip/hip_bf16.h>
#include <stdint.h>

typedef unsigned short u16;
typedef __bf16 bf16t;
typedef _Float16 f16t;
typedef __attribute__((ext_vector_type(8))) bf16t bf16x8;
typedef __attribute__((ext_vector_type(4))) float f32x4;
typedef __attribute__((ext_vector_type(2))) _Float16 h2;

#define B_   512
#define N_   100
#define P_   20
#define E_   256
#define H_   512
#define G4H_ 2048
#define BT_  (B_ * N_)   // 51200
#define BC_  128         // phase-B batch chunk
#define NCHUNK_ (B_ / BC_)
#define TSZ_ 4608        // 64*72 shorts per LDS tile chunk (9216 B)

__device__ __forceinline__ float bfu2f(unsigned u) {
    union { unsigned i; float f; } v; v.i = u << 16; return v.f;
}
__device__ __forceinline__ float bf2f(u16 x) { return bfu2f((unsigned)x); }
__device__ __forceinline__ u16 f2bf(float f) {
    union { float f; unsigned i; } v; v.f = f;
    unsigned r = v.i + 0x7FFFu + ((v.i >> 16) & 1u);
    return (u16)(r >> 16);
}
__device__ __forceinline__ u16 f2h_bits(float f) {
    union { f16t h; u16 u; } c; c.h = (f16t)f; return c.u;
}
__device__ __forceinline__ void unpack8(uint4 r, float* o) {
    o[0] = bfu2f(r.x & 0xffffu); o[1] = bfu2f(r.x >> 16);
    o[2] = bfu2f(r.y & 0xffffu); o[3] = bfu2f(r.y >> 16);
    o[4] = bfu2f(r.z & 0xffffu); o[5] = bfu2f(r.z >> 16);
    o[6] = bfu2f(r.w & 0xffffu); o[7] = bfu2f(r.w >> 16);
}
__device__ __forceinline__ void toh2x4(uint4 r, h2* o) {
    union { uint4 u; h2 h[4]; } c; c.u = r;
    o[0] = c.h[0]; o[1] = c.h[1]; o[2] = c.h[2]; o[3] = c.h[3];
}
__device__ __forceinline__ float tanh_f(float x) {
    x = fminf(15.f, fmaxf(-15.f, x));
    float e = __expf(2.f * x);
    return __fdividef(e - 1.f, e + 1.f);
}
__device__ __forceinline__ float sig_f(float x) {
    x = fminf(15.f, fmaxf(-15.f, x));
    return __fdividef(1.f, 1.f + __expf(-x));
}
// f32 polynomial tanh (clamped both ends) — used on the per-n final logit only
__device__ __forceinline__ float tanh_poly(float x) {
    x = fminf(3.25f, fmaxf(-3.25f, x));
    float z = x * x;
    float p = fmaf(fmaf(fmaf(-0.0018661f, z, 0.037231f), z, -0.249208f), z, 0.984238f);
    float r = x * p;
    return fminf(1.0f, fmaxf(-1.0f, r));
}
// packed-f16 tanh-dot step: s += dot2(vh, tanh_pk(qh + uh)).
__device__ __forceinline__ float tanhdot_h2(h2 uh, h2 qh, h2 vh, float s) {
    const h2 kLo = { (f16t)-3.25f, (f16t)-3.25f };
    const h2 kHi = { (f16t)3.25f,  (f16t)3.25f };
    const h2 c3 = { (f16t)-0.0018661f, (f16t)-0.0018661f };
    const h2 c2 = { (f16t)0.037231f,   (f16t)0.037231f };
    const h2 c1 = { (f16t)-0.249208f,  (f16t)-0.249208f };
    const h2 c0 = { (f16t)0.984238f,   (f16t)0.984238f };
    h2 t = uh + qh;
    t = __builtin_elementwise_max(t, kLo);
    t = __builtin_elementwise_min(t, kHi);
    h2 z = t * t;
    h2 p = __builtin_elementwise_fma(c3, z, c2);
    p = __builtin_elementwise_fma(p, z, c1);
    p = __builtin_elementwise_fma(p, z, c0);
    h2 r = t * p;
#if defined(__has_builtin) && __has_builtin(__builtin_amdgcn_fdot2)
    return __builtin_amdgcn_fdot2(r, vh, s, false);
#else
    return s + (float)r.x * (float)vh.x + (float)r.y * (float)vh.y;
#endif
}
__device__ __forceinline__ f32x4 mfma16(bf16x8 a, bf16x8 b, f32x4 c) {
    return __builtin_amdgcn_mfma_f32_16x16x32_bf16(a, b, c, 0, 0, 0);
}

// ---------------------------------------------------------------------------
__global__ void sentinel_kernel(float* out) {
    int i = blockIdx.x * 256 + threadIdx.x;
    if (i < B_) out[BT_ + i] = 1.0e9f;   // signals "workspace too small"
}

// init: zero c, zero_h, ll; broadcast dec_input0 rows
__global__ void init_kernel(float* c, u16* zero_h, float* ll, u16* dec0_rows,
                            const u16* __restrict__ dec0) {
    int i = blockIdx.x * 256 + threadIdx.x;          // 262144 threads
    if (i < B_ * H_) { c[i] = 0.f; zero_h[i] = 0; }
    if (i < B_) ll[i] = 0.f;
    if (i < B_ * E_) dec0_rows[i] = dec0[i & (E_ - 1)];
}

// embed[b,n,e] = sum_p x[b,n,p] * emb_W[e,p]
__global__ void embed_kernel(const u16* __restrict__ x, const u16* __restrict__ emb_W,
                             u16* __restrict__ embed) {
    __shared__ float xs[P_];
    int bt = blockIdx.x, tid = threadIdx.x;
    if (tid < P_) xs[tid] = bf2f(x[(size_t)bt * P_ + tid]);
    __syncthreads();
    float s = 0.f;
#pragma unroll
    for (int p = 0; p < P_; ++p) s += xs[p] * bf2f(emb_W[tid * P_ + p]);
    embed[(size_t)bt * E_ + tid] = f2bf(s);
}

// mask[b,t,n] = #{s<t : y[b,s]==n}   (cumulative COUNT, y may repeat)
__global__ void mask_kernel(const int* __restrict__ y, unsigned char* __restrict__ mask) {
    int b = blockIdx.x, n = threadIdx.x;
    if (n >= N_) return;
    unsigned char cnt = 0;
    for (int t = 0; t < N_; ++t) {
        mask[((size_t)b * N_ + t) * N_ + n] = cnt;
        if (y[b * N_ + t] == n) cnt++;
    }
}

// ---------------------------------------------------------------------------
// Fused LSTM step v9: fused8 (verified R11) + XCD-locality remap (R13
// mechanism): bm = lid&7 so the writer and ALL readers of h row-block bm sit
// on the same XCD -> h(t-1) reads hit that XCD's L2 instead of L3/HBM.
// Pure block-role remap => bit-identical numerics.
#define LOADSET(c0, A0,A1,A2,A3,A4,A5,B0,B1,B2,B3,B4,B5) do { \
    const u16* sa0_ = srcA(c0); const u16* sa1_ = srcA((c0)+1); const u16* sa2_ = srcA((c0)+2); \
    const u16* sb0_ = srcB(c0); const u16* sb1_ = srcB((c0)+1); const u16* sb2_ = srcB((c0)+2); \
    A0 = *(const uint4*)sa0_; A1 = *(const uint4*)(sa0_ + 8); \
    A2 = *(const uint4*)sa1_; A3 = *(const uint4*)(sa1_ + 8); \
    A4 = *(const uint4*)sa2_; A5 = *(const uint4*)(sa2_ + 8); \
    B0 = *(const uint4*)sb0_; B1 = *(const uint4*)(sb0_ + 8); \
    B2 = *(const uint4*)sb1_; B3 = *(const uint4*)(sb1_ + 8); \
    B4 = *(const uint4*)sb2_; B5 = *(const uint4*)(sb2_ + 8); \
} while(0)

#define WRITESET(A0,A1,A2,A3,A4,A5,B0,B1,B2,B3,B4,B5) do { \
    *(uint4*)asw0 = A0;  *(uint4*)(asw0 + 8) = A1; \
    *(uint4*)asw1 = A2;  *(uint4*)(asw1 + 8) = A3; \
    *(uint4*)asw2 = A4;  *(uint4*)(asw2 + 8) = A5; \
    *(uint4*)bsw0 = B0;  *(uint4*)(bsw0 + 8) = B1; \
    *(uint4*)bsw1 = B2;  *(uint4*)(bsw1 + 8) = B3; \
    *(uint4*)bsw2 = B4;  *(uint4*)(bsw2 + 8) = B5; \
} while(0)

#define COMPUTE3() do { \
    _Pragma("unroll") \
    for (int s_ = 0; s_ < 3; ++s_) { \
        const int so_ = s_ * TSZ_; \
        bf16x8 af0_ = *(const bf16x8*)(arp + so_); \
        bf16x8 af1_ = *(const bf16x8*)(arp + so_ + 32); \
        _Pragma("unroll") \
        for (int g_ = 0; g_ < 4; ++g_) { \
            const short* brp_ = &Bs[so_ + (g_ * 16 + rl) * 72 + q8]; \
            bf16x8 bb0_ = *(const bf16x8*)brp_; \
            bf16x8 bb1_ = *(const bf16x8*)(brp_ + 32); \
            acc[g_] = mfma16(af0_, bb0_, acc[g_]); \
            acc[g_] = mfma16(af1_, bb1_, acc[g_]); \
        } \
    } \
} while(0)

__global__ __launch_bounds__(256) void fused8_step_kernel(
    const u16* __restrict__ h_base, int h_lda,
    const u16* __restrict__ x_base,
    const int* __restrict__ y,
    const u16* __restrict__ Whh, const u16* __restrict__ Wih,
    const u16* __restrict__ bih, const u16* __restrict__ bhh,
    float* __restrict__ cbuf,
    u16* __restrict__ hout,
    int mode, int t)
{
    __shared__ __align__(16) short As[3 * TSZ_];   // chunk slots 0|1|2
    __shared__ __align__(16) short Bs[3 * TSZ_];
    const int tid = threadIdx.x;
    // XCD-locality remap: linear id -> (bm = lid&7 on XCD lid%8, bn = lid>>3)
    const int lid = blockIdx.x + 32 * blockIdx.y;
    const int bm = lid & 7, bn = lid >> 3;
    const int w = tid >> 6, l = tid & 63, rl = l & 15, q = l >> 4, q8 = q * 8;
    const int srow = tid >> 2, koff = (tid & 3) * 16;
    const int brw = bm * 64 + srow;

    const u16* hp = h_base + (size_t)brw * h_lda + koff;
    size_t xrow;
    if (mode == 0)      xrow = ((size_t)brw * N_ + t) * E_;
    else if (mode == 1) xrow = (size_t)brw * E_;
    else                xrow = ((size_t)brw * N_ + (size_t)y[brw * N_ + t - 1]) * E_;
    const u16* xp = x_base + xrow + koff;

    const int wrow = (srow >> 4) * 512 + bn * 16 + (srow & 15);
    const u16* whp = Whh + (size_t)wrow * H_ + koff;
    const u16* wip = Wih + (size_t)wrow * E_ + koff;

    float bsum[4];
#pragma unroll
    for (int g = 0; g < 4; ++g) {
        int col = g * 512 + bn * 16 + rl;
        bsum[g] = bf2f(bih[col]) + bf2f(bhh[col]);
    }

    f32x4 acc[4];
#pragma unroll
    for (int g = 0; g < 4; ++g) acc[g] = (f32x4){0.f, 0.f, 0.f, 0.f};

    auto srcA = [&](int c) -> const u16* {
        return (c < 8) ? (hp + c * 64) : (xp + (c - 8) * 64);
    };
    auto srcB = [&](int c) -> const u16* {
        return (c < 8) ? (whp + c * 64) : (wip + (c - 8) * 64);
    };

    short* asw0 = &As[srow * 72 + koff];
    short* asw1 = asw0 + TSZ_;
    short* asw2 = asw0 + 2 * TSZ_;
    short* bsw0 = &Bs[srow * 72 + koff];
    short* bsw1 = bsw0 + TSZ_;
    short* bsw2 = bsw0 + 2 * TSZ_;
    const short* arp = &As[(w * 16 + rl) * 72 + q8];

    uint4 xa0, xa1, xa2, xa3, xa4, xa5, xb0, xb1, xb2, xb3, xb4, xb5;
    uint4 ya0, ya1, ya2, ya3, ya4, ya5, yb0, yb1, yb2, yb3, yb4, yb5;

    LOADSET(0, xa0,xa1,xa2,xa3,xa4,xa5, xb0,xb1,xb2,xb3,xb4,xb5);
    LOADSET(3, ya0,ya1,ya2,ya3,ya4,ya5, yb0,yb1,yb2,yb3,yb4,yb5);

    __syncthreads();
    WRITESET(xa0,xa1,xa2,xa3,xa4,xa5, xb0,xb1,xb2,xb3,xb4,xb5);
    __syncthreads();
    LOADSET(6, xa0,xa1,xa2,xa3,xa4,xa5, xb0,xb1,xb2,xb3,xb4,xb5);
    COMPUTE3();
    __syncthreads();
    WRITESET(ya0,ya1,ya2,ya3,ya4,ya5, yb0,yb1,yb2,yb3,yb4,yb5);
    __syncthreads();
    LOADSET(9, ya0,ya1,ya2,ya3,ya4,ya5, yb0,yb1,yb2,yb3,yb4,yb5);
    COMPUTE3();
    __syncthreads();
    WRITESET(xa0,xa1,xa2,xa3,xa4,xa5, xb0,xb1,xb2,xb3,xb4,xb5);
    __syncthreads();
    COMPUTE3();
    __syncthreads();
    WRITESET(ya0,ya1,ya2,ya3,ya4,ya5, yb0,yb1,yb2,yb3,yb4,yb5);
    __syncthreads();
    COMPUTE3();

    const int hcol = bn * 16 + rl;
#pragma unroll
    for (int r = 0; r < 4; ++r) {
        int brow = bm * 64 + w * 16 + q * 4 + r;
        float gi = acc[0][r] + bsum[0];
        float gf = acc[1][r] + bsum[1];
        float gg = acc[2][r] + bsum[2];
        float go = acc[3][r] + bsum[3];
        size_t cidx = (size_t)brow * H_ + hcol;
        float cv = sig_f(gf) * cbuf[cidx] + sig_f(gi) * tanh_f(gg);
        cbuf[cidx] = cv;
        hout[(size_t)brow * (N_ * H_) + hcol] = f2bf(sig_f(go) * tanh_f(cv));
    }
}

// ---------------------------------------------------------------------------
// Head GEMM (R3-proven structure): C = A @ Bw^T + bias, 64x64 tile, BK=32.
__global__ __launch_bounds__(256) void gemm_bt_kernel(
    const u16* __restrict__ A, int lda,
    const u16* __restrict__ Bw,
    const u16* __restrict__ bias,
    u16* __restrict__ C, int ldc, int K)
{
    __shared__ __align__(16) short As[64 * 40];
    __shared__ __align__(16) short Bs[64 * 40];
    const int tid = threadIdx.x;
    const int bn = blockIdx.x, bm = blockIdx.y;
    const int srow = tid >> 2, koff = (tid & 3) * 8;
    const size_t aBase = (size_t)(bm * 64 + srow) * lda + koff;
    const size_t bBase = (size_t)(bn * 64 + srow) * K + koff;
    const int NKT = K >> 5;
    uint4 aReg = *(const uint4*)(A + aBase);
    uint4 bReg = *(const uint4*)(Bw + bBase);
    const int w = tid >> 6, l = tid & 63;
    const int wm = w & 1, wn = w >> 1;
    const int rl = l & 15, q8 = (l >> 4) * 8;
    f32x4 acc00 = {0.f,0.f,0.f,0.f}, acc01 = {0.f,0.f,0.f,0.f};
    f32x4 acc10 = {0.f,0.f,0.f,0.f}, acc11 = {0.f,0.f,0.f,0.f};
    short* asw = &As[srow * 40 + koff];
    short* bsw = &Bs[srow * 40 + koff];
    const short* ar0 = &As[(wm * 32 + rl) * 40 + q8];
    const short* ar1 = &As[(wm * 32 + 16 + rl) * 40 + q8];
    const short* br0 = &Bs[(wn * 32 + rl) * 40 + q8];
    const short* br1 = &Bs[(wn * 32 + 16 + rl) * 40 + q8];
    for (int kt = 0; kt < NKT; ++kt) {
        __syncthreads();
        *(uint4*)asw = aReg;
        *(uint4*)bsw = bReg;
        __syncthreads();
        if (kt + 1 < NKT) {
            aReg = *(const uint4*)(A + aBase + (kt + 1) * 32);
            bReg = *(const uint4*)(Bw + bBase + (kt + 1) * 32);
        }
        bf16x8 a0 = *(const bf16x8*)ar0;
        bf16x8 a1 = *(const bf16x8*)ar1;
        bf16x8 b0 = *(const bf16x8*)br0;
        bf16x8 b1 = *(const bf16x8*)br1;
        acc00 = mfma16(a0, b0, acc00);
        acc01 = mfma16(a0, b1, acc01);
        acc10 = mfma16(a1, b0, acc10);
        acc11 = mfma16(a1, b1, acc11);
    }
    const int col0 = bn * 64 + wn * 32 + rl;
    const int row0 = bm * 64 + wm * 32 + (l >> 4) * 4;
    const float bv0 = bias ? bf2f(bias[col0]) : 0.f;
    const float bv1 = bias ? bf2f(bias[col0 + 16]) : 0.f;
#pragma unroll
    for (int r = 0; r < 4; ++r) {
        C[(size_t)(row0 + r) * ldc + col0]           = f2h_bits(acc00[r] + bv0);
        C[(size_t)(row0 + r) * ldc + col0 + 16]      = f2h_bits(acc01[r] + bv1);
        C[(size_t)(row0 + 16 + r) * ldc + col0]      = f2h_bits(acc10[r] + bv0);
        C[(size_t)(row0 + 16 + r) * ldc + col0 + 16] = f2h_bits(acc11[r] + bv1);
    }
}

// ---------------------------------------------------------------------------
// XCD-locality block remap (R13): with round-robin dispatch, blocks with
// bid%8==k land on XCD k. Map all 100 t-blocks of one b to the SAME XCD so
// u2g[b]/ref[b] (~204 KB) stay in that XCD's 4MB L2 (16 b's x 204KB = 3.3MB).
__device__ __forceinline__ void xcd_bt(int bid, int& b, int& bt) {
    b = ((bid & 7) << 4) + ((bid >> 3) / N_);
    const int t = (bid >> 3) % N_;
    bt = b * N_ + t;
}

// Glimpse v10 (verified R13): 128 thr + XCD-locality remap.
__global__ __launch_bounds__(128) void glimpse_kernel(
    const u16* __restrict__ q1, const u16* __restrict__ u2g,
    const u16* __restrict__ ref, const u16* __restrict__ Vec,
    const unsigned char* __restrict__ mask, u16* __restrict__ query2)
{
    int b, bt;
    xcd_bt(blockIdx.x, b, bt);
    const int tid = threadIdx.x, w = tid >> 6, l = tid & 63;
    const int g16 = l >> 4, l16 = l & 15;
    __shared__ float u_s[N_], a_s[N_], red[4];
    __shared__ short list[N_];
    __shared__ int wcnt[2], cnt_s;
    __shared__ __align__(16) float pv_s[2][H_];   // 4 KB PV partials
    const int h32 = l16 * 32;                     // scoring slice (16 lanes/n)
    const int h0 = l * 8;                         // PV slice (64 lanes)
    // ---- preload q and Vec 32-elem slices (scoring) ----
    h2 qh[16], vh[16];
    {
        const u16* qp = q1 + (size_t)bt * H_ + h32;
        toh2x4(*(const uint4*)qp,        qh);
        toh2x4(*(const uint4*)(qp + 8),  qh + 4);
        toh2x4(*(const uint4*)(qp + 16), qh + 8);
        toh2x4(*(const uint4*)(qp + 24), qh + 12);
        const u16* vp = Vec + h32;
#pragma unroll
        for (int m = 0; m < 4; ++m) {
            float vf[8]; unpack8(*(const uint4*)(vp + m * 8), vf);
#pragma unroll
            for (int j = 0; j < 4; ++j)
                vh[m * 4 + j] = (h2){ (f16t)vf[2 * j], (f16t)vf[2 * j + 1] };
        }
    }
    bool un = false;
    if (tid < N_) {
        un = (mask[(size_t)bt * N_ + tid] == 0);
        u_s[tid] = -3.0e38f;                 // init ALL entries (R6 scar)
    }
    unsigned long long bal = __ballot(un);
    if (l == 0) wcnt[w] = __popcll(bal);
    __syncthreads();
    const int base = (w == 1) ? wcnt[0] : 0;
    const int pos = __popcll(bal & ((1ULL << l) - 1ULL));
    if (un) list[base + pos] = (short)tid;
    if (tid == 0) cnt_s = wcnt[0] + wcnt[1];
    __syncthreads();
    const int cnt = cnt_s;
    const u16* ub = u2g + (size_t)b * N_ * H_;
    // ---- scoring: group (w,g16) handles k = w*4+g16 (mod 8) ----
    for (int k = w * 4 + g16; k < cnt; k += 8) {
        const int n = list[k];
        const u16* up = ub + (size_t)n * H_ + h32;
        h2 uh[16];
        toh2x4(*(const uint4*)up,        uh);
        toh2x4(*(const uint4*)(up + 8),  uh + 4);
        toh2x4(*(const uint4*)(up + 16), uh + 8);
        toh2x4(*(const uint4*)(up + 24), uh + 12);
        float sa = 0.f, sb = 0.f, sc = 0.f, sd = 0.f;
#pragma unroll
        for (int j = 0; j < 4; ++j) {
            sa = tanhdot_h2(uh[j],      qh[j],      vh[j],      sa);
            sb = tanhdot_h2(uh[4 + j],  qh[4 + j],  vh[4 + j],  sb);
            sc = tanhdot_h2(uh[8 + j],  qh[8 + j],  vh[8 + j],  sc);
            sd = tanhdot_h2(uh[12 + j], qh[12 + j], vh[12 + j], sd);
        }
        float s = (sa + sb) + (sc + sd);
#pragma unroll
        for (int off = 8; off > 0; off >>= 1) s += __shfl_xor(s, off, 64);
        if (l16 == 0) u_s[n] = s;
    }
    __syncthreads();
    float v = un ? u_s[tid] : -3.0e38f;
    float m = v;
#pragma unroll
    for (int off = 32; off > 0; off >>= 1) m = fmaxf(m, __shfl_xor(m, off, 64));
    if (l == 0) red[w] = m;
    __syncthreads();
    float mx = fmaxf(red[0], red[1]);
    float e = un ? __expf(v - mx) : 0.f;
    float s2 = e;
#pragma unroll
    for (int off = 32; off > 0; off >>= 1) s2 += __shfl_xor(s2, off, 64);
    if (l == 0) red[2 + w] = s2;
    __syncthreads();
    float inv = __fdividef(1.f, red[2] + red[3]);
    if (tid < N_) a_s[tid] = e * inv;
    __syncthreads();
    // ---- PV split-k: wave w sums k == w (mod 2); lane owns h0..h0+7 ----
    const u16* refb = ref + (size_t)b * N_ * H_;
    float pacc[8] = {0.f, 0.f, 0.f, 0.f, 0.f, 0.f, 0.f, 0.f};
    for (int k = w; k < cnt; k += 2) {
        const int n = list[k];
        const float a = a_s[n];
        float rv[8];
        unpack8(*(const uint4*)(refb + (size_t)n * H_ + h0), rv);
#pragma unroll
        for (int j = 0; j < 8; ++j) pacc[j] = fmaf(a, rv[j], pacc[j]);
    }
    {
        float4 pa0 = {pacc[0], pacc[1], pacc[2], pacc[3]};
        float4 pa1 = {pacc[4], pacc[5], pacc[6], pacc[7]};
        *(float4*)&pv_s[w][h0]     = pa0;
        *(float4*)&pv_s[w][h0 + 4] = pa1;
    }
    __syncthreads();
    const int hh = tid * 4;                       // 128 threads x 4 elems
    float s0 = pv_s[0][hh]     + pv_s[1][hh];
    float s1 = pv_s[0][hh + 1] + pv_s[1][hh + 1];
    float s2b = pv_s[0][hh + 2] + pv_s[1][hh + 2];
    float s3 = pv_s[0][hh + 3] + pv_s[1][hh + 3];
    uint2 packed;
    packed.x = ((unsigned)f2bf(s1) << 16) | (unsigned)f2bf(s0);
    packed.y = ((unsigned)f2bf(s3) << 16) | (unsigned)f2bf(s2b);
    *(uint2*)(query2 + (size_t)bt * H_ + hh) = packed;
}

// Pointer head v9 (verified R13): 128 thr + XCD-locality remap.
__global__ __launch_bounds__(128) void final_attn_kernel(
    const u16* __restrict__ q2, const u16* __restrict__ u2p,
    const u16* __restrict__ Vec2, const unsigned char* __restrict__ mask,
    const int* __restrict__ y, float* __restrict__ ll, float* __restrict__ ps)
{
    int b, bt;
    xcd_bt(blockIdx.x, b, bt);
    const int tid = threadIdx.x, w = tid >> 6, l = tid & 63;
    const int g16 = l >> 4, l16 = l & 15;
    __shared__ float u_s[N_], lp_s[N_], red[4];
    __shared__ short list[N_];
    __shared__ unsigned char msk[128];
    __shared__ int wcnt[2], cnt_s;
    const int h32 = l16 * 32;
    h2 qh[16], vh[16];
    {
        const u16* qp = q2 + (size_t)bt * H_ + h32;
        toh2x4(*(const uint4*)qp,        qh);
        toh2x4(*(const uint4*)(qp + 8),  qh + 4);
        toh2x4(*(const uint4*)(qp + 16), qh + 8);
        toh2x4(*(const uint4*)(qp + 24), qh + 12);
        const u16* vp = Vec2 + h32;
#pragma unroll
        for (int m = 0; m < 4; ++m) {
            float vf[8]; unpack8(*(const uint4*)(vp + m * 8), vf);
#pragma unroll
            for (int j = 0; j < 4; ++j)
                vh[m * 4 + j] = (h2){ (f16t)vf[2 * j], (f16t)vf[2 * j + 1] };
        }
    }
    bool un = false;
    msk[tid] = (tid < N_) ? mask[(size_t)bt * N_ + tid] : 1;
    if (tid < N_) {
        un = (msk[tid] == 0);
        u_s[tid] = 0.f;
    }
    unsigned long long bal = __ballot(un);
    if (l == 0) wcnt[w] = __popcll(bal);
    __syncthreads();
    const int base = (w == 1) ? wcnt[0] : 0;
    const int pos = __popcll(bal & ((1ULL << l) - 1ULL));
    if (un) list[base + pos] = (short)tid;
    if (tid == 0) cnt_s = wcnt[0] + wcnt[1];
    __syncthreads();
    const int cnt = cnt_s;
    const u16* ub = u2p + (size_t)b * N_ * H_;
    for (int k = w * 4 + g16; k < cnt; k += 8) {
        const int n = list[k];
        const u16* up = ub + (size_t)n * H_ + h32;
        h2 uh[16];
        toh2x4(*(const uint4*)up,        uh);
        toh2x4(*(const uint4*)(up + 8),  uh + 4);
        toh2x4(*(const uint4*)(up + 16), uh + 8);
        toh2x4(*(const uint4*)(up + 24), uh + 12);
        float sa = 0.f, sb = 0.f, sc = 0.f, sd = 0.f;
#pragma unroll
        for (int j = 0; j < 4; ++j) {
            sa = tanhdot_h2(uh[j],      qh[j],      vh[j],      sa);
            sb = tanhdot_h2(uh[4 + j],  qh[4 + j],  vh[4 + j],  sb);
            sc = tanhdot_h2(uh[8 + j],  qh[8 + j],  vh[8 + j],  sc);
            sd = tanhdot_h2(uh[12 + j], qh[12 + j], vh[12 + j], sd);
        }
        float s = (sa + sb) + (sc + sd);
#pragma unroll
        for (int off = 8; off > 0; off >>= 1) s += __shfl_xor(s, off, 64);
        if (l16 == 0) u_s[n] = s;
    }
    __syncthreads();
    float lg = -3.0e38f;
    if (tid < N_) {
        unsigned char c = msk[tid];
        if (c) lg = -1e8f * (float)c;
        else   lg = 10.f * tanh_poly(u_s[tid]);
    }
    float m = lg;
#pragma unroll
    for (int off = 32; off > 0; off >>= 1) m = fmaxf(m, __shfl_xor(m, off, 64));
    if (l == 0) red[w] = m;
    __syncthreads();
    float mx = fmaxf(red[0], red[1]);
    float e = (tid < N_) ? __expf(lg - mx) : 0.f;
    float s2 = e;
#pragma unroll
    for (int off = 32; off > 0; off >>= 1) s2 += __shfl_xor(s2, off, 64);
    if (l == 0) red[2 + w] = s2;
    __syncthreads();
    float lse = mx + __logf(red[2] + red[3]);
    if (tid < N_) {
        float lp = lg - lse;
        ps[(size_t)bt * N_ + tid] = lp;
        lp_s[tid] = lp;
    }
    __syncthreads();
    if (tid == 0) atomicAdd(&ll[b], lp_s[y[bt]]);
}

// outputs (float32): pi = float(y); ll from f32 accumulator
__global__ void write_out_kernel(const int* __restrict__ y, const float* __restrict__ ll,
                                 float* __restrict__ out) {
    int i = blockIdx.x * 256 + threadIdx.x;   // 51200 threads
    if (i < BT_) out[i] = (float)y[i];
    if (i < B_)  out[BT_ + i] = ll[i];
}

// ---------------------------------------------------------------------------
extern "C" void kernel_launch(void* const* d_in, const int* in_sizes, int n_in,
                              void* d_out, int out_size, void* d_ws, size_t ws_size,
                              hipStream_t stream)
{
    const u16* x        = (const u16*)d_in[0];
    const int* y        = (const int*)d_in[1];
    const u16* emb_W    = (const u16*)d_in[2];
    const u16* enc_Wih  = (const u16*)d_in[3];
    const u16* enc_Whh  = (const u16*)d_in[4];
    const u16* enc_bih  = (const u16*)d_in[5];
    const u16* enc_bhh  = (const u16*)d_in[6];
    const u16* dec_Wih  = (const u16*)d_in[7];
    const u16* dec_Whh  = (const u16*)d_in[8];
    const u16* dec_bih  = (const u16*)d_in[9];
    const u16* dec_bhh  = (const u16*)d_in[10];
    const u16* Vec      = (const u16*)d_in[11];
    const u16* Vec2     = (const u16*)d_in[12];
    const u16* Wq_W     = (const u16*)d_in[13];
    const u16* Wq_b     = (const u16*)d_in[14];
    const u16* Wref_W   = (const u16*)d_in[15];
    const u16* Wref_b   = (const u16*)d_in[16];
    const u16* Wq2_W    = (const u16*)d_in[17];
    const u16* Wq2_b    = (const u16*)d_in[18];
    const u16* Wref2_W  = (const u16*)d_in[19];
    const u16* Wref2_b  = (const u16*)d_in[20];
    const u16* dec0     = (const u16*)d_in[21];

    char* p = (char*)d_ws;
    auto carve = [&](size_t bytes) -> char* {
        char* r = p; p += (bytes + 255) & ~(size_t)255; return r;
    };
    u16*   embed     = (u16*)  carve((size_t)BT_ * E_ * 2);      // 26.21 MB
    float* cbuf      = (float*)carve((size_t)B_ * H_ * 4);       //  1.05 MB
    u16*   zero_h    = (u16*)  carve((size_t)B_ * H_ * 2);       //  0.52 MB
    u16*   dec0_rows = (u16*)  carve((size_t)B_ * E_ * 2);       //  0.26 MB
    u16*   ref       = (u16*)  carve((size_t)BT_ * H_ * 2);      // 52.43 MB
    u16*   dec_hs    = (u16*)  carve((size_t)BT_ * H_ * 2);      // 52.43 MB (later: qry2)
    unsigned char* maskb = (unsigned char*)carve((size_t)BT_ * N_); // 5.12 MB
    float* llb       = (float*)carve((size_t)B_ * 4);
    const size_t need = (size_t)(p - (char*)d_ws);
    u16* Ybuf = embed;                                  // u2g / u2p chunk (f16)
    u16* Zbuf = embed + (size_t)BC_ * N_ * H_;          // q1 / q2 chunk (f16)

    if (need > ws_size) {
        sentinel_kernel<<<(B_ + 255) / 256, 256, 0, stream>>>((float*)d_out);
        return;
    }

    init_kernel<<<(B_ * H_) / 256, 256, 0, stream>>>(cbuf, zero_h, llb, dec0_rows, dec0);
    embed_kernel<<<BT_, 256, 0, stream>>>(x, emb_W, embed);
    mask_kernel<<<B_, 128, 0, stream>>>(y, maskb);

    // ---- LSTM steps: multi-launch, fused8+XCD (BK=192, depth-2 prefetch) ----
    dim3 sgrid(32, 8);   // linearized then remapped in-kernel
    for (int t = 0; t < N_; ++t) {
        const u16* hb = (t == 0) ? zero_h : (ref + (size_t)(t - 1) * H_);
        int hlda = (t == 0) ? H_ : (N_ * H_);
        fused8_step_kernel<<<sgrid, 256, 0, stream>>>(hb, hlda, embed, y,
                                                      enc_Whh, enc_Wih, enc_bih, enc_bhh,
                                                      cbuf, ref + (size_t)t * H_, 0, t);
    }
    for (int t = 0; t < N_; ++t) {
        const u16* hb = (t == 0) ? (ref + (size_t)(N_ - 1) * H_) : (dec_hs + (size_t)(t - 1) * H_);
        const u16* xb = (t == 0) ? dec0_rows : embed;
        int mode = (t == 0) ? 1 : 2;
        fused8_step_kernel<<<sgrid, 256, 0, stream>>>(hb, N_ * H_, xb, y,
                                                      dec_Whh, dec_Wih, dec_bih, dec_bhh,
                                                      cbuf, dec_hs + (size_t)t * H_, mode, t);
    }

    // ---- batched attention, chunked over batch (embed now dead) ----
    float* out = (float*)d_out;
    const int MC = BC_ * N_;                     // 12800 rows per chunk
    dim3 cgrid(H_ / 64, MC / 64);                // (8, 200)
    for (int c = 0; c < NCHUNK_; ++c) {
        const size_t rowOff = (size_t)c * BC_ * N_ * H_;
        const size_t btOff  = (size_t)c * BC_ * N_;
        gemm_bt_kernel<<<cgrid, 256, 0, stream>>>(dec_hs + rowOff, H_, Wq_W,  Wq_b,  Zbuf, H_, H_);
        gemm_bt_kernel<<<cgrid, 256, 0, stream>>>(ref + rowOff,    H_, Wref_W, Wref_b, Ybuf, H_, H_);
        glimpse_kernel<<<MC, 128, 0, stream>>>(Zbuf, Ybuf, ref + rowOff, Vec,
                                               maskb + btOff * N_, dec_hs + rowOff);
        gemm_bt_kernel<<<cgrid, 256, 0, stream>>>(dec_hs + rowOff, H_, Wq2_W, Wq2_b, Zbuf, H_, H_);
        gemm_bt_kernel<<<cgrid, 256, 0, stream>>>(ref + rowOff,    H_, Wref2_W, Wref2_b, Ybuf, H_, H_);
        final_attn_kernel<<<MC, 128, 0, stream>>>(Zbuf, Ybuf, Vec2, maskb + btOff * N_,
                                                  y + btOff, llb + (size_t)c * BC_,
                                                  out + BT_ + B_ + btOff * N_);
    }
    write_out_kernel<<<BT_ / 256, 256, 0, stream>>>(y, llb, out);
}

// Round 15
// 2526.626 us; speedup vs baseline: 1.2699x; 1.0501x over previous
//
#include <hip/hip_runtime.h>
#include <hip/hip_bf16.h>
#include <stdint.h>

typedef unsigned short u16;
typedef __bf16 bf16t;
typedef _Float16 f16t;
typedef __attribute__((ext_vector_type(8))) bf16t bf16x8;
typedef __attribute__((ext_vector_type(4))) float f32x4;
typedef __attribute__((ext_vector_type(2))) _Float16 h2;

#define B_   512
#define N_   100
#define P_   20
#define E_   256
#define H_   512
#define G4H_ 2048
#define BT_  (B_ * N_)   // 51200
#define BC_  128         // phase-B batch chunk
#define NCHUNK_ (B_ / BC_)
#define TSZ_ 4608        // 64*72 shorts per LDS tile chunk (9216 B)

__device__ __forceinline__ float bfu2f(unsigned u) {
    union { unsigned i; float f; } v; v.i = u << 16; return v.f;
}
__device__ __forceinline__ float bf2f(u16 x) { return bfu2f((unsigned)x); }
__device__ __forceinline__ u16 f2bf(float f) {
    union { float f; unsigned i; } v; v.f = f;
    unsigned r = v.i + 0x7FFFu + ((v.i >> 16) & 1u);
    return (u16)(r >> 16);
}
__device__ __forceinline__ u16 f2h_bits(float f) {
    union { f16t h; u16 u; } c; c.h = (f16t)f; return c.u;
}
__device__ __forceinline__ void unpack8(uint4 r, float* o) {
    o[0] = bfu2f(r.x & 0xffffu); o[1] = bfu2f(r.x >> 16);
    o[2] = bfu2f(r.y & 0xffffu); o[3] = bfu2f(r.y >> 16);
    o[4] = bfu2f(r.z & 0xffffu); o[5] = bfu2f(r.z >> 16);
    o[6] = bfu2f(r.w & 0xffffu); o[7] = bfu2f(r.w >> 16);
}
__device__ __forceinline__ void toh2x4(uint4 r, h2* o) {
    union { uint4 u; h2 h[4]; } c; c.u = r;
    o[0] = c.h[0]; o[1] = c.h[1]; o[2] = c.h[2]; o[3] = c.h[3];
}
__device__ __forceinline__ float tanh_f(float x) {
    x = fminf(15.f, fmaxf(-15.f, x));
    float e = __expf(2.f * x);
    return __fdividef(e - 1.f, e + 1.f);
}
__device__ __forceinline__ float sig_f(float x) {
    x = fminf(15.f, fmaxf(-15.f, x));
    return __fdividef(1.f, 1.f + __expf(-x));
}
// f32 polynomial tanh (clamped both ends) — used on the per-n final logit only
__device__ __forceinline__ float tanh_poly(float x) {
    x = fminf(3.25f, fmaxf(-3.25f, x));
    float z = x * x;
    float p = fmaf(fmaf(fmaf(-0.0018661f, z, 0.037231f), z, -0.249208f), z, 0.984238f);
    float r = x * p;
    return fminf(1.0f, fmaxf(-1.0f, r));
}
// packed-f16 tanh-dot step: s += dot2(vh, tanh_pk(qh + uh)).
__device__ __forceinline__ float tanhdot_h2(h2 uh, h2 qh, h2 vh, float s) {
    const h2 kLo = { (f16t)-3.25f, (f16t)-3.25f };
    const h2 kHi = { (f16t)3.25f,  (f16t)3.25f };
    const h2 c3 = { (f16t)-0.0018661f, (f16t)-0.0018661f };
    const h2 c2 = { (f16t)0.037231f,   (f16t)0.037231f };
    const h2 c1 = { (f16t)-0.249208f,  (f16t)-0.249208f };
    const h2 c0 = { (f16t)0.984238f,   (f16t)0.984238f };
    h2 t = uh + qh;
    t = __builtin_elementwise_max(t, kLo);
    t = __builtin_elementwise_min(t, kHi);
    h2 z = t * t;
    h2 p = __builtin_elementwise_fma(c3, z, c2);
    p = __builtin_elementwise_fma(p, z, c1);
    p = __builtin_elementwise_fma(p, z, c0);
    h2 r = t * p;
#if defined(__has_builtin) && __has_builtin(__builtin_amdgcn_fdot2)
    return __builtin_amdgcn_fdot2(r, vh, s, false);
#else
    return s + (float)r.x * (float)vh.x + (float)r.y * (float)vh.y;
#endif
}
__device__ __forceinline__ f32x4 mfma16(bf16x8 a, bf16x8 b, f32x4 c) {
    return __builtin_amdgcn_mfma_f32_16x16x32_bf16(a, b, c, 0, 0, 0);
}

// ---------------------------------------------------------------------------
__global__ void sentinel_kernel(float* out) {
    int i = blockIdx.x * 256 + threadIdx.x;
    if (i < B_) out[BT_ + i] = 1.0e9f;   // signals "workspace too small"
}

// init: zero c, zero_h, ll; broadcast dec_input0 rows
__global__ void init_kernel(float* c, u16* zero_h, float* ll, u16* dec0_rows,
                            const u16* __restrict__ dec0) {
    int i = blockIdx.x * 256 + threadIdx.x;          // 262144 threads
    if (i < B_ * H_) { c[i] = 0.f; zero_h[i] = 0; }
    if (i < B_) ll[i] = 0.f;
    if (i < B_ * E_) dec0_rows[i] = dec0[i & (E_ - 1)];
}

// embed[b,n,e] = sum_p x[b,n,p] * emb_W[e,p]
__global__ void embed_kernel(const u16* __restrict__ x, const u16* __restrict__ emb_W,
                             u16* __restrict__ embed) {
    __shared__ float xs[P_];
    int bt = blockIdx.x, tid = threadIdx.x;
    if (tid < P_) xs[tid] = bf2f(x[(size_t)bt * P_ + tid]);
    __syncthreads();
    float s = 0.f;
#pragma unroll
    for (int p = 0; p < P_; ++p) s += xs[p] * bf2f(emb_W[tid * P_ + p]);
    embed[(size_t)bt * E_ + tid] = f2bf(s);
}

// mask[b,t,n] = #{s<t : y[b,s]==n}   (cumulative COUNT, y may repeat)
__global__ void mask_kernel(const int* __restrict__ y, unsigned char* __restrict__ mask) {
    int b = blockIdx.x, n = threadIdx.x;
    if (n >= N_) return;
    unsigned char cnt = 0;
    for (int t = 0; t < N_; ++t) {
        mask[((size_t)b * N_ + t) * N_ + n] = cnt;
        if (y[b * N_ + t] == n) cnt++;
    }
}

// ---------------------------------------------------------------------------
// Fused LSTM step v9 (verified R14): fused8 + XCD-locality remap (bm=lid&7).
#define LOADSET(c0, A0,A1,A2,A3,A4,A5,B0,B1,B2,B3,B4,B5) do { \
    const u16* sa0_ = srcA(c0); const u16* sa1_ = srcA((c0)+1); const u16* sa2_ = srcA((c0)+2); \
    const u16* sb0_ = srcB(c0); const u16* sb1_ = srcB((c0)+1); const u16* sb2_ = srcB((c0)+2); \
    A0 = *(const uint4*)sa0_; A1 = *(const uint4*)(sa0_ + 8); \
    A2 = *(const uint4*)sa1_; A3 = *(const uint4*)(sa1_ + 8); \
    A4 = *(const uint4*)sa2_; A5 = *(const uint4*)(sa2_ + 8); \
    B0 = *(const uint4*)sb0_; B1 = *(const uint4*)(sb0_ + 8); \
    B2 = *(const uint4*)sb1_; B3 = *(const uint4*)(sb1_ + 8); \
    B4 = *(const uint4*)sb2_; B5 = *(const uint4*)(sb2_ + 8); \
} while(0)

#define WRITESET(A0,A1,A2,A3,A4,A5,B0,B1,B2,B3,B4,B5) do { \
    *(uint4*)asw0 = A0;  *(uint4*)(asw0 + 8) = A1; \
    *(uint4*)asw1 = A2;  *(uint4*)(asw1 + 8) = A3; \
    *(uint4*)asw2 = A4;  *(uint4*)(asw2 + 8) = A5; \
    *(uint4*)bsw0 = B0;  *(uint4*)(bsw0 + 8) = B1; \
    *(uint4*)bsw1 = B2;  *(uint4*)(bsw1 + 8) = B3; \
    *(uint4*)bsw2 = B4;  *(uint4*)(bsw2 + 8) = B5; \
} while(0)

#define COMPUTE3() do { \
    _Pragma("unroll") \
    for (int s_ = 0; s_ < 3; ++s_) { \
        const int so_ = s_ * TSZ_; \
        bf16x8 af0_ = *(const bf16x8*)(arp + so_); \
        bf16x8 af1_ = *(const bf16x8*)(arp + so_ + 32); \
        _Pragma("unroll") \
        for (int g_ = 0; g_ < 4; ++g_) { \
            const short* brp_ = &Bs[so_ + (g_ * 16 + rl) * 72 + q8]; \
            bf16x8 bb0_ = *(const bf16x8*)brp_; \
            bf16x8 bb1_ = *(const bf16x8*)(brp_ + 32); \
            acc[g_] = mfma16(af0_, bb0_, acc[g_]); \
            acc[g_] = mfma16(af1_, bb1_, acc[g_]); \
        } \
    } \
} while(0)

__global__ __launch_bounds__(256) void fused8_step_kernel(
    const u16* __restrict__ h_base, int h_lda,
    const u16* __restrict__ x_base,
    const int* __restrict__ y,
    const u16* __restrict__ Whh, const u16* __restrict__ Wih,
    const u16* __restrict__ bih, const u16* __restrict__ bhh,
    float* __restrict__ cbuf,
    u16* __restrict__ hout,
    int mode, int t)
{
    __shared__ __align__(16) short As[3 * TSZ_];   // chunk slots 0|1|2
    __shared__ __align__(16) short Bs[3 * TSZ_];
    const int tid = threadIdx.x;
    // XCD-locality remap: linear id -> (bm = lid&7 on XCD lid%8, bn = lid>>3)
    const int lid = blockIdx.x + 32 * blockIdx.y;
    const int bm = lid & 7, bn = lid >> 3;
    const int w = tid >> 6, l = tid & 63, rl = l & 15, q = l >> 4, q8 = q * 8;
    const int srow = tid >> 2, koff = (tid & 3) * 16;
    const int brw = bm * 64 + srow;

    const u16* hp = h_base + (size_t)brw * h_lda + koff;
    size_t xrow;
    if (mode == 0)      xrow = ((size_t)brw * N_ + t) * E_;
    else if (mode == 1) xrow = (size_t)brw * E_;
    else                xrow = ((size_t)brw * N_ + (size_t)y[brw * N_ + t - 1]) * E_;
    const u16* xp = x_base + xrow + koff;

    const int wrow = (srow >> 4) * 512 + bn * 16 + (srow & 15);
    const u16* whp = Whh + (size_t)wrow * H_ + koff;
    const u16* wip = Wih + (size_t)wrow * E_ + koff;

    float bsum[4];
#pragma unroll
    for (int g = 0; g < 4; ++g) {
        int col = g * 512 + bn * 16 + rl;
        bsum[g] = bf2f(bih[col]) + bf2f(bhh[col]);
    }

    f32x4 acc[4];
#pragma unroll
    for (int g = 0; g < 4; ++g) acc[g] = (f32x4){0.f, 0.f, 0.f, 0.f};

    auto srcA = [&](int c) -> const u16* {
        return (c < 8) ? (hp + c * 64) : (xp + (c - 8) * 64);
    };
    auto srcB = [&](int c) -> const u16* {
        return (c < 8) ? (whp + c * 64) : (wip + (c - 8) * 64);
    };

    short* asw0 = &As[srow * 72 + koff];
    short* asw1 = asw0 + TSZ_;
    short* asw2 = asw0 + 2 * TSZ_;
    short* bsw0 = &Bs[srow * 72 + koff];
    short* bsw1 = bsw0 + TSZ_;
    short* bsw2 = bsw0 + 2 * TSZ_;
    const short* arp = &As[(w * 16 + rl) * 72 + q8];

    uint4 xa0, xa1, xa2, xa3, xa4, xa5, xb0, xb1, xb2, xb3, xb4, xb5;
    uint4 ya0, ya1, ya2, ya3, ya4, ya5, yb0, yb1, yb2, yb3, yb4, yb5;

    LOADSET(0, xa0,xa1,xa2,xa3,xa4,xa5, xb0,xb1,xb2,xb3,xb4,xb5);
    LOADSET(3, ya0,ya1,ya2,ya3,ya4,ya5, yb0,yb1,yb2,yb3,yb4,yb5);

    __syncthreads();
    WRITESET(xa0,xa1,xa2,xa3,xa4,xa5, xb0,xb1,xb2,xb3,xb4,xb5);
    __syncthreads();
    LOADSET(6, xa0,xa1,xa2,xa3,xa4,xa5, xb0,xb1,xb2,xb3,xb4,xb5);
    COMPUTE3();
    __syncthreads();
    WRITESET(ya0,ya1,ya2,ya3,ya4,ya5, yb0,yb1,yb2,yb3,yb4,yb5);
    __syncthreads();
    LOADSET(9, ya0,ya1,ya2,ya3,ya4,ya5, yb0,yb1,yb2,yb3,yb4,yb5);
    COMPUTE3();
    __syncthreads();
    WRITESET(xa0,xa1,xa2,xa3,xa4,xa5, xb0,xb1,xb2,xb3,xb4,xb5);
    __syncthreads();
    COMPUTE3();
    __syncthreads();
    WRITESET(ya0,ya1,ya2,ya3,ya4,ya5, yb0,yb1,yb2,yb3,yb4,yb5);
    __syncthreads();
    COMPUTE3();

    const int hcol = bn * 16 + rl;
#pragma unroll
    for (int r = 0; r < 4; ++r) {
        int brow = bm * 64 + w * 16 + q * 4 + r;
        float gi = acc[0][r] + bsum[0];
        float gf = acc[1][r] + bsum[1];
        float gg = acc[2][r] + bsum[2];
        float go = acc[3][r] + bsum[3];
        size_t cidx = (size_t)brow * H_ + hcol;
        float cv = sig_f(gf) * cbuf[cidx] + sig_f(gi) * tanh_f(gg);
        cbuf[cidx] = cv;
        hout[(size_t)brow * (N_ * H_) + hcol] = f2bf(sig_f(go) * tanh_f(cv));
    }
}

// ---------------------------------------------------------------------------
// Dual head GEMM (R15): two independent C = A @ Bw^T + bias gemms (same
// shape, M=12800, K=H) fused in one launch, grid (8,400) = 3200 blocks.
// XCD remap: lid = bx + 8*by; c = lid&7; bmall = c*50 + ((lid>>3)>>3);
// bn = (lid>>3)&7  — bijective; all 8 bn-blocks sharing an A-row panel land
// on XCD c, so the panel is read into ONE L2 instead of 8 L3 fetches.
// Per-block tiling/MFMA order byte-identical to verified gemm_bt.
__global__ __launch_bounds__(256) void gemm_bt2_kernel(
    const u16* __restrict__ A1, const u16* __restrict__ Bw1,
    const u16* __restrict__ bias1, u16* __restrict__ C1,
    const u16* __restrict__ A2, const u16* __restrict__ Bw2,
    const u16* __restrict__ bias2, u16* __restrict__ C2)
{
    __shared__ __align__(16) short As[64 * 40];
    __shared__ __align__(16) short Bs[64 * 40];
    const int tid = threadIdx.x;
    const int lid = blockIdx.x + 8 * blockIdx.y;
    const int c = lid & 7;
    const int rest = lid >> 3;                 // [0,400)
    const int bmall = c * 50 + (rest >> 3);    // [0,400) bijective
    const int bn = rest & 7;
    const u16* A;  const u16* Bw; const u16* bias; u16* C; int bm;
    if (bmall < 200) { A = A1; Bw = Bw1; bias = bias1; C = C1; bm = bmall; }
    else             { A = A2; Bw = Bw2; bias = bias2; C = C2; bm = bmall - 200; }

    const int srow = tid >> 2, koff = (tid & 3) * 8;
    const size_t aBase = (size_t)(bm * 64 + srow) * H_ + koff;
    const size_t bBase = (size_t)(bn * 64 + srow) * H_ + koff;
    const int NKT = H_ >> 5;                   // 16
    uint4 aReg = *(const uint4*)(A + aBase);
    uint4 bReg = *(const uint4*)(Bw + bBase);
    const int w = tid >> 6, l = tid & 63;
    const int wm = w & 1, wn = w >> 1;
    const int rl = l & 15, q8 = (l >> 4) * 8;
    f32x4 acc00 = {0.f,0.f,0.f,0.f}, acc01 = {0.f,0.f,0.f,0.f};
    f32x4 acc10 = {0.f,0.f,0.f,0.f}, acc11 = {0.f,0.f,0.f,0.f};
    short* asw = &As[srow * 40 + koff];
    short* bsw = &Bs[srow * 40 + koff];
    const short* ar0 = &As[(wm * 32 + rl) * 40 + q8];
    const short* ar1 = &As[(wm * 32 + 16 + rl) * 40 + q8];
    const short* br0 = &Bs[(wn * 32 + rl) * 40 + q8];
    const short* br1 = &Bs[(wn * 32 + 16 + rl) * 40 + q8];
    for (int kt = 0; kt < NKT; ++kt) {
        __syncthreads();
        *(uint4*)asw = aReg;
        *(uint4*)bsw = bReg;
        __syncthreads();
        if (kt + 1 < NKT) {
            aReg = *(const uint4*)(A + aBase + (kt + 1) * 32);
            bReg = *(const uint4*)(Bw + bBase + (kt + 1) * 32);
        }
        bf16x8 a0 = *(const bf16x8*)ar0;
        bf16x8 a1 = *(const bf16x8*)ar1;
        bf16x8 b0 = *(const bf16x8*)br0;
        bf16x8 b1 = *(const bf16x8*)br1;
        acc00 = mfma16(a0, b0, acc00);
        acc01 = mfma16(a0, b1, acc01);
        acc10 = mfma16(a1, b0, acc10);
        acc11 = mfma16(a1, b1, acc11);
    }
    const int col0 = bn * 64 + wn * 32 + rl;
    const int row0 = bm * 64 + wm * 32 + (l >> 4) * 4;
    const float bv0 = bf2f(bias[col0]);
    const float bv1 = bf2f(bias[col0 + 16]);
#pragma unroll
    for (int r = 0; r < 4; ++r) {
        C[(size_t)(row0 + r) * H_ + col0]           = f2h_bits(acc00[r] + bv0);
        C[(size_t)(row0 + r) * H_ + col0 + 16]      = f2h_bits(acc01[r] + bv1);
        C[(size_t)(row0 + 16 + r) * H_ + col0]      = f2h_bits(acc10[r] + bv0);
        C[(size_t)(row0 + 16 + r) * H_ + col0 + 16] = f2h_bits(acc11[r] + bv1);
    }
}

// ---------------------------------------------------------------------------
// XCD-locality block remap (R13): with round-robin dispatch, blocks with
// bid%8==k land on XCD k. Map all 100 t-blocks of one b to the SAME XCD so
// u2g[b]/ref[b] (~204 KB) stay in that XCD's 4MB L2 (16 b's x 204KB = 3.3MB).
__device__ __forceinline__ void xcd_bt(int bid, int& b, int& bt) {
    b = ((bid & 7) << 4) + ((bid >> 3) / N_);
    const int t = (bid >> 3) % N_;
    bt = b * N_ + t;
}

// Glimpse v10 (verified R13): 128 thr + XCD-locality remap.
__global__ __launch_bounds__(128) void glimpse_kernel(
    const u16* __restrict__ q1, const u16* __restrict__ u2g,
    const u16* __restrict__ ref, const u16* __restrict__ Vec,
    const unsigned char* __restrict__ mask, u16* __restrict__ query2)
{
    int b, bt;
    xcd_bt(blockIdx.x, b, bt);
    const int tid = threadIdx.x, w = tid >> 6, l = tid & 63;
    const int g16 = l >> 4, l16 = l & 15;
    __shared__ float u_s[N_], a_s[N_], red[4];
    __shared__ short list[N_];
    __shared__ int wcnt[2], cnt_s;
    __shared__ __align__(16) float pv_s[2][H_];   // 4 KB PV partials
    const int h32 = l16 * 32;                     // scoring slice (16 lanes/n)
    const int h0 = l * 8;                         // PV slice (64 lanes)
    // ---- preload q and Vec 32-elem slices (scoring) ----
    h2 qh[16], vh[16];
    {
        const u16* qp = q1 + (size_t)bt * H_ + h32;
        toh2x4(*(const uint4*)qp,        qh);
        toh2x4(*(const uint4*)(qp + 8),  qh + 4);
        toh2x4(*(const uint4*)(qp + 16), qh + 8);
        toh2x4(*(const uint4*)(qp + 24), qh + 12);
        const u16* vp = Vec + h32;
#pragma unroll
        for (int m = 0; m < 4; ++m) {
            float vf[8]; unpack8(*(const uint4*)(vp + m * 8), vf);
#pragma unroll
            for (int j = 0; j < 4; ++j)
                vh[m * 4 + j] = (h2){ (f16t)vf[2 * j], (f16t)vf[2 * j + 1] };
        }
    }
    bool un = false;
    if (tid < N_) {
        un = (mask[(size_t)bt * N_ + tid] == 0);
        u_s[tid] = -3.0e38f;                 // init ALL entries (R6 scar)
    }
    unsigned long long bal = __ballot(un);
    if (l == 0) wcnt[w] = __popcll(bal);
    __syncthreads();
    const int base = (w == 1) ? wcnt[0] : 0;
    const int pos = __popcll(bal & ((1ULL << l) - 1ULL));
    if (un) list[base + pos] = (short)tid;
    if (tid == 0) cnt_s = wcnt[0] + wcnt[1];
    __syncthreads();
    const int cnt = cnt_s;
    const u16* ub = u2g + (size_t)b * N_ * H_;
    // ---- scoring: group (w,g16) handles k = w*4+g16 (mod 8) ----
    for (int k = w * 4 + g16; k < cnt; k += 8) {
        const int n = list[k];
        const u16* up = ub + (size_t)n * H_ + h32;
        h2 uh[16];
        toh2x4(*(const uint4*)up,        uh);
        toh2x4(*(const uint4*)(up + 8),  uh + 4);
        toh2x4(*(const uint4*)(up + 16), uh + 8);
        toh2x4(*(const uint4*)(up + 24), uh + 12);
        float sa = 0.f, sb = 0.f, sc = 0.f, sd = 0.f;
#pragma unroll
        for (int j = 0; j < 4; ++j) {
            sa = tanhdot_h2(uh[j],      qh[j],      vh[j],      sa);
            sb = tanhdot_h2(uh[4 + j],  qh[4 + j],  vh[4 + j],  sb);
            sc = tanhdot_h2(uh[8 + j],  qh[8 + j],  vh[8 + j],  sc);
            sd = tanhdot_h2(uh[12 + j], qh[12 + j], vh[12 + j], sd);
        }
        float s = (sa + sb) + (sc + sd);
#pragma unroll
        for (int off = 8; off > 0; off >>= 1) s += __shfl_xor(s, off, 64);
        if (l16 == 0) u_s[n] = s;
    }
    __syncthreads();
    float v = un ? u_s[tid] : -3.0e38f;
    float m = v;
#pragma unroll
    for (int off = 32; off > 0; off >>= 1) m = fmaxf(m, __shfl_xor(m, off, 64));
    if (l == 0) red[w] = m;
    __syncthreads();
    float mx = fmaxf(red[0], red[1]);
    float e = un ? __expf(v - mx) : 0.f;
    float s2 = e;
#pragma unroll
    for (int off = 32; off > 0; off >>= 1) s2 += __shfl_xor(s2, off, 64);
    if (l == 0) red[2 + w] = s2;
    __syncthreads();
    float inv = __fdividef(1.f, red[2] + red[3]);
    if (tid < N_) a_s[tid] = e * inv;
    __syncthreads();
    // ---- PV split-k: wave w sums k == w (mod 2); lane owns h0..h0+7 ----
    const u16* refb = ref + (size_t)b * N_ * H_;
    float pacc[8] = {0.f, 0.f, 0.f, 0.f, 0.f, 0.f, 0.f, 0.f};
    for (int k = w; k < cnt; k += 2) {
        const int n = list[k];
        const float a = a_s[n];
        float rv[8];
        unpack8(*(const uint4*)(refb + (size_t)n * H_ + h0), rv);
#pragma unroll
        for (int j = 0; j < 8; ++j) pacc[j] = fmaf(a, rv[j], pacc[j]);
    }
    {
        float4 pa0 = {pacc[0], pacc[1], pacc[2], pacc[3]};
        float4 pa1 = {pacc[4], pacc[5], pacc[6], pacc[7]};
        *(float4*)&pv_s[w][h0]     = pa0;
        *(float4*)&pv_s[w][h0 + 4] = pa1;
    }
    __syncthreads();
    const int hh = tid * 4;                       // 128 threads x 4 elems
    float s0 = pv_s[0][hh]     + pv_s[1][hh];
    float s1 = pv_s[0][hh + 1] + pv_s[1][hh + 1];
    float s2b = pv_s[0][hh + 2] + pv_s[1][hh + 2];
    float s3 = pv_s[0][hh + 3] + pv_s[1][hh + 3];
    uint2 packed;
    packed.x = ((unsigned)f2bf(s1) << 16) | (unsigned)f2bf(s0);
    packed.y = ((unsigned)f2bf(s3) << 16) | (unsigned)f2bf(s2b);
    *(uint2*)(query2 + (size_t)bt * H_ + hh) = packed;
}

// Pointer head v9 (verified R13): 128 thr + XCD-locality remap.
__global__ __launch_bounds__(128) void final_attn_kernel(
    const u16* __restrict__ q2, const u16* __restrict__ u2p,
    const u16* __restrict__ Vec2, const unsigned char* __restrict__ mask,
    const int* __restrict__ y, float* __restrict__ ll, float* __restrict__ ps)
{
    int b, bt;
    xcd_bt(blockIdx.x, b, bt);
    const int tid = threadIdx.x, w = tid >> 6, l = tid & 63;
    const int g16 = l >> 4, l16 = l & 15;
    __shared__ float u_s[N_], lp_s[N_], red[4];
    __shared__ short list[N_];
    __shared__ unsigned char msk[128];
    __shared__ int wcnt[2], cnt_s;
    const int h32 = l16 * 32;
    h2 qh[16], vh[16];
    {
        const u16* qp = q2 + (size_t)bt * H_ + h32;
        toh2x4(*(const uint4*)qp,        qh);
        toh2x4(*(const uint4*)(qp + 8),  qh + 4);
        toh2x4(*(const uint4*)(qp + 16), qh + 8);
        toh2x4(*(const uint4*)(qp + 24), qh + 12);
        const u16* vp = Vec2 + h32;
#pragma unroll
        for (int m = 0; m < 4; ++m) {
            float vf[8]; unpack8(*(const uint4*)(vp + m * 8), vf);
#pragma unroll
            for (int j = 0; j < 4; ++j)
                vh[m * 4 + j] = (h2){ (f16t)vf[2 * j], (f16t)vf[2 * j + 1] };
        }
    }
    bool un = false;
    msk[tid] = (tid < N_) ? mask[(size_t)bt * N_ + tid] : 1;
    if (tid < N_) {
        un = (msk[tid] == 0);
        u_s[tid] = 0.f;
    }
    unsigned long long bal = __ballot(un);
    if (l == 0) wcnt[w] = __popcll(bal);
    __syncthreads();
    const int base = (w == 1) ? wcnt[0] : 0;
    const int pos = __popcll(bal & ((1ULL << l) - 1ULL));
    if (un) list[base + pos] = (short)tid;
    if (tid == 0) cnt_s = wcnt[0] + wcnt[1];
    __syncthreads();
    const int cnt = cnt_s;
    const u16* ub = u2p + (size_t)b * N_ * H_;
    for (int k = w * 4 + g16; k < cnt; k += 8) {
        const int n = list[k];
        const u16* up = ub + (size_t)n * H_ + h32;
        h2 uh[16];
        toh2x4(*(const uint4*)up,        uh);
        toh2x4(*(const uint4*)(up + 8),  uh + 4);
        toh2x4(*(const uint4*)(up + 16), uh + 8);
        toh2x4(*(const uint4*)(up + 24), uh + 12);
        float sa = 0.f, sb = 0.f, sc = 0.f, sd = 0.f;
#pragma unroll
        for (int j = 0; j < 4; ++j) {
            sa = tanhdot_h2(uh[j],      qh[j],      vh[j],      sa);
            sb = tanhdot_h2(uh[4 + j],  qh[4 + j],  vh[4 + j],  sb);
            sc = tanhdot_h2(uh[8 + j],  qh[8 + j],  vh[8 + j],  sc);
            sd = tanhdot_h2(uh[12 + j], qh[12 + j], vh[12 + j], sd);
        }
        float s = (sa + sb) + (sc + sd);
#pragma unroll
        for (int off = 8; off > 0; off >>= 1) s += __shfl_xor(s, off, 64);
        if (l16 == 0) u_s[n] = s;
    }
    __syncthreads();
    float lg = -3.0e38f;
    if (tid < N_) {
        unsigned char c = msk[tid];
        if (c) lg = -1e8f * (float)c;
        else   lg = 10.f * tanh_poly(u_s[tid]);
    }
    float m = lg;
#pragma unroll
    for (int off = 32; off > 0; off >>= 1) m = fmaxf(m, __shfl_xor(m, off, 64));
    if (l == 0) red[w] = m;
    __syncthreads();
    float mx = fmaxf(red[0], red[1]);
    float e = (tid < N_) ? __expf(lg - mx) : 0.f;
    float s2 = e;
#pragma unroll
    for (int off = 32; off > 0; off >>= 1) s2 += __shfl_xor(s2, off, 64);
    if (l == 0) red[2 + w] = s2;
    __syncthreads();
    float lse = mx + __logf(red[2] + red[3]);
    if (tid < N_) {
        float lp = lg - lse;
        ps[(size_t)bt * N_ + tid] = lp;
        lp_s[tid] = lp;
    }
    __syncthreads();
    if (tid == 0) atomicAdd(&ll[b], lp_s[y[bt]]);
}

// outputs (float32): pi = float(y); ll from f32 accumulator
__global__ void write_out_kernel(const int* __restrict__ y, const float* __restrict__ ll,
                                 float* __restrict__ out) {
    int i = blockIdx.x * 256 + threadIdx.x;   // 51200 threads
    if (i < BT_) out[i] = (float)y[i];
    if (i < B_)  out[BT_ + i] = ll[i];
}

// ---------------------------------------------------------------------------
extern "C" void kernel_launch(void* const* d_in, const int* in_sizes, int n_in,
                              void* d_out, int out_size, void* d_ws, size_t ws_size,
                              hipStream_t stream)
{
    const u16* x        = (const u16*)d_in[0];
    const int* y        = (const int*)d_in[1];
    const u16* emb_W    = (const u16*)d_in[2];
    const u16* enc_Wih  = (const u16*)d_in[3];
    const u16* enc_Whh  = (const u16*)d_in[4];
    const u16* enc_bih  = (const u16*)d_in[5];
    const u16* enc_bhh  = (const u16*)d_in[6];
    const u16* dec_Wih  = (const u16*)d_in[7];
    const u16* dec_Whh  = (const u16*)d_in[8];
    const u16* dec_bih  = (const u16*)d_in[9];
    const u16* dec_bhh  = (const u16*)d_in[10];
    const u16* Vec      = (const u16*)d_in[11];
    const u16* Vec2     = (const u16*)d_in[12];
    const u16* Wq_W     = (const u16*)d_in[13];
    const u16* Wq_b     = (const u16*)d_in[14];
    const u16* Wref_W   = (const u16*)d_in[15];
    const u16* Wref_b   = (const u16*)d_in[16];
    const u16* Wq2_W    = (const u16*)d_in[17];
    const u16* Wq2_b    = (const u16*)d_in[18];
    const u16* Wref2_W  = (const u16*)d_in[19];
    const u16* Wref2_b  = (const u16*)d_in[20];
    const u16* dec0     = (const u16*)d_in[21];

    char* p = (char*)d_ws;
    auto carve = [&](size_t bytes) -> char* {
        char* r = p; p += (bytes + 255) & ~(size_t)255; return r;
    };
    u16*   embed     = (u16*)  carve((size_t)BT_ * E_ * 2);      // 26.21 MB
    float* cbuf      = (float*)carve((size_t)B_ * H_ * 4);       //  1.05 MB
    u16*   zero_h    = (u16*)  carve((size_t)B_ * H_ * 2);       //  0.52 MB
    u16*   dec0_rows = (u16*)  carve((size_t)B_ * E_ * 2);       //  0.26 MB
    u16*   ref       = (u16*)  carve((size_t)BT_ * H_ * 2);      // 52.43 MB
    u16*   dec_hs    = (u16*)  carve((size_t)BT_ * H_ * 2);      // 52.43 MB (later: qry2)
    unsigned char* maskb = (unsigned char*)carve((size_t)BT_ * N_); // 5.12 MB
    float* llb       = (float*)carve((size_t)B_ * 4);
    const size_t need = (size_t)(p - (char*)d_ws);
    u16* Ybuf = embed;                                  // u2g / u2p chunk (f16)
    u16* Zbuf = embed + (size_t)BC_ * N_ * H_;          // q1 / q2 chunk (f16)

    if (need > ws_size) {
        sentinel_kernel<<<(B_ + 255) / 256, 256, 0, stream>>>((float*)d_out);
        return;
    }

    init_kernel<<<(B_ * H_) / 256, 256, 0, stream>>>(cbuf, zero_h, llb, dec0_rows, dec0);
    embed_kernel<<<BT_, 256, 0, stream>>>(x, emb_W, embed);
    mask_kernel<<<B_, 128, 0, stream>>>(y, maskb);

    // ---- LSTM steps: multi-launch, fused8+XCD (BK=192, depth-2 prefetch) ----
    dim3 sgrid(32, 8);   // linearized then remapped in-kernel
    for (int t = 0; t < N_; ++t) {
        const u16* hb = (t == 0) ? zero_h : (ref + (size_t)(t - 1) * H_);
        int hlda = (t == 0) ? H_ : (N_ * H_);
        fused8_step_kernel<<<sgrid, 256, 0, stream>>>(hb, hlda, embed, y,
                                                      enc_Whh, enc_Wih, enc_bih, enc_bhh,
                                                      cbuf, ref + (size_t)t * H_, 0, t);
    }
    for (int t = 0; t < N_; ++t) {
        const u16* hb = (t == 0) ? (ref + (size_t)(N_ - 1) * H_) : (dec_hs + (size_t)(t - 1) * H_);
        const u16* xb = (t == 0) ? dec0_rows : embed;
        int mode = (t == 0) ? 1 : 2;
        fused8_step_kernel<<<sgrid, 256, 0, stream>>>(hb, N_ * H_, xb, y,
                                                      dec_Whh, dec_Wih, dec_bih, dec_bhh,
                                                      cbuf, dec_hs + (size_t)t * H_, mode, t);
    }

    // ---- batched attention, chunked over batch (embed now dead) ----
    float* out = (float*)d_out;
    const int MC = BC_ * N_;                     // 12800 rows per chunk
    dim3 ggrid(8, 400);                          // dual gemm, XCD-remapped
    for (int c = 0; c < NCHUNK_; ++c) {
        const size_t rowOff = (size_t)c * BC_ * N_ * H_;
        const size_t btOff  = (size_t)c * BC_ * N_;
        gemm_bt2_kernel<<<ggrid, 256, 0, stream>>>(dec_hs + rowOff, Wq_W,  Wq_b,  Zbuf,
                                                   ref + rowOff,    Wref_W, Wref_b, Ybuf);
        glimpse_kernel<<<MC, 128, 0, stream>>>(Zbuf, Ybuf, ref + rowOff, Vec,
                                               maskb + btOff * N_, dec_hs + rowOff);
        gemm_bt2_kernel<<<ggrid, 256, 0, stream>>>(dec_hs + rowOff, Wq2_W, Wq2_b, Zbuf,
                                                   ref + rowOff,    Wref2_W, Wref2_b, Ybuf);
        final_attn_kernel<<<MC, 128, 0, stream>>>(Zbuf, Ybuf, Vec2, maskb + btOff * N_,
                                                  y + btOff, llb + (size_t)c * BC_,
                                                  out + BT_ + B_ + btOff * N_);
    }
    write_out_kernel<<<BT_ / 256, 256, 0, stream>>>(y, llb, out);
}

// Round 16
// 2512.819 us; speedup vs baseline: 1.2768x; 1.0055x over previous
//
#include <hip/hip_runtime.h>
#include <hip/hip_bf16.h>
#include <stdint.h>

typedef unsigned short u16;
typedef __bf16 bf16t;
typedef _Float16 f16t;
typedef __attribute__((ext_vector_type(8))) bf16t bf16x8;
typedef __attribute__((ext_vector_type(4))) float f32x4;
typedef __attribute__((ext_vector_type(2))) _Float16 h2;

#define B_   512
#define N_   100
#define P_   20
#define E_   256
#define H_   512
#define G4H_ 2048
#define BT_  (B_ * N_)   // 51200
#define BC_  128         // phase-B batch chunk
#define NCHUNK_ (B_ / BC_)
#define TSZ_ 4608        // 64*72 shorts per LDS tile chunk (9216 B)

__device__ __forceinline__ float bfu2f(unsigned u) {
    union { unsigned i; float f; } v; v.i = u << 16; return v.f;
}
__device__ __forceinline__ float bf2f(u16 x) { return bfu2f((unsigned)x); }
__device__ __forceinline__ u16 f2bf(float f) {
    union { float f; unsigned i; } v; v.f = f;
    unsigned r = v.i + 0x7FFFu + ((v.i >> 16) & 1u);
    return (u16)(r >> 16);
}
__device__ __forceinline__ u16 f2h_bits(float f) {
    union { f16t h; u16 u; } c; c.h = (f16t)f; return c.u;
}
__device__ __forceinline__ void unpack8(uint4 r, float* o) {
    o[0] = bfu2f(r.x & 0xffffu); o[1] = bfu2f(r.x >> 16);
    o[2] = bfu2f(r.y & 0xffffu); o[3] = bfu2f(r.y >> 16);
    o[4] = bfu2f(r.z & 0xffffu); o[5] = bfu2f(r.z >> 16);
    o[6] = bfu2f(r.w & 0xffffu); o[7] = bfu2f(r.w >> 16);
}
__device__ __forceinline__ void toh2x4(uint4 r, h2* o) {
    union { uint4 u; h2 h[4]; } c; c.u = r;
    o[0] = c.h[0]; o[1] = c.h[1]; o[2] = c.h[2]; o[3] = c.h[3];
}
__device__ __forceinline__ float tanh_f(float x) {
    x = fminf(15.f, fmaxf(-15.f, x));
    float e = __expf(2.f * x);
    return __fdividef(e - 1.f, e + 1.f);
}
__device__ __forceinline__ float sig_f(float x) {
    x = fminf(15.f, fmaxf(-15.f, x));
    return __fdividef(1.f, 1.f + __expf(-x));
}
// f32 polynomial tanh (clamped both ends) — used on the per-n final logit only
__device__ __forceinline__ float tanh_poly(float x) {
    x = fminf(3.25f, fmaxf(-3.25f, x));
    float z = x * x;
    float p = fmaf(fmaf(fmaf(-0.0018661f, z, 0.037231f), z, -0.249208f), z, 0.984238f);
    float r = x * p;
    return fminf(1.0f, fmaxf(-1.0f, r));
}
// packed-f16 tanh-dot step: s += dot2(vh, tanh_pk(qh + uh)).
__device__ __forceinline__ float tanhdot_h2(h2 uh, h2 qh, h2 vh, float s) {
    const h2 kLo = { (f16t)-3.25f, (f16t)-3.25f };
    const h2 kHi = { (f16t)3.25f,  (f16t)3.25f };
    const h2 c3 = { (f16t)-0.0018661f, (f16t)-0.0018661f };
    const h2 c2 = { (f16t)0.037231f,   (f16t)0.037231f };
    const h2 c1 = { (f16t)-0.249208f,  (f16t)-0.249208f };
    const h2 c0 = { (f16t)0.984238f,   (f16t)0.984238f };
    h2 t = uh + qh;
    t = __builtin_elementwise_max(t, kLo);
    t = __builtin_elementwise_min(t, kHi);
    h2 z = t * t;
    h2 p = __builtin_elementwise_fma(c3, z, c2);
    p = __builtin_elementwise_fma(p, z, c1);
    p = __builtin_elementwise_fma(p, z, c0);
    h2 r = t * p;
#if defined(__has_builtin) && __has_builtin(__builtin_amdgcn_fdot2)
    return __builtin_amdgcn_fdot2(r, vh, s, false);
#else
    return s + (float)r.x * (float)vh.x + (float)r.y * (float)vh.y;
#endif
}
__device__ __forceinline__ f32x4 mfma16(bf16x8 a, bf16x8 b, f32x4 c) {
    return __builtin_amdgcn_mfma_f32_16x16x32_bf16(a, b, c, 0, 0, 0);
}

// ---------------------------------------------------------------------------
__global__ void sentinel_kernel(float* out) {
    int i = blockIdx.x * 256 + threadIdx.x;
    if (i < B_) out[BT_ + i] = 1.0e9f;   // signals "workspace too small"
}

// init: zero c, zero_h, ll; broadcast dec_input0 rows
__global__ void init_kernel(float* c, u16* zero_h, float* ll, u16* dec0_rows,
                            const u16* __restrict__ dec0) {
    int i = blockIdx.x * 256 + threadIdx.x;          // 262144 threads
    if (i < B_ * H_) { c[i] = 0.f; zero_h[i] = 0; }
    if (i < B_) ll[i] = 0.f;
    if (i < B_ * E_) dec0_rows[i] = dec0[i & (E_ - 1)];
}

// embed[b,n,e] = sum_p x[b,n,p] * emb_W[e,p]
__global__ void embed_kernel(const u16* __restrict__ x, const u16* __restrict__ emb_W,
                             u16* __restrict__ embed) {
    __shared__ float xs[P_];
    int bt = blockIdx.x, tid = threadIdx.x;
    if (tid < P_) xs[tid] = bf2f(x[(size_t)bt * P_ + tid]);
    __syncthreads();
    float s = 0.f;
#pragma unroll
    for (int p = 0; p < P_; ++p) s += xs[p] * bf2f(emb_W[tid * P_ + p]);
    embed[(size_t)bt * E_ + tid] = f2bf(s);
}

// mask[b,t,n] = #{s<t : y[b,s]==n}   (cumulative COUNT, y may repeat)
__global__ void mask_kernel(const int* __restrict__ y, unsigned char* __restrict__ mask) {
    int b = blockIdx.x, n = threadIdx.x;
    if (n >= N_) return;
    unsigned char cnt = 0;
    for (int t = 0; t < N_; ++t) {
        mask[((size_t)b * N_ + t) * N_ + n] = cnt;
        if (y[b * N_ + t] == n) cnt++;
    }
}

// ---------------------------------------------------------------------------
// Fused LSTM step v10 (fused9): fused8+XCD with the A (h/x) LDS staging
// REMOVED — each lane loads its MFMA A-fragments directly from global (L2-
// resident post-R14 remap) into named register sets P/Q, one iteration ahead.
// B (weights) keeps the verified LDS staging. Fragment values and MFMA order
// unchanged => bit-identical numerics. LDS halves to 27.6 KB; removes
// 96 ds_write + 96 ds_read per CU per step.
#define LOADB(c0, B0,B1,B2,B3,B4,B5) do { \
    const u16* sb0_ = srcB(c0); const u16* sb1_ = srcB((c0)+1); const u16* sb2_ = srcB((c0)+2); \
    B0 = *(const uint4*)sb0_; B1 = *(const uint4*)(sb0_ + 8); \
    B2 = *(const uint4*)sb1_; B3 = *(const uint4*)(sb1_ + 8); \
    B4 = *(const uint4*)sb2_; B5 = *(const uint4*)(sb2_ + 8); \
} while(0)

#define WRITEB(B0,B1,B2,B3,B4,B5) do { \
    *(uint4*)bsw0 = B0;  *(uint4*)(bsw0 + 8) = B1; \
    *(uint4*)bsw1 = B2;  *(uint4*)(bsw1 + 8) = B3; \
    *(uint4*)bsw2 = B4;  *(uint4*)(bsw2 + 8) = B5; \
} while(0)

// per-lane A-fragment source for chunk c (compile-time c in unrolled calls)
#define APTR(c) (((c) < 8) ? (hq + (c) * 64) : (xq + ((c) - 8) * 64))
#define LOADA3(c0, R0,R1,R2,R3,R4,R5) do { \
    R0 = *(const bf16x8*)(APTR(c0) + q8);        R1 = *(const bf16x8*)(APTR(c0) + q8 + 32); \
    R2 = *(const bf16x8*)(APTR((c0)+1) + q8);    R3 = *(const bf16x8*)(APTR((c0)+1) + q8 + 32); \
    R4 = *(const bf16x8*)(APTR((c0)+2) + q8);    R5 = *(const bf16x8*)(APTR((c0)+2) + q8 + 32); \
} while(0)

#define COMPUTE1(s_, AF0, AF1) do { \
    const int so_ = (s_) * TSZ_; \
    _Pragma("unroll") \
    for (int g_ = 0; g_ < 4; ++g_) { \
        const short* brp_ = &Bs[so_ + (g_ * 16 + rl) * 72 + q8]; \
        bf16x8 bb0_ = *(const bf16x8*)brp_; \
        bf16x8 bb1_ = *(const bf16x8*)(brp_ + 32); \
        acc[g_] = mfma16(AF0, bb0_, acc[g_]); \
        acc[g_] = mfma16(AF1, bb1_, acc[g_]); \
    } \
} while(0)
#define COMPUTE3D(A0,A1,A2,A3,A4,A5) do { \
    COMPUTE1(0, A0, A1); COMPUTE1(1, A2, A3); COMPUTE1(2, A4, A5); \
} while(0)

__global__ __launch_bounds__(256) void fused9_step_kernel(
    const u16* __restrict__ h_base, int h_lda,
    const u16* __restrict__ x_base,
    const int* __restrict__ y,
    const u16* __restrict__ Whh, const u16* __restrict__ Wih,
    const u16* __restrict__ bih, const u16* __restrict__ bhh,
    float* __restrict__ cbuf,
    u16* __restrict__ hout,
    int mode, int t)
{
    __shared__ __align__(16) short Bs[3 * TSZ_];   // B chunk slots 0|1|2
    const int tid = threadIdx.x;
    // XCD-locality remap (R14): bm = lid&7 -> h row-block stays on one XCD
    const int lid = blockIdx.x + 32 * blockIdx.y;
    const int bm = lid & 7, bn = lid >> 3;
    const int w = tid >> 6, l = tid & 63, rl = l & 15, q = l >> 4, q8 = q * 8;
    const int srow = tid >> 2, koff = (tid & 3) * 16;

    // ---- per-lane A-fragment row pointers (row = bm*64 + w*16 + rl) ----
    const int rowl = bm * 64 + w * 16 + rl;
    const u16* hq = h_base + (size_t)rowl * h_lda;
    size_t xrow2;
    if (mode == 0)      xrow2 = ((size_t)rowl * N_ + t) * E_;
    else if (mode == 1) xrow2 = (size_t)rowl * E_;
    else                xrow2 = ((size_t)rowl * N_ + (size_t)y[rowl * N_ + t - 1]) * E_;
    const u16* xq = x_base + xrow2;

    // ---- B (weights) staging pointers, same as fused8 ----
    const int wrow = (srow >> 4) * 512 + bn * 16 + (srow & 15);
    const u16* whp = Whh + (size_t)wrow * H_ + koff;
    const u16* wip = Wih + (size_t)wrow * E_ + koff;
    auto srcB = [&](int c) -> const u16* {
        return (c < 8) ? (whp + c * 64) : (wip + (c - 8) * 64);
    };

    float bsum[4];
#pragma unroll
    for (int g = 0; g < 4; ++g) {
        int col = g * 512 + bn * 16 + rl;
        bsum[g] = bf2f(bih[col]) + bf2f(bhh[col]);
    }

    f32x4 acc[4];
#pragma unroll
    for (int g = 0; g < 4; ++g) acc[g] = (f32x4){0.f, 0.f, 0.f, 0.f};

    short* bsw0 = &Bs[srow * 72 + koff];
    short* bsw1 = bsw0 + TSZ_;
    short* bsw2 = bsw0 + 2 * TSZ_;

    uint4 xb0, xb1, xb2, xb3, xb4, xb5;      // B set X (even iterations)
    uint4 yb0, yb1, yb2, yb3, yb4, yb5;      // B set Y (odd iterations)
    bf16x8 pa0, pa1, pa2, pa3, pa4, pa5;     // A set P
    bf16x8 qa0, qa1, qa2, qa3, qa4, qa5;     // A set Q

    // prologue: B chunks 0-2 -> X, 3-5 -> Y; A fragments chunks 0-2 -> P
    LOADB(0, xb0,xb1,xb2,xb3,xb4,xb5);
    LOADB(3, yb0,yb1,yb2,yb3,yb4,yb5);
    LOADA3(0, pa0,pa1,pa2,pa3,pa4,pa5);

    // it0: stage B(0-2), refill X<-B(6-8), A Q<-(3-5), compute chunks 0-2
    __syncthreads();
    WRITEB(xb0,xb1,xb2,xb3,xb4,xb5);
    __syncthreads();
    LOADB(6, xb0,xb1,xb2,xb3,xb4,xb5);
    LOADA3(3, qa0,qa1,qa2,qa3,qa4,qa5);
    COMPUTE3D(pa0,pa1,pa2,pa3,pa4,pa5);
    // it1: stage B(3-5), refill Y<-B(9-11), A P<-(6-8), compute 3-5
    __syncthreads();
    WRITEB(yb0,yb1,yb2,yb3,yb4,yb5);
    __syncthreads();
    LOADB(9, yb0,yb1,yb2,yb3,yb4,yb5);
    LOADA3(6, pa0,pa1,pa2,pa3,pa4,pa5);
    COMPUTE3D(qa0,qa1,qa2,qa3,qa4,qa5);
    // it2: stage B(6-8), A Q<-(9-11), compute 6-8
    __syncthreads();
    WRITEB(xb0,xb1,xb2,xb3,xb4,xb5);
    __syncthreads();
    LOADA3(9, qa0,qa1,qa2,qa3,qa4,qa5);
    COMPUTE3D(pa0,pa1,pa2,pa3,pa4,pa5);
    // it3: stage B(9-11), compute 9-11
    __syncthreads();
    WRITEB(yb0,yb1,yb2,yb3,yb4,yb5);
    __syncthreads();
    COMPUTE3D(qa0,qa1,qa2,qa3,qa4,qa5);

    const int hcol = bn * 16 + rl;
#pragma unroll
    for (int r = 0; r < 4; ++r) {
        int brow = bm * 64 + w * 16 + q * 4 + r;
        float gi = acc[0][r] + bsum[0];
        float gf = acc[1][r] + bsum[1];
        float gg = acc[2][r] + bsum[2];
        float go = acc[3][r] + bsum[3];
        size_t cidx = (size_t)brow * H_ + hcol;
        float cv = sig_f(gf) * cbuf[cidx] + sig_f(gi) * tanh_f(gg);
        cbuf[cidx] = cv;
        hout[(size_t)brow * (N_ * H_) + hcol] = f2bf(sig_f(go) * tanh_f(cv));
    }
}

// ---------------------------------------------------------------------------
// Dual head GEMM (verified R15): two independent C = A @ Bw^T + bias gemms
// fused, grid (8,400), XCD remap for A-panel L2 locality.
__global__ __launch_bounds__(256) void gemm_bt2_kernel(
    const u16* __restrict__ A1, const u16* __restrict__ Bw1,
    const u16* __restrict__ bias1, u16* __restrict__ C1,
    const u16* __restrict__ A2, const u16* __restrict__ Bw2,
    const u16* __restrict__ bias2, u16* __restrict__ C2)
{
    __shared__ __align__(16) short As[64 * 40];
    __shared__ __align__(16) short Bs[64 * 40];
    const int tid = threadIdx.x;
    const int lid = blockIdx.x + 8 * blockIdx.y;
    const int c = lid & 7;
    const int rest = lid >> 3;                 // [0,400)
    const int bmall = c * 50 + (rest >> 3);    // [0,400) bijective
    const int bn = rest & 7;
    const u16* A;  const u16* Bw; const u16* bias; u16* C; int bm;
    if (bmall < 200) { A = A1; Bw = Bw1; bias = bias1; C = C1; bm = bmall; }
    else             { A = A2; Bw = Bw2; bias = bias2; C = C2; bm = bmall - 200; }

    const int srow = tid >> 2, koff = (tid & 3) * 8;
    const size_t aBase = (size_t)(bm * 64 + srow) * H_ + koff;
    const size_t bBase = (size_t)(bn * 64 + srow) * H_ + koff;
    const int NKT = H_ >> 5;                   // 16
    uint4 aReg = *(const uint4*)(A + aBase);
    uint4 bReg = *(const uint4*)(Bw + bBase);
    const int w = tid >> 6, l = tid & 63;
    const int wm = w & 1, wn = w >> 1;
    const int rl = l & 15, q8 = (l >> 4) * 8;
    f32x4 acc00 = {0.f,0.f,0.f,0.f}, acc01 = {0.f,0.f,0.f,0.f};
    f32x4 acc10 = {0.f,0.f,0.f,0.f}, acc11 = {0.f,0.f,0.f,0.f};
    short* asw = &As[srow * 40 + koff];
    short* bsw = &Bs[srow * 40 + koff];
    const short* ar0 = &As[(wm * 32 + rl) * 40 + q8];
    const short* ar1 = &As[(wm * 32 + 16 + rl) * 40 + q8];
    const short* br0 = &Bs[(wn * 32 + rl) * 40 + q8];
    const short* br1 = &Bs[(wn * 32 + 16 + rl) * 40 + q8];
    for (int kt = 0; kt < NKT; ++kt) {
        __syncthreads();
        *(uint4*)asw = aReg;
        *(uint4*)bsw = bReg;
        __syncthreads();
        if (kt + 1 < NKT) {
            aReg = *(const uint4*)(A + aBase + (kt + 1) * 32);
            bReg = *(const uint4*)(Bw + bBase + (kt + 1) * 32);
        }
        bf16x8 a0 = *(const bf16x8*)ar0;
        bf16x8 a1 = *(const bf16x8*)ar1;
        bf16x8 b0 = *(const bf16x8*)br0;
        bf16x8 b1 = *(const bf16x8*)br1;
        acc00 = mfma16(a0, b0, acc00);
        acc01 = mfma16(a0, b1, acc01);
        acc10 = mfma16(a1, b0, acc10);
        acc11 = mfma16(a1, b1, acc11);
    }
    const int col0 = bn * 64 + wn * 32 + rl;
    const int row0 = bm * 64 + wm * 32 + (l >> 4) * 4;
    const float bv0 = bf2f(bias[col0]);
    const float bv1 = bf2f(bias[col0 + 16]);
#pragma unroll
    for (int r = 0; r < 4; ++r) {
        C[(size_t)(row0 + r) * H_ + col0]           = f2h_bits(acc00[r] + bv0);
        C[(size_t)(row0 + r) * H_ + col0 + 16]      = f2h_bits(acc01[r] + bv1);
        C[(size_t)(row0 + 16 + r) * H_ + col0]      = f2h_bits(acc10[r] + bv0);
        C[(size_t)(row0 + 16 + r) * H_ + col0 + 16] = f2h_bits(acc11[r] + bv1);
    }
}

// ---------------------------------------------------------------------------
// XCD-locality block remap (R13): with round-robin dispatch, blocks with
// bid%8==k land on XCD k. Map all 100 t-blocks of one b to the SAME XCD so
// u2g[b]/ref[b] (~204 KB) stay in that XCD's 4MB L2 (16 b's x 204KB = 3.3MB).
__device__ __forceinline__ void xcd_bt(int bid, int& b, int& bt) {
    b = ((bid & 7) << 4) + ((bid >> 3) / N_);
    const int t = (bid >> 3) % N_;
    bt = b * N_ + t;
}

// Glimpse v10 (verified R13): 128 thr + XCD-locality remap.
__global__ __launch_bounds__(128) void glimpse_kernel(
    const u16* __restrict__ q1, const u16* __restrict__ u2g,
    const u16* __restrict__ ref, const u16* __restrict__ Vec,
    const unsigned char* __restrict__ mask, u16* __restrict__ query2)
{
    int b, bt;
    xcd_bt(blockIdx.x, b, bt);
    const int tid = threadIdx.x, w = tid >> 6, l = tid & 63;
    const int g16 = l >> 4, l16 = l & 15;
    __shared__ float u_s[N_], a_s[N_], red[4];
    __shared__ short list[N_];
    __shared__ int wcnt[2], cnt_s;
    __shared__ __align__(16) float pv_s[2][H_];   // 4 KB PV partials
    const int h32 = l16 * 32;                     // scoring slice (16 lanes/n)
    const int h0 = l * 8;                         // PV slice (64 lanes)
    // ---- preload q and Vec 32-elem slices (scoring) ----
    h2 qh[16], vh[16];
    {
        const u16* qp = q1 + (size_t)bt * H_ + h32;
        toh2x4(*(const uint4*)qp,        qh);
        toh2x4(*(const uint4*)(qp + 8),  qh + 4);
        toh2x4(*(const uint4*)(qp + 16), qh + 8);
        toh2x4(*(const uint4*)(qp + 24), qh + 12);
        const u16* vp = Vec + h32;
#pragma unroll
        for (int m = 0; m < 4; ++m) {
            float vf[8]; unpack8(*(const uint4*)(vp + m * 8), vf);
#pragma unroll
            for (int j = 0; j < 4; ++j)
                vh[m * 4 + j] = (h2){ (f16t)vf[2 * j], (f16t)vf[2 * j + 1] };
        }
    }
    bool un = false;
    if (tid < N_) {
        un = (mask[(size_t)bt * N_ + tid] == 0);
        u_s[tid] = -3.0e38f;                 // init ALL entries (R6 scar)
    }
    unsigned long long bal = __ballot(un);
    if (l == 0) wcnt[w] = __popcll(bal);
    __syncthreads();
    const int base = (w == 1) ? wcnt[0] : 0;
    const int pos = __popcll(bal & ((1ULL << l) - 1ULL));
    if (un) list[base + pos] = (short)tid;
    if (tid == 0) cnt_s = wcnt[0] + wcnt[1];
    __syncthreads();
    const int cnt = cnt_s;
    const u16* ub = u2g + (size_t)b * N_ * H_;
    // ---- scoring: group (w,g16) handles k = w*4+g16 (mod 8) ----
    for (int k = w * 4 + g16; k < cnt; k += 8) {
        const int n = list[k];
        const u16* up = ub + (size_t)n * H_ + h32;
        h2 uh[16];
        toh2x4(*(const uint4*)up,        uh);
        toh2x4(*(const uint4*)(up + 8),  uh + 4);
        toh2x4(*(const uint4*)(up + 16), uh + 8);
        toh2x4(*(const uint4*)(up + 24), uh + 12);
        float sa = 0.f, sb = 0.f, sc = 0.f, sd = 0.f;
#pragma unroll
        for (int j = 0; j < 4; ++j) {
            sa = tanhdot_h2(uh[j],      qh[j],      vh[j],      sa);
            sb = tanhdot_h2(uh[4 + j],  qh[4 + j],  vh[4 + j],  sb);
            sc = tanhdot_h2(uh[8 + j],  qh[8 + j],  vh[8 + j],  sc);
            sd = tanhdot_h2(uh[12 + j], qh[12 + j], vh[12 + j], sd);
        }
        float s = (sa + sb) + (sc + sd);
#pragma unroll
        for (int off = 8; off > 0; off >>= 1) s += __shfl_xor(s, off, 64);
        if (l16 == 0) u_s[n] = s;
    }
    __syncthreads();
    float v = un ? u_s[tid] : -3.0e38f;
    float m = v;
#pragma unroll
    for (int off = 32; off > 0; off >>= 1) m = fmaxf(m, __shfl_xor(m, off, 64));
    if (l == 0) red[w] = m;
    __syncthreads();
    float mx = fmaxf(red[0], red[1]);
    float e = un ? __expf(v - mx) : 0.f;
    float s2 = e;
#pragma unroll
    for (int off = 32; off > 0; off >>= 1) s2 += __shfl_xor(s2, off, 64);
    if (l == 0) red[2 + w] = s2;
    __syncthreads();
    float inv = __fdividef(1.f, red[2] + red[3]);
    if (tid < N_) a_s[tid] = e * inv;
    __syncthreads();
    // ---- PV split-k: wave w sums k == w (mod 2); lane owns h0..h0+7 ----
    const u16* refb = ref + (size_t)b * N_ * H_;
    float pacc[8] = {0.f, 0.f, 0.f, 0.f, 0.f, 0.f, 0.f, 0.f};
    for (int k = w; k < cnt; k += 2) {
        const int n = list[k];
        const float a = a_s[n];
        float rv[8];
        unpack8(*(const uint4*)(refb + (size_t)n * H_ + h0), rv);
#pragma unroll
        for (int j = 0; j < 8; ++j) pacc[j] = fmaf(a, rv[j], pacc[j]);
    }
    {
        float4 pa0 = {pacc[0], pacc[1], pacc[2], pacc[3]};
        float4 pa1 = {pacc[4], pacc[5], pacc[6], pacc[7]};
        *(float4*)&pv_s[w][h0]     = pa0;
        *(float4*)&pv_s[w][h0 + 4] = pa1;
    }
    __syncthreads();
    const int hh = tid * 4;                       // 128 threads x 4 elems
    float s0 = pv_s[0][hh]     + pv_s[1][hh];
    float s1 = pv_s[0][hh + 1] + pv_s[1][hh + 1];
    float s2b = pv_s[0][hh + 2] + pv_s[1][hh + 2];
    float s3 = pv_s[0][hh + 3] + pv_s[1][hh + 3];
    uint2 packed;
    packed.x = ((unsigned)f2bf(s1) << 16) | (unsigned)f2bf(s0);
    packed.y = ((unsigned)f2bf(s3) << 16) | (unsigned)f2bf(s2b);
    *(uint2*)(query2 + (size_t)bt * H_ + hh) = packed;
}

// Pointer head v9 (verified R13): 128 thr + XCD-locality remap.
__global__ __launch_bounds__(128) void final_attn_kernel(
    const u16* __restrict__ q2, const u16* __restrict__ u2p,
    const u16* __restrict__ Vec2, const unsigned char* __restrict__ mask,
    const int* __restrict__ y, float* __restrict__ ll, float* __restrict__ ps)
{
    int b, bt;
    xcd_bt(blockIdx.x, b, bt);
    const int tid = threadIdx.x, w = tid >> 6, l = tid & 63;
    const int g16 = l >> 4, l16 = l & 15;
    __shared__ float u_s[N_], lp_s[N_], red[4];
    __shared__ short list[N_];
    __shared__ unsigned char msk[128];
    __shared__ int wcnt[2], cnt_s;
    const int h32 = l16 * 32;
    h2 qh[16], vh[16];
    {
        const u16* qp = q2 + (size_t)bt * H_ + h32;
        toh2x4(*(const uint4*)qp,        qh);
        toh2x4(*(const uint4*)(qp + 8),  qh + 4);
        toh2x4(*(const uint4*)(qp + 16), qh + 8);
        toh2x4(*(const uint4*)(qp + 24), qh + 12);
        const u16* vp = Vec2 + h32;
#pragma unroll
        for (int m = 0; m < 4; ++m) {
            float vf[8]; unpack8(*(const uint4*)(vp + m * 8), vf);
#pragma unroll
            for (int j = 0; j < 4; ++j)
                vh[m * 4 + j] = (h2){ (f16t)vf[2 * j], (f16t)vf[2 * j + 1] };
        }
    }
    bool un = false;
    msk[tid] = (tid < N_) ? mask[(size_t)bt * N_ + tid] : 1;
    if (tid < N_) {
        un = (msk[tid] == 0);
        u_s[tid] = 0.f;
    }
    unsigned long long bal = __ballot(un);
    if (l == 0) wcnt[w] = __popcll(bal);
    __syncthreads();
    const int base = (w == 1) ? wcnt[0] : 0;
    const int pos = __popcll(bal & ((1ULL << l) - 1ULL));
    if (un) list[base + pos] = (short)tid;
    if (tid == 0) cnt_s = wcnt[0] + wcnt[1];
    __syncthreads();
    const int cnt = cnt_s;
    const u16* ub = u2p + (size_t)b * N_ * H_;
    for (int k = w * 4 + g16; k < cnt; k += 8) {
        const int n = list[k];
        const u16* up = ub + (size_t)n * H_ + h32;
        h2 uh[16];
        toh2x4(*(const uint4*)up,        uh);
        toh2x4(*(const uint4*)(up + 8),  uh + 4);
        toh2x4(*(const uint4*)(up + 16), uh + 8);
        toh2x4(*(const uint4*)(up + 24), uh + 12);
        float sa = 0.f, sb = 0.f, sc = 0.f, sd = 0.f;
#pragma unroll
        for (int j = 0; j < 4; ++j) {
            sa = tanhdot_h2(uh[j],      qh[j],      vh[j],      sa);
            sb = tanhdot_h2(uh[4 + j],  qh[4 + j],  vh[4 + j],  sb);
            sc = tanhdot_h2(uh[8 + j],  qh[8 + j],  vh[8 + j],  sc);
            sd = tanhdot_h2(uh[12 + j], qh[12 + j], vh[12 + j], sd);
        }
        float s = (sa + sb) + (sc + sd);
#pragma unroll
        for (int off = 8; off > 0; off >>= 1) s += __shfl_xor(s, off, 64);
        if (l16 == 0) u_s[n] = s;
    }
    __syncthreads();
    float lg = -3.0e38f;
    if (tid < N_) {
        unsigned char c = msk[tid];
        if (c) lg = -1e8f * (float)c;
        else   lg = 10.f * tanh_poly(u_s[tid]);
    }
    float m = lg;
#pragma unroll
    for (int off = 32; off > 0; off >>= 1) m = fmaxf(m, __shfl_xor(m, off, 64));
    if (l == 0) red[w] = m;
    __syncthreads();
    float mx = fmaxf(red[0], red[1]);
    float e = (tid < N_) ? __expf(lg - mx) : 0.f;
    float s2 = e;
#pragma unroll
    for (int off = 32; off > 0; off >>= 1) s2 += __shfl_xor(s2, off, 64);
    if (l == 0) red[2 + w] = s2;
    __syncthreads();
    float lse = mx + __logf(red[2] + red[3]);
    if (tid < N_) {
        float lp = lg - lse;
        ps[(size_t)bt * N_ + tid] = lp;
        lp_s[tid] = lp;
    }
    __syncthreads();
    if (tid == 0) atomicAdd(&ll[b], lp_s[y[bt]]);
}

// outputs (float32): pi = float(y); ll from f32 accumulator
__global__ void write_out_kernel(const int* __restrict__ y, const float* __restrict__ ll,
                                 float* __restrict__ out) {
    int i = blockIdx.x * 256 + threadIdx.x;   // 51200 threads
    if (i < BT_) out[i] = (float)y[i];
    if (i < B_)  out[BT_ + i] = ll[i];
}

// ---------------------------------------------------------------------------
extern "C" void kernel_launch(void* const* d_in, const int* in_sizes, int n_in,
                              void* d_out, int out_size, void* d_ws, size_t ws_size,
                              hipStream_t stream)
{
    const u16* x        = (const u16*)d_in[0];
    const int* y        = (const int*)d_in[1];
    const u16* emb_W    = (const u16*)d_in[2];
    const u16* enc_Wih  = (const u16*)d_in[3];
    const u16* enc_Whh  = (const u16*)d_in[4];
    const u16* enc_bih  = (const u16*)d_in[5];
    const u16* enc_bhh  = (const u16*)d_in[6];
    const u16* dec_Wih  = (const u16*)d_in[7];
    const u16* dec_Whh  = (const u16*)d_in[8];
    const u16* dec_bih  = (const u16*)d_in[9];
    const u16* dec_bhh  = (const u16*)d_in[10];
    const u16* Vec      = (const u16*)d_in[11];
    const u16* Vec2     = (const u16*)d_in[12];
    const u16* Wq_W     = (const u16*)d_in[13];
    const u16* Wq_b     = (const u16*)d_in[14];
    const u16* Wref_W   = (const u16*)d_in[15];
    const u16* Wref_b   = (const u16*)d_in[16];
    const u16* Wq2_W    = (const u16*)d_in[17];
    const u16* Wq2_b    = (const u16*)d_in[18];
    const u16* Wref2_W  = (const u16*)d_in[19];
    const u16* Wref2_b  = (const u16*)d_in[20];
    const u16* dec0     = (const u16*)d_in[21];

    char* p = (char*)d_ws;
    auto carve = [&](size_t bytes) -> char* {
        char* r = p; p += (bytes + 255) & ~(size_t)255; return r;
    };
    u16*   embed     = (u16*)  carve((size_t)BT_ * E_ * 2);      // 26.21 MB
    float* cbuf      = (float*)carve((size_t)B_ * H_ * 4);       //  1.05 MB
    u16*   zero_h    = (u16*)  carve((size_t)B_ * H_ * 2);       //  0.52 MB
    u16*   dec0_rows = (u16*)  carve((size_t)B_ * E_ * 2);       //  0.26 MB
    u16*   ref       = (u16*)  carve((size_t)BT_ * H_ * 2);      // 52.43 MB
    u16*   dec_hs    = (u16*)  carve((size_t)BT_ * H_ * 2);      // 52.43 MB (later: qry2)
    unsigned char* maskb = (unsigned char*)carve((size_t)BT_ * N_); // 5.12 MB
    float* llb       = (float*)carve((size_t)B_ * 4);
    const size_t need = (size_t)(p - (char*)d_ws);
    u16* Ybuf = embed;                                  // u2g / u2p chunk (f16)
    u16* Zbuf = embed + (size_t)BC_ * N_ * H_;          // q1 / q2 chunk (f16)

    if (need > ws_size) {
        sentinel_kernel<<<(B_ + 255) / 256, 256, 0, stream>>>((float*)d_out);
        return;
    }

    init_kernel<<<(B_ * H_) / 256, 256, 0, stream>>>(cbuf, zero_h, llb, dec0_rows, dec0);
    embed_kernel<<<BT_, 256, 0, stream>>>(x, emb_W, embed);
    mask_kernel<<<B_, 128, 0, stream>>>(y, maskb);

    // ---- LSTM steps: multi-launch, fused9 (A-direct, B-staged, XCD) ----
    dim3 sgrid(32, 8);   // linearized then remapped in-kernel
    for (int t = 0; t < N_; ++t) {
        const u16* hb = (t == 0) ? zero_h : (ref + (size_t)(t - 1) * H_);
        int hlda = (t == 0) ? H_ : (N_ * H_);
        fused9_step_kernel<<<sgrid, 256, 0, stream>>>(hb, hlda, embed, y,
                                                      enc_Whh, enc_Wih, enc_bih, enc_bhh,
                                                      cbuf, ref + (size_t)t * H_, 0, t);
    }
    for (int t = 0; t < N_; ++t) {
        const u16* hb = (t == 0) ? (ref + (size_t)(N_ - 1) * H_) : (dec_hs + (size_t)(t - 1) * H_);
        const u16* xb = (t == 0) ? dec0_rows : embed;
        int mode = (t == 0) ? 1 : 2;
        fused9_step_kernel<<<sgrid, 256, 0, stream>>>(hb, N_ * H_, xb, y,
                                                      dec_Whh, dec_Wih, dec_bih, dec_bhh,
                                                      cbuf, dec_hs + (size_t)t * H_, mode, t);
    }

    // ---- batched attention, chunked over batch (embed now dead) ----
    float* out = (float*)d_out;
    const int MC = BC_ * N_;                     // 12800 rows per chunk
    dim3 ggrid(8, 400);                          // dual gemm, XCD-remapped
    for (int c = 0; c < NCHUNK_; ++c) {
        const size_t rowOff = (size_t)c * BC_ * N_ * H_;
        const size_t btOff  = (size_t)c * BC_ * N_;
        gemm_bt2_kernel<<<ggrid, 256, 0, stream>>>(dec_hs + rowOff, Wq_W,  Wq_b,  Zbuf,
                                                   ref + rowOff,    Wref_W, Wref_b, Ybuf);
        glimpse_kernel<<<MC, 128, 0, stream>>>(Zbuf, Ybuf, ref + rowOff, Vec,
                                               maskb + btOff * N_, dec_hs + rowOff);
        gemm_bt2_kernel<<<ggrid, 256, 0, stream>>>(dec_hs + rowOff, Wq2_W, Wq2_b, Zbuf,
                                                   ref + rowOff,    Wref2_W, Wref2_b, Ybuf);
        final_attn_kernel<<<MC, 128, 0, stream>>>(Zbuf, Ybuf, Vec2, maskb + btOff * N_,
                                                  y + btOff, llb + (size_t)c * BC_,
                                                  out + BT_ + B_ + btOff * N_);
    }
    write_out_kernel<<<BT_ / 256, 256, 0, stream>>>(y, llb, out);
}